// Round 1
// baseline (9793.401 us; speedup 1.0000x reference)
//
#include <hip/hip_runtime.h>

#define N_NODES 8192
#define N_EDGES 262144
#define SLOPE 0.25f

__device__ __forceinline__ float lrelu(float x) { return x >= 0.f ? x : SLOPE * x; }

// ---------------- GEMM: C[M,N] = A[M,K] @ B[K,N], fp32 ----------------
// BM=128, BN=64, BK=16; 256 threads; each thread computes 8x4.
#define BM 128
#define BN 64
#define BK 16
#define AS_LD 132  // BM + 4 pad: keeps 16B alignment for float4 LDS reads, breaks store conflicts

__global__ __launch_bounds__(256) void gemm_f32(const float* __restrict__ A,
                                                const float* __restrict__ B,
                                                float* __restrict__ C,
                                                int M, int K, int N) {
    __shared__ float As[BK * AS_LD];   // As[k][m]
    __shared__ float Bs[BK * BN];      // Bs[k][n]
    const int tid = threadIdx.x;
    const int bm0 = blockIdx.y * BM;
    const int bn0 = blockIdx.x * BN;
    const int ty = tid >> 4;   // 0..15 -> rows ty*8..ty*8+7
    const int tx = tid & 15;   // 0..15 -> cols tx*4..tx*4+3

    float acc[8][4];
#pragma unroll
    for (int i = 0; i < 8; ++i)
#pragma unroll
        for (int j = 0; j < 4; ++j) acc[i][j] = 0.f;

    for (int k0 = 0; k0 < K; k0 += BK) {
        // stage A tile (128x16 = 512 float4), transposed into As[k][m]
#pragma unroll
        for (int it = 0; it < 2; ++it) {
            const int f = tid + it * 256;        // float4 id in [0,512)
            const int r = f >> 2;                // row in tile [0,128)
            const int c4 = (f & 3) << 2;         // k-col [0,16) step 4
            const float4 v = *reinterpret_cast<const float4*>(
                A + (long long)(bm0 + r) * K + k0 + c4);
            As[(c4 + 0) * AS_LD + r] = v.x;
            As[(c4 + 1) * AS_LD + r] = v.y;
            As[(c4 + 2) * AS_LD + r] = v.z;
            As[(c4 + 3) * AS_LD + r] = v.w;
        }
        // stage B tile (16x64 = 256 float4)
        {
            const int r = tid >> 4;              // [0,16)
            const int c4 = (tid & 15) << 2;      // [0,64) step 4
            const float4 v = *reinterpret_cast<const float4*>(
                B + (long long)(k0 + r) * N + bn0 + c4);
            *reinterpret_cast<float4*>(&Bs[r * BN + c4]) = v;
        }
        __syncthreads();
#pragma unroll
        for (int k = 0; k < BK; ++k) {
            const float4 a0 = *reinterpret_cast<const float4*>(&As[k * AS_LD + ty * 8]);
            const float4 a1 = *reinterpret_cast<const float4*>(&As[k * AS_LD + ty * 8 + 4]);
            const float4 b4 = *reinterpret_cast<const float4*>(&Bs[k * BN + tx * 4]);
            const float a[8] = {a0.x, a0.y, a0.z, a0.w, a1.x, a1.y, a1.z, a1.w};
            const float bb[4] = {b4.x, b4.y, b4.z, b4.w};
#pragma unroll
            for (int i = 0; i < 8; ++i)
#pragma unroll
                for (int j = 0; j < 4; ++j) acc[i][j] = fmaf(a[i], bb[j], acc[i][j]);
        }
        __syncthreads();
    }
#pragma unroll
    for (int i = 0; i < 8; ++i) {
        float4 v = make_float4(acc[i][0], acc[i][1], acc[i][2], acc[i][3]);
        *reinterpret_cast<float4*>(C + (long long)(bm0 + ty * 8 + i) * N + bn0 + tx * 4) = v;
    }
}

// ---------------- SpMM scatter: H[rows[e], :] += vals[e] * Y[cols[e], :] -------
// One thread per (edge, 4-column chunk). lgchunks = log2(nc/4).
__global__ __launch_bounds__(256) void spmm_atomic(const int* __restrict__ rows,
                                                   const int* __restrict__ cols,
                                                   const float* __restrict__ vals,
                                                   const float* __restrict__ Y,
                                                   float* __restrict__ H,
                                                   int lgchunks, int nc) {
    const long long idx = (long long)blockIdx.x * blockDim.x + threadIdx.x;
    const int e = (int)(idx >> lgchunks);
    if (e >= N_EDGES) return;
    const int c4 = ((int)idx & ((1 << lgchunks) - 1)) << 2;
    const int r = rows[e];
    const int cl = cols[e];
    const float v = vals[e];
    const float4 y = *reinterpret_cast<const float4*>(Y + (long long)cl * nc + c4);
    float* h = H + (long long)r * nc + c4;
    atomicAdd(h + 0, v * y.x);
    atomicAdd(h + 1, v * y.y);
    atomicAdd(h + 2, v * y.z);
    atomicAdd(h + 3, v * y.w);
}

// ---------------- H = leaky(H + bias) (row-broadcast bias) ----------------
__global__ __launch_bounds__(256) void bias_leaky(float* __restrict__ H,
                                                  const float* __restrict__ bias,
                                                  int lgnc4, long long total4) {
    const long long idx = (long long)blockIdx.x * blockDim.x + threadIdx.x;
    if (idx >= total4) return;
    const int c4 = ((int)idx & ((1 << lgnc4) - 1)) << 2;
    float4 h = *reinterpret_cast<float4*>(H + idx * 4);
    const float4 b = *reinterpret_cast<const float4*>(bias + c4);
    h.x = lrelu(h.x + b.x);
    h.y = lrelu(h.y + b.y);
    h.z = lrelu(h.z + b.z);
    h.w = lrelu(h.w + b.w);
    *reinterpret_cast<float4*>(H + idx * 4) = h;
}

// ---------------- out (+)= 0.25 * leaky(H2 + b2) ----------------
__global__ __launch_bounds__(256) void accum_out(float* __restrict__ out,
                                                 const float* __restrict__ H2,
                                                 const float* __restrict__ bias,
                                                 int first) {
    const long long idx = (long long)blockIdx.x * blockDim.x + threadIdx.x;  // 8192*32 total
    const int c4 = ((int)idx & 31) << 2;  // DF=128 -> 32 chunks
    const float4 h = *reinterpret_cast<const float4*>(H2 + idx * 4);
    const float4 b = *reinterpret_cast<const float4*>(bias + c4);
    float4 r;
    r.x = 0.25f * lrelu(h.x + b.x);
    r.y = 0.25f * lrelu(h.y + b.y);
    r.z = 0.25f * lrelu(h.z + b.z);
    r.w = 0.25f * lrelu(h.w + b.w);
    if (!first) {
        const float4 o = *reinterpret_cast<const float4*>(out + idx * 4);
        r.x += o.x; r.y += o.y; r.z += o.z; r.w += o.w;
    }
    *reinterpret_cast<float4*>(out + idx * 4) = r;
}

extern "C" void kernel_launch(void* const* d_in, const int* in_sizes, int n_in,
                              void* d_out, int out_size, void* d_ws, size_t ws_size,
                              hipStream_t stream) {
    const float* X[4]    = {(const float*)d_in[0], (const float*)d_in[1],
                            (const float*)d_in[2], (const float*)d_in[3]};
    const int* rows[4]   = {(const int*)d_in[4], (const int*)d_in[7],
                            (const int*)d_in[10], (const int*)d_in[13]};
    const int* cols[4]   = {(const int*)d_in[5], (const int*)d_in[8],
                            (const int*)d_in[11], (const int*)d_in[14]};
    const float* vals[4] = {(const float*)d_in[6], (const float*)d_in[9],
                            (const float*)d_in[12], (const float*)d_in[15]};
    const float *w1[4], *b1[4], *w2[4], *b2[4];
    for (int b = 0; b < 4; ++b) {
        w1[b] = (const float*)d_in[16 + 4 * b + 0];
        b1[b] = (const float*)d_in[16 + 4 * b + 1];
        w2[b] = (const float*)d_in[16 + 4 * b + 2];
        b2[b] = (const float*)d_in[16 + 4 * b + 3];
    }
    const int din[4] = {4096, 4096, 4096, 1024};
    const int dh[4]  = {512, 512, 512, 256};

    float* Y1 = (float*)d_ws;                         // 8192*512
    float* H1 = Y1 + (size_t)N_NODES * 512;           // 8192*512
    float* Y2 = H1 + (size_t)N_NODES * 512;           // 8192*128
    float* H2 = Y2 + (size_t)N_NODES * 128;           // 8192*128
    float* out = (float*)d_out;

    for (int b = 0; b < 4; ++b) {
        const int K1 = din[b], N1 = dh[b];
        // lg2(nc/4): 512->7, 256->6, 128->5
        const int lg1 = (N1 == 512) ? 7 : (N1 == 256) ? 6 : 5;

        // Y1 = X @ W1
        {
            dim3 grid(N1 / BN, N_NODES / BM);
            gemm_f32<<<grid, 256, 0, stream>>>(X[b], w1[b], Y1, N_NODES, K1, N1);
        }
        // H1 = spmm(Y1)
        hipMemsetAsync(H1, 0, (size_t)N_NODES * N1 * sizeof(float), stream);
        {
            const long long total = (long long)N_EDGES << lg1;
            spmm_atomic<<<(int)(total / 256), 256, 0, stream>>>(
                rows[b], cols[b], vals[b], Y1, H1, lg1, N1);
        }
        // H1 = leaky(H1 + b1)
        {
            const long long total4 = (long long)N_NODES * N1 / 4;
            bias_leaky<<<(int)((total4 + 255) / 256), 256, 0, stream>>>(H1, b1[b], lg1, total4);
        }
        // Y2 = H1 @ W2
        {
            dim3 grid(128 / BN, N_NODES / BM);
            gemm_f32<<<grid, 256, 0, stream>>>(H1, w2[b], Y2, N_NODES, N1, 128);
        }
        // H2 = spmm(Y2)
        hipMemsetAsync(H2, 0, (size_t)N_NODES * 128 * sizeof(float), stream);
        {
            const long long total = (long long)N_EDGES << 5;
            spmm_atomic<<<(int)(total / 256), 256, 0, stream>>>(
                rows[b], cols[b], vals[b], Y2, H2, 5, 128);
        }
        // out (+)= 0.25 * leaky(H2 + b2)
        {
            const long long total4 = (long long)N_NODES * 128 / 4;
            accum_out<<<(int)(total4 / 256), 256, 0, stream>>>(out, H2, b2[b], b == 0);
        }
    }
}

// Round 2
// 2204.714 us; speedup vs baseline: 4.4420x; 4.4420x over previous
//
#include <hip/hip_runtime.h>

#define N_NODES 8192
#define N_EDGES 262144
#define SLOPE 0.25f

__device__ __forceinline__ float lrelu(float x) { return x >= 0.f ? x : SLOPE * x; }

// ---------------- GEMM: C[M,N] = A[M,K] @ B[K,N], fp32 ----------------
#define BM 128
#define BN 64
#define BK 16
#define AS_LD 132

__global__ __launch_bounds__(256) void gemm_f32(const float* __restrict__ A,
                                                const float* __restrict__ B,
                                                float* __restrict__ C,
                                                int M, int K, int N) {
    __shared__ float As[BK * AS_LD];   // As[k][m]
    __shared__ float Bs[BK * BN];      // Bs[k][n]
    const int tid = threadIdx.x;
    const int bm0 = blockIdx.y * BM;
    const int bn0 = blockIdx.x * BN;
    const int ty = tid >> 4;
    const int tx = tid & 15;

    float acc[8][4];
#pragma unroll
    for (int i = 0; i < 8; ++i)
#pragma unroll
        for (int j = 0; j < 4; ++j) acc[i][j] = 0.f;

    for (int k0 = 0; k0 < K; k0 += BK) {
#pragma unroll
        for (int it = 0; it < 2; ++it) {
            const int f = tid + it * 256;
            const int r = f >> 2;
            const int c4 = (f & 3) << 2;
            const float4 v = *reinterpret_cast<const float4*>(
                A + (long long)(bm0 + r) * K + k0 + c4);
            As[(c4 + 0) * AS_LD + r] = v.x;
            As[(c4 + 1) * AS_LD + r] = v.y;
            As[(c4 + 2) * AS_LD + r] = v.z;
            As[(c4 + 3) * AS_LD + r] = v.w;
        }
        {
            const int r = tid >> 4;
            const int c4 = (tid & 15) << 2;
            const float4 v = *reinterpret_cast<const float4*>(
                B + (long long)(k0 + r) * N + bn0 + c4);
            *reinterpret_cast<float4*>(&Bs[r * BN + c4]) = v;
        }
        __syncthreads();
#pragma unroll
        for (int k = 0; k < BK; ++k) {
            const float4 a0 = *reinterpret_cast<const float4*>(&As[k * AS_LD + ty * 8]);
            const float4 a1 = *reinterpret_cast<const float4*>(&As[k * AS_LD + ty * 8 + 4]);
            const float4 b4 = *reinterpret_cast<const float4*>(&Bs[k * BN + tx * 4]);
            const float a[8] = {a0.x, a0.y, a0.z, a0.w, a1.x, a1.y, a1.z, a1.w};
            const float bb[4] = {b4.x, b4.y, b4.z, b4.w};
#pragma unroll
            for (int i = 0; i < 8; ++i)
#pragma unroll
                for (int j = 0; j < 4; ++j) acc[i][j] = fmaf(a[i], bb[j], acc[i][j]);
        }
        __syncthreads();
    }
#pragma unroll
    for (int i = 0; i < 8; ++i) {
        float4 v = make_float4(acc[i][0], acc[i][1], acc[i][2], acc[i][3]);
        *reinterpret_cast<float4*>(C + (long long)(bm0 + ty * 8 + i) * N + bn0 + tx * 4) = v;
    }
}

// ---------------- CSR build ----------------
__global__ __launch_bounds__(256) void hist_rows(const int* __restrict__ rows,
                                                 int* __restrict__ cnt) {
    const int e = blockIdx.x * 256 + threadIdx.x;  // E divisible by 256
    atomicAdd(&cnt[rows[e]], 1);
}

// single block, 256 threads: exclusive scan of cnt[0..8191] -> row_start[0..8192], cursor copy
__global__ __launch_bounds__(256) void scan8192(const int* __restrict__ cnt,
                                                int* __restrict__ row_start,
                                                int* __restrict__ cursor) {
    __shared__ int ssum[256];
    const int t = threadIdx.x;
    int local[32];
    int s = 0;
#pragma unroll
    for (int j = 0; j < 32; ++j) { local[j] = cnt[t * 32 + j]; s += local[j]; }
    ssum[t] = s;
    __syncthreads();
    for (int off = 1; off < 256; off <<= 1) {
        const int v = ssum[t];
        const int add = (t >= off) ? ssum[t - off] : 0;
        __syncthreads();
        ssum[t] = v + add;
        __syncthreads();
    }
    int run = (t == 0) ? 0 : ssum[t - 1];
#pragma unroll
    for (int j = 0; j < 32; ++j) {
        row_start[t * 32 + j] = run;
        cursor[t * 32 + j] = run;
        run += local[j];
    }
    if (t == 255) row_start[8192] = run;
}

__global__ __launch_bounds__(256) void scatter_edges(const int* __restrict__ rows,
                                                     const int* __restrict__ cols,
                                                     const float* __restrict__ vals,
                                                     int* __restrict__ cursor,
                                                     int* __restrict__ pcol,
                                                     float* __restrict__ pval) {
    const int e = blockIdx.x * 256 + threadIdx.x;
    const int r = rows[e];
    const int pos = atomicAdd(&cursor[r], 1);
    pcol[pos] = cols[e];
    pval[pos] = vals[e];
}

// ---------------- gather SpMM, one wave per row, fused epilogue ----------------
// MODE 0: Out[i,:] = lrelu(spmm + bias)
// MODE 1: Out[i,:] = (first?0:Out[i,:]) + 0.25*lrelu(spmm + bias)
template <int NC, int MODE>
__global__ __launch_bounds__(256) void spmm_gather(const int* __restrict__ row_start,
                                                   const int* __restrict__ pcol,
                                                   const float* __restrict__ pval,
                                                   const float* __restrict__ Y,
                                                   const float* __restrict__ bias,
                                                   float* __restrict__ Out,
                                                   int first) {
    constexpr int PL = NC / 64;  // floats per lane
    const int row = (blockIdx.x * 256 + threadIdx.x) >> 6;
    const int lane = threadIdx.x & 63;
    const int s = row_start[row];
    const int e1 = row_start[row + 1];
    const int base = lane * PL;
    float acc[PL];
#pragma unroll
    for (int j = 0; j < PL; ++j) acc[j] = 0.f;

    for (int e = s; e < e1; ++e) {
        const int c = pcol[e];
        const float v = pval[e];
        const float* y = Y + (size_t)c * NC + base;
        if constexpr (PL >= 4) {
#pragma unroll
            for (int q = 0; q < PL / 4; ++q) {
                const float4 a = *reinterpret_cast<const float4*>(y + q * 4);
                acc[q * 4 + 0] = fmaf(v, a.x, acc[q * 4 + 0]);
                acc[q * 4 + 1] = fmaf(v, a.y, acc[q * 4 + 1]);
                acc[q * 4 + 2] = fmaf(v, a.z, acc[q * 4 + 2]);
                acc[q * 4 + 3] = fmaf(v, a.w, acc[q * 4 + 3]);
            }
        } else {
            const float2 a = *reinterpret_cast<const float2*>(y);
            acc[0] = fmaf(v, a.x, acc[0]);
            acc[1] = fmaf(v, a.y, acc[1]);
        }
    }

    float r[PL];
#pragma unroll
    for (int j = 0; j < PL; ++j) {
        float x = lrelu(acc[j] + bias[base + j]);
        if (MODE == 1) x *= 0.25f;
        r[j] = x;
    }
    float* o = Out + (size_t)row * NC + base;
    if constexpr (MODE == 1) {
        if (!first) {
#pragma unroll
            for (int j = 0; j < PL; ++j) r[j] += o[j];
        }
    }
    if constexpr (PL >= 4) {
#pragma unroll
        for (int q = 0; q < PL / 4; ++q)
            *reinterpret_cast<float4*>(o + q * 4) =
                make_float4(r[q * 4], r[q * 4 + 1], r[q * 4 + 2], r[q * 4 + 3]);
    } else {
        *reinterpret_cast<float2*>(o) = make_float2(r[0], r[1]);
    }
}

extern "C" void kernel_launch(void* const* d_in, const int* in_sizes, int n_in,
                              void* d_out, int out_size, void* d_ws, size_t ws_size,
                              hipStream_t stream) {
    const float* X[4]    = {(const float*)d_in[0], (const float*)d_in[1],
                            (const float*)d_in[2], (const float*)d_in[3]};
    const int* rows[4]   = {(const int*)d_in[4], (const int*)d_in[7],
                            (const int*)d_in[10], (const int*)d_in[13]};
    const int* cols[4]   = {(const int*)d_in[5], (const int*)d_in[8],
                            (const int*)d_in[11], (const int*)d_in[14]};
    const float* vals[4] = {(const float*)d_in[6], (const float*)d_in[9],
                            (const float*)d_in[12], (const float*)d_in[15]};
    const float *w1[4], *b1[4], *w2[4], *b2[4];
    for (int b = 0; b < 4; ++b) {
        w1[b] = (const float*)d_in[16 + 4 * b + 0];
        b1[b] = (const float*)d_in[16 + 4 * b + 1];
        w2[b] = (const float*)d_in[16 + 4 * b + 2];
        b2[b] = (const float*)d_in[16 + 4 * b + 3];
    }
    const int din[4] = {4096, 4096, 4096, 1024};
    const int dh[4]  = {512, 512, 512, 256};

    // workspace layout (floats/ints)
    float* Y1 = (float*)d_ws;                           // 8192*512
    float* H1 = Y1 + (size_t)N_NODES * 512;             // 8192*512
    float* Y2 = H1 + (size_t)N_NODES * 512;             // 8192*128
    int*   cnt = (int*)(Y2 + (size_t)N_NODES * 128);    // 8192
    int*   row_start = cnt + N_NODES;                   // 8193
    int*   cursor = row_start + N_NODES + 1;            // 8192
    int*   pcol = cursor + N_NODES;                     // E
    float* pval = (float*)(pcol + N_EDGES);             // E
    float* out = (float*)d_out;

    for (int b = 0; b < 4; ++b) {
        const int K1 = din[b], N1 = dh[b];

        // --- CSR build for this branch's graph ---
        hipMemsetAsync(cnt, 0, N_NODES * sizeof(int), stream);
        hist_rows<<<N_EDGES / 256, 256, 0, stream>>>(rows[b], cnt);
        scan8192<<<1, 256, 0, stream>>>(cnt, row_start, cursor);
        scatter_edges<<<N_EDGES / 256, 256, 0, stream>>>(rows[b], cols[b], vals[b],
                                                         cursor, pcol, pval);

        // Y1 = X @ W1
        {
            dim3 grid(N1 / BN, N_NODES / BM);
            gemm_f32<<<grid, 256, 0, stream>>>(X[b], w1[b], Y1, N_NODES, K1, N1);
        }
        // H1 = lrelu(spmm(Y1) + b1)
        if (N1 == 512)
            spmm_gather<512, 0><<<N_NODES / 4, 256, 0, stream>>>(row_start, pcol, pval,
                                                                 Y1, b1[b], H1, 0);
        else
            spmm_gather<256, 0><<<N_NODES / 4, 256, 0, stream>>>(row_start, pcol, pval,
                                                                 Y1, b1[b], H1, 0);
        // Y2 = H1 @ W2
        {
            dim3 grid(128 / BN, N_NODES / BM);
            gemm_f32<<<grid, 256, 0, stream>>>(H1, w2[b], Y2, N_NODES, N1, 128);
        }
        // out (+)= 0.25 * lrelu(spmm(Y2) + b2)
        spmm_gather<128, 1><<<N_NODES / 4, 256, 0, stream>>>(row_start, pcol, pval,
                                                             Y2, b2[b], out, b == 0);
    }
}

// Round 3
// 1403.430 us; speedup vs baseline: 6.9782x; 1.5709x over previous
//
#include <hip/hip_runtime.h>

#define N_NODES 8192
#define N_EDGES 262144
#define SLOPE 0.25f

typedef __attribute__((ext_vector_type(8))) short bf16x8;
typedef __attribute__((ext_vector_type(4))) float f32x4;

__device__ __forceinline__ float lrelu(float x) { return x >= 0.f ? x : SLOPE * x; }

__device__ __forceinline__ unsigned bf16_rne(float x) {
    unsigned u = __float_as_uint(x);
    return (u + 0x7FFFu + ((u >> 16) & 1u)) >> 16;
}
__device__ __forceinline__ void bsplit(float x, unsigned short& h, unsigned short& l) {
    unsigned hr = bf16_rne(x);
    h = (unsigned short)hr;
    float res = x - __uint_as_float(hr << 16);
    l = (unsigned short)bf16_rne(res);
}

#define GLDS16(g, l)                                                              \
    __builtin_amdgcn_global_load_lds((const __attribute__((address_space(1))) void*)(g), \
                                     (__attribute__((address_space(3))) void*)(l), 16, 0, 0)

// ---------------- split: A f32 -> hi/lo bf16 ----------------
__global__ __launch_bounds__(256) void split_f32(const float* __restrict__ A,
                                                 unsigned short* __restrict__ hi,
                                                 unsigned short* __restrict__ lo,
                                                 long long n4) {
    const long long i = (long long)blockIdx.x * 256 + threadIdx.x;
    if (i >= n4) return;
    const float4 a = reinterpret_cast<const float4*>(A)[i];
    ushort4 h, l;
    bsplit(a.x, h.x, l.x);
    bsplit(a.y, h.y, l.y);
    bsplit(a.z, h.z, l.z);
    bsplit(a.w, h.w, l.w);
    reinterpret_cast<ushort4*>(hi)[i] = h;
    reinterpret_cast<ushort4*>(lo)[i] = l;
}

// ---------------- W [K,N] f32 -> WT hi/lo bf16 [N,K] ----------------
__global__ __launch_bounds__(256) void transpose_split(const float* __restrict__ W,
                                                       unsigned short* __restrict__ Th,
                                                       unsigned short* __restrict__ Tl,
                                                       int K, int N) {
    __shared__ float t[32][33];
    const int k0 = blockIdx.x * 32, n0 = blockIdx.y * 32;
    const int tx = threadIdx.x & 31, ty = threadIdx.x >> 5;
#pragma unroll
    for (int i = 0; i < 32; i += 8)
        t[ty + i][tx] = W[(size_t)(k0 + ty + i) * N + n0 + tx];
    __syncthreads();
#pragma unroll
    for (int i = 0; i < 32; i += 8) {
        const int n = ty + i;
        unsigned short h, l;
        bsplit(t[tx][n], h, l);
        Th[(size_t)(n0 + n) * K + k0 + tx] = h;
        Tl[(size_t)(n0 + n) * K + k0 + tx] = l;
    }
}

// ---------------- split-bf16 MFMA GEMM ----------------
// C[M,N] = A @ B, A given as Ahi/Alo [M,K] bf16, B as Bhi/Blo [N,K] bf16 (pre-transposed).
// Tile 64(M) x 128(N) x 32(K); 256 threads = 4 waves in 2x2; wave tile 32x64.
// LDS rows: 128 B = [0..63]=hi k-tile bytes, [64..127]=lo; XOR-swizzled by ((row&7)<<4).
__global__ __launch_bounds__(256) void gemm_split(const unsigned short* __restrict__ Ahi,
                                                  const unsigned short* __restrict__ Alo,
                                                  const unsigned short* __restrict__ Bhi,
                                                  const unsigned short* __restrict__ Blo,
                                                  float* __restrict__ C,
                                                  int M, int K, int N) {
    __shared__ unsigned short As[64 * 64];    // 8 KB
    __shared__ unsigned short Bs[128 * 64];   // 16 KB
    const int tid = threadIdx.x;
    const int w = tid >> 6, lane = tid & 63;
    const int wm = w >> 1, wn = w & 1;
    const int bm0 = blockIdx.x * 64, bn0 = blockIdx.y * 128;

    f32x4 acc[2][4];
#pragma unroll
    for (int mf = 0; mf < 2; ++mf)
#pragma unroll
        for (int nf = 0; nf < 4; ++nf) acc[mf][nf] = (f32x4){0.f, 0.f, 0.f, 0.f};

    for (int k0 = 0; k0 < K; k0 += 32) {
        // stage A (8 KB): 2 issues/wave
#pragma unroll
        for (int i = 0; i < 2; ++i) {
            const int o = (w * 2 + i) * 1024 + lane * 16;
            const int row = o >> 7;
            const int c = (o & 127) ^ ((row & 7) << 4);
            const unsigned short* g =
                (c < 64) ? Ahi + (size_t)(bm0 + row) * K + k0 + (c >> 1)
                         : Alo + (size_t)(bm0 + row) * K + k0 + ((c - 64) >> 1);
            GLDS16(g, &As[(w * 2 + i) * 512]);
        }
        // stage B (16 KB): 4 issues/wave
#pragma unroll
        for (int i = 0; i < 4; ++i) {
            const int o = (w * 4 + i) * 1024 + lane * 16;
            const int row = o >> 7;
            const int c = (o & 127) ^ ((row & 7) << 4);
            const unsigned short* g =
                (c < 64) ? Bhi + (size_t)(bn0 + row) * K + k0 + (c >> 1)
                         : Blo + (size_t)(bn0 + row) * K + k0 + ((c - 64) >> 1);
            GLDS16(g, &Bs[(w * 4 + i) * 512]);
        }
        __syncthreads();

        const int kb = (lane >> 4) * 16;   // byte offset of this lane's 8-bf16 k-group
        bf16x8 ah[2], al[2], bh[4], bl[4];
#pragma unroll
        for (int mf = 0; mf < 2; ++mf) {
            const int r = wm * 32 + mf * 16 + (lane & 15);
            const int sw = (r & 7) << 4;
            ah[mf] = *reinterpret_cast<const bf16x8*>(&As[r * 64 + ((kb ^ sw) >> 1)]);
            al[mf] = *reinterpret_cast<const bf16x8*>(&As[r * 64 + (((64 + kb) ^ sw) >> 1)]);
        }
#pragma unroll
        for (int nf = 0; nf < 4; ++nf) {
            const int r = wn * 64 + nf * 16 + (lane & 15);
            const int sw = (r & 7) << 4;
            bh[nf] = *reinterpret_cast<const bf16x8*>(&Bs[r * 64 + ((kb ^ sw) >> 1)]);
            bl[nf] = *reinterpret_cast<const bf16x8*>(&Bs[r * 64 + (((64 + kb) ^ sw) >> 1)]);
        }
#pragma unroll
        for (int mf = 0; mf < 2; ++mf)
#pragma unroll
            for (int nf = 0; nf < 4; ++nf) {
                acc[mf][nf] = __builtin_amdgcn_mfma_f32_16x16x32_bf16(ah[mf], bh[nf], acc[mf][nf], 0, 0, 0);
                acc[mf][nf] = __builtin_amdgcn_mfma_f32_16x16x32_bf16(ah[mf], bl[nf], acc[mf][nf], 0, 0, 0);
                acc[mf][nf] = __builtin_amdgcn_mfma_f32_16x16x32_bf16(al[mf], bh[nf], acc[mf][nf], 0, 0, 0);
            }
        __syncthreads();
    }

    const int cr = (lane >> 4) * 4, cc = lane & 15;
#pragma unroll
    for (int mf = 0; mf < 2; ++mf)
#pragma unroll
        for (int nf = 0; nf < 4; ++nf)
#pragma unroll
            for (int j = 0; j < 4; ++j)
                C[(size_t)(bm0 + wm * 32 + mf * 16 + cr + j) * N + bn0 + wn * 64 + nf * 16 + cc] =
                    acc[mf][nf][j];
}

// ---------------- fp32 GEMM (layer 2 + fallback) ----------------
#define BM 128
#define BN 64
#define BK 16
#define AS_LD 132

__global__ __launch_bounds__(256) void gemm_f32(const float* __restrict__ A,
                                                const float* __restrict__ B,
                                                float* __restrict__ C,
                                                int M, int K, int N) {
    __shared__ float As[BK * AS_LD];
    __shared__ float Bs[BK * BN];
    const int tid = threadIdx.x;
    const int bm0 = blockIdx.y * BM;
    const int bn0 = blockIdx.x * BN;
    const int ty = tid >> 4;
    const int tx = tid & 15;

    float acc[8][4];
#pragma unroll
    for (int i = 0; i < 8; ++i)
#pragma unroll
        for (int j = 0; j < 4; ++j) acc[i][j] = 0.f;

    for (int k0 = 0; k0 < K; k0 += BK) {
#pragma unroll
        for (int it = 0; it < 2; ++it) {
            const int f = tid + it * 256;
            const int r = f >> 2;
            const int c4 = (f & 3) << 2;
            const float4 v = *reinterpret_cast<const float4*>(
                A + (long long)(bm0 + r) * K + k0 + c4);
            As[(c4 + 0) * AS_LD + r] = v.x;
            As[(c4 + 1) * AS_LD + r] = v.y;
            As[(c4 + 2) * AS_LD + r] = v.z;
            As[(c4 + 3) * AS_LD + r] = v.w;
        }
        {
            const int r = tid >> 4;
            const int c4 = (tid & 15) << 2;
            const float4 v = *reinterpret_cast<const float4*>(
                B + (long long)(k0 + r) * N + bn0 + c4);
            *reinterpret_cast<float4*>(&Bs[r * BN + c4]) = v;
        }
        __syncthreads();
#pragma unroll
        for (int k = 0; k < BK; ++k) {
            const float4 a0 = *reinterpret_cast<const float4*>(&As[k * AS_LD + ty * 8]);
            const float4 a1 = *reinterpret_cast<const float4*>(&As[k * AS_LD + ty * 8 + 4]);
            const float4 b4 = *reinterpret_cast<const float4*>(&Bs[k * BN + tx * 4]);
            const float a[8] = {a0.x, a0.y, a0.z, a0.w, a1.x, a1.y, a1.z, a1.w};
            const float bb[4] = {b4.x, b4.y, b4.z, b4.w};
#pragma unroll
            for (int i = 0; i < 8; ++i)
#pragma unroll
                for (int j = 0; j < 4; ++j) acc[i][j] = fmaf(a[i], bb[j], acc[i][j]);
        }
        __syncthreads();
    }
#pragma unroll
    for (int i = 0; i < 8; ++i) {
        float4 v = make_float4(acc[i][0], acc[i][1], acc[i][2], acc[i][3]);
        *reinterpret_cast<float4*>(C + (long long)(bm0 + ty * 8 + i) * N + bn0 + tx * 4) = v;
    }
}

// ---------------- CSR build ----------------
__global__ __launch_bounds__(256) void hist_rows(const int* __restrict__ rows,
                                                 int* __restrict__ cnt) {
    const int e = blockIdx.x * 256 + threadIdx.x;
    atomicAdd(&cnt[rows[e]], 1);
}

__global__ __launch_bounds__(256) void scan8192(const int* __restrict__ cnt,
                                                int* __restrict__ row_start,
                                                int* __restrict__ cursor) {
    __shared__ int ssum[256];
    const int t = threadIdx.x;
    int local[32];
    int s = 0;
#pragma unroll
    for (int j = 0; j < 32; ++j) { local[j] = cnt[t * 32 + j]; s += local[j]; }
    ssum[t] = s;
    __syncthreads();
    for (int off = 1; off < 256; off <<= 1) {
        const int v = ssum[t];
        const int add = (t >= off) ? ssum[t - off] : 0;
        __syncthreads();
        ssum[t] = v + add;
        __syncthreads();
    }
    int run = (t == 0) ? 0 : ssum[t - 1];
#pragma unroll
    for (int j = 0; j < 32; ++j) {
        row_start[t * 32 + j] = run;
        cursor[t * 32 + j] = run;
        run += local[j];
    }
    if (t == 255) row_start[8192] = run;
}

__global__ __launch_bounds__(256) void scatter_edges(const int* __restrict__ rows,
                                                     const int* __restrict__ cols,
                                                     const float* __restrict__ vals,
                                                     int* __restrict__ cursor,
                                                     int* __restrict__ pcol,
                                                     float* __restrict__ pval) {
    const int e = blockIdx.x * 256 + threadIdx.x;
    const int r = rows[e];
    const int pos = atomicAdd(&cursor[r], 1);
    pcol[pos] = cols[e];
    pval[pos] = vals[e];
}

// ---------------- gather SpMM, one wave per row, fused epilogue ----------------
template <int NC, int MODE>
__global__ __launch_bounds__(256) void spmm_gather(const int* __restrict__ row_start,
                                                   const int* __restrict__ pcol,
                                                   const float* __restrict__ pval,
                                                   const float* __restrict__ Y,
                                                   const float* __restrict__ bias,
                                                   float* __restrict__ Out,
                                                   int first) {
    constexpr int PL = NC / 64;
    const int row = (blockIdx.x * 256 + threadIdx.x) >> 6;
    const int lane = threadIdx.x & 63;
    const int s = row_start[row];
    const int e1 = row_start[row + 1];
    const int base = lane * PL;
    float acc[PL];
#pragma unroll
    for (int j = 0; j < PL; ++j) acc[j] = 0.f;

    for (int e = s; e < e1; ++e) {
        const int c = pcol[e];
        const float v = pval[e];
        const float* y = Y + (size_t)c * NC + base;
        if constexpr (PL >= 4) {
#pragma unroll
            for (int q = 0; q < PL / 4; ++q) {
                const float4 a = *reinterpret_cast<const float4*>(y + q * 4);
                acc[q * 4 + 0] = fmaf(v, a.x, acc[q * 4 + 0]);
                acc[q * 4 + 1] = fmaf(v, a.y, acc[q * 4 + 1]);
                acc[q * 4 + 2] = fmaf(v, a.z, acc[q * 4 + 2]);
                acc[q * 4 + 3] = fmaf(v, a.w, acc[q * 4 + 3]);
            }
        } else {
            const float2 a = *reinterpret_cast<const float2*>(y);
            acc[0] = fmaf(v, a.x, acc[0]);
            acc[1] = fmaf(v, a.y, acc[1]);
        }
    }

    float r[PL];
#pragma unroll
    for (int j = 0; j < PL; ++j) {
        float x = lrelu(acc[j] + bias[base + j]);
        if (MODE == 1) x *= 0.25f;
        r[j] = x;
    }
    float* o = Out + (size_t)row * NC + base;
    if constexpr (MODE == 1) {
        if (!first) {
#pragma unroll
            for (int j = 0; j < PL; ++j) r[j] += o[j];
        }
    }
    if constexpr (PL >= 4) {
#pragma unroll
        for (int q = 0; q < PL / 4; ++q)
            *reinterpret_cast<float4*>(o + q * 4) =
                make_float4(r[q * 4], r[q * 4 + 1], r[q * 4 + 2], r[q * 4 + 3]);
    } else {
        *reinterpret_cast<float2*>(o) = make_float2(r[0], r[1]);
    }
}

extern "C" void kernel_launch(void* const* d_in, const int* in_sizes, int n_in,
                              void* d_out, int out_size, void* d_ws, size_t ws_size,
                              hipStream_t stream) {
    const float* X[4]    = {(const float*)d_in[0], (const float*)d_in[1],
                            (const float*)d_in[2], (const float*)d_in[3]};
    const int* rows[4]   = {(const int*)d_in[4], (const int*)d_in[7],
                            (const int*)d_in[10], (const int*)d_in[13]};
    const int* cols[4]   = {(const int*)d_in[5], (const int*)d_in[8],
                            (const int*)d_in[11], (const int*)d_in[14]};
    const float* vals[4] = {(const float*)d_in[6], (const float*)d_in[9],
                            (const float*)d_in[12], (const float*)d_in[15]};
    const float *w1[4], *b1[4], *w2[4], *b2[4];
    for (int b = 0; b < 4; ++b) {
        w1[b] = (const float*)d_in[16 + 4 * b + 0];
        b1[b] = (const float*)d_in[16 + 4 * b + 1];
        w2[b] = (const float*)d_in[16 + 4 * b + 2];
        b2[b] = (const float*)d_in[16 + 4 * b + 3];
    }
    const int din[4] = {4096, 4096, 4096, 1024};
    const int dh[4]  = {512, 512, 512, 256};

    // ---- workspace carve-up (16B-aligned regions) ----
    char* wsc = (char*)d_ws;
    size_t off = 0;
    auto carve = [&](size_t bytes) { void* p = wsc + off; off += (bytes + 15) & ~(size_t)15; return p; };
    float* Y1        = (float*)carve((size_t)N_NODES * 512 * 4);
    float* H1        = (float*)carve((size_t)N_NODES * 512 * 4);
    float* Y2        = (float*)carve((size_t)N_NODES * 128 * 4);
    int*   cnt       = (int*)carve((size_t)N_NODES * 4);
    int*   row_start = (int*)carve((size_t)(N_NODES + 1) * 4);
    int*   cursor    = (int*)carve((size_t)N_NODES * 4);
    int*   pcol      = (int*)carve((size_t)N_EDGES * 4);
    float* pval      = (float*)carve((size_t)N_EDGES * 4);
    unsigned short* Xhi = (unsigned short*)carve((size_t)N_NODES * 4096 * 2);
    unsigned short* Xlo = (unsigned short*)carve((size_t)N_NODES * 4096 * 2);
    unsigned short* WTh = (unsigned short*)carve((size_t)512 * 4096 * 2);
    unsigned short* WTl = (unsigned short*)carve((size_t)512 * 4096 * 2);
    const bool use_mfma = (off <= ws_size);
    float* out = (float*)d_out;

    for (int b = 0; b < 4; ++b) {
        const int K1 = din[b], N1 = dh[b];

        // --- CSR build ---
        hipMemsetAsync(cnt, 0, N_NODES * sizeof(int), stream);
        hist_rows<<<N_EDGES / 256, 256, 0, stream>>>(rows[b], cnt);
        scan8192<<<1, 256, 0, stream>>>(cnt, row_start, cursor);
        scatter_edges<<<N_EDGES / 256, 256, 0, stream>>>(rows[b], cols[b], vals[b],
                                                         cursor, pcol, pval);

        // --- Y1 = X @ W1 ---
        if (use_mfma) {
            const long long n4 = (long long)N_NODES * K1 / 4;
            split_f32<<<(int)(n4 / 256), 256, 0, stream>>>(X[b], Xhi, Xlo, n4);
            dim3 tg(K1 / 32, N1 / 32);
            transpose_split<<<tg, 256, 0, stream>>>(w1[b], WTh, WTl, K1, N1);
            dim3 grid(N_NODES / 64, N1 / 128);
            gemm_split<<<grid, 256, 0, stream>>>(Xhi, Xlo, WTh, WTl, Y1,
                                                 N_NODES, K1, N1);
        } else {
            dim3 grid(N1 / BN, N_NODES / BM);
            gemm_f32<<<grid, 256, 0, stream>>>(X[b], w1[b], Y1, N_NODES, K1, N1);
        }

        // --- H1 = lrelu(spmm(Y1) + b1) ---
        if (N1 == 512)
            spmm_gather<512, 0><<<N_NODES / 4, 256, 0, stream>>>(row_start, pcol, pval,
                                                                 Y1, b1[b], H1, 0);
        else
            spmm_gather<256, 0><<<N_NODES / 4, 256, 0, stream>>>(row_start, pcol, pval,
                                                                 Y1, b1[b], H1, 0);

        // --- Y2 = H1 @ W2 ---
        {
            dim3 grid(128 / BN, N_NODES / BM);
            gemm_f32<<<grid, 256, 0, stream>>>(H1, w2[b], Y2, N_NODES, N1, 128);
        }

        // --- out (+)= 0.25 * lrelu(spmm(Y2) + b2) ---
        spmm_gather<128, 1><<<N_NODES / 4, 256, 0, stream>>>(row_start, pcol, pval,
                                                             Y2, b2[b], out, b == 0);
    }
}

// Round 4
// 1210.986 us; speedup vs baseline: 8.0871x; 1.1589x over previous
//
#include <hip/hip_runtime.h>

#define N_NODES 8192
#define N_EDGES 262144
#define SLOPE 0.25f

typedef __attribute__((ext_vector_type(8))) short bf16x8;
typedef __attribute__((ext_vector_type(4))) float f32x4;

__device__ __forceinline__ float lrelu(float x) { return x >= 0.f ? x : SLOPE * x; }

__device__ __forceinline__ unsigned bf16_rne(float x) {
    unsigned u = __float_as_uint(x);
    return (u + 0x7FFFu + ((u >> 16) & 1u)) >> 16;
}
__device__ __forceinline__ void bsplit(float x, unsigned short& h, unsigned short& l) {
    unsigned hr = bf16_rne(x);
    h = (unsigned short)hr;
    float res = x - __uint_as_float(hr << 16);
    l = (unsigned short)bf16_rne(res);
}

#define GLDS16(g, l)                                                              \
    __builtin_amdgcn_global_load_lds((const __attribute__((address_space(1))) void*)(g), \
                                     (__attribute__((address_space(3))) void*)(l), 16, 0, 0)

// ---------------- split: A f32 -> hi/lo bf16 ----------------
__global__ __launch_bounds__(256) void split_f32(const float* __restrict__ A,
                                                 unsigned short* __restrict__ hi,
                                                 unsigned short* __restrict__ lo,
                                                 long long n4) {
    const long long i = (long long)blockIdx.x * 256 + threadIdx.x;
    if (i >= n4) return;
    const float4 a = reinterpret_cast<const float4*>(A)[i];
    ushort4 h, l;
    bsplit(a.x, h.x, l.x);
    bsplit(a.y, h.y, l.y);
    bsplit(a.z, h.z, l.z);
    bsplit(a.w, h.w, l.w);
    reinterpret_cast<ushort4*>(hi)[i] = h;
    reinterpret_cast<ushort4*>(lo)[i] = l;
}

// ---------------- W [K,N] f32 -> WT hi/lo bf16 [N,K] ----------------
__global__ __launch_bounds__(256) void transpose_split(const float* __restrict__ W,
                                                       unsigned short* __restrict__ Th,
                                                       unsigned short* __restrict__ Tl,
                                                       int K, int N) {
    __shared__ float t[32][33];
    const int k0 = blockIdx.x * 32, n0 = blockIdx.y * 32;
    const int tx = threadIdx.x & 31, ty = threadIdx.x >> 5;
#pragma unroll
    for (int i = 0; i < 32; i += 8)
        t[ty + i][tx] = W[(size_t)(k0 + ty + i) * N + n0 + tx];
    __syncthreads();
#pragma unroll
    for (int i = 0; i < 32; i += 8) {
        const int n = ty + i;
        unsigned short h, l;
        bsplit(t[tx][n], h, l);
        Th[(size_t)(n0 + n) * K + k0 + tx] = h;
        Tl[(size_t)(n0 + n) * K + k0 + tx] = l;
    }
}

// ---------------- split-bf16 MFMA GEMM, double-buffered 2-phase ----------------
// C[M,N] = A @ B; A as Ahi/Alo [M,K] bf16, B as Bhi/Blo [N,K] bf16.
// Tile 64(M) x 128(N) x 32(K); 256 threads = 4 waves (2x2); wave tile 32x64.
// LDS row: 128 B = [hi 64B | lo 64B], XOR-swizzled by ((row&7)<<4).
__global__ __launch_bounds__(256) void gemm_split(const unsigned short* __restrict__ Ahi,
                                                  const unsigned short* __restrict__ Alo,
                                                  const unsigned short* __restrict__ Bhi,
                                                  const unsigned short* __restrict__ Blo,
                                                  float* __restrict__ C,
                                                  int M, int K, int N) {
    __shared__ unsigned short As[2][64 * 64];    // 8 KB x2
    __shared__ unsigned short Bs[2][128 * 64];   // 16 KB x2
    const int tid = threadIdx.x;
    const int w = tid >> 6, lane = tid & 63;
    const int wm = w >> 1, wn = w & 1;
    const int bm0 = blockIdx.x * 64, bn0 = blockIdx.y * 128;

    auto stage = [&](int buf, int k0) {
#pragma unroll
        for (int i = 0; i < 2; ++i) {
            const int o = (w * 2 + i) * 1024 + lane * 16;
            const int row = o >> 7;
            const int c = (o & 127) ^ ((row & 7) << 4);
            const unsigned short* g =
                (c < 64) ? Ahi + (size_t)(bm0 + row) * K + k0 + (c >> 1)
                         : Alo + (size_t)(bm0 + row) * K + k0 + ((c - 64) >> 1);
            GLDS16(g, &As[buf][(w * 2 + i) * 512]);
        }
#pragma unroll
        for (int i = 0; i < 4; ++i) {
            const int o = (w * 4 + i) * 1024 + lane * 16;
            const int row = o >> 7;
            const int c = (o & 127) ^ ((row & 7) << 4);
            const unsigned short* g =
                (c < 64) ? Bhi + (size_t)(bn0 + row) * K + k0 + (c >> 1)
                         : Blo + (size_t)(bn0 + row) * K + k0 + ((c - 64) >> 1);
            GLDS16(g, &Bs[buf][(w * 4 + i) * 512]);
        }
    };

    f32x4 acc[2][4];
#pragma unroll
    for (int mf = 0; mf < 2; ++mf)
#pragma unroll
        for (int nf = 0; nf < 4; ++nf) acc[mf][nf] = (f32x4){0.f, 0.f, 0.f, 0.f};

    stage(0, 0);
    __syncthreads();  // drains vmcnt(0): buf0 ready

    const int nk = K >> 5;
    for (int t = 0; t < nk; ++t) {
        const int cur = t & 1;
        if (t + 1 < nk) stage(cur ^ 1, (t + 1) << 5);  // overlap with compute below

        const int kb = (lane >> 4) * 16;
        bf16x8 ah[2], al[2], bh[4], bl[4];
#pragma unroll
        for (int mf = 0; mf < 2; ++mf) {
            const int r = wm * 32 + mf * 16 + (lane & 15);
            const int sw = (r & 7) << 4;
            ah[mf] = *reinterpret_cast<const bf16x8*>(&As[cur][r * 64 + ((kb ^ sw) >> 1)]);
            al[mf] = *reinterpret_cast<const bf16x8*>(&As[cur][r * 64 + (((64 + kb) ^ sw) >> 1)]);
        }
#pragma unroll
        for (int nf = 0; nf < 4; ++nf) {
            const int r = wn * 64 + nf * 16 + (lane & 15);
            const int sw = (r & 7) << 4;
            bh[nf] = *reinterpret_cast<const bf16x8*>(&Bs[cur][r * 64 + ((kb ^ sw) >> 1)]);
            bl[nf] = *reinterpret_cast<const bf16x8*>(&Bs[cur][r * 64 + (((64 + kb) ^ sw) >> 1)]);
        }
#pragma unroll
        for (int mf = 0; mf < 2; ++mf)
#pragma unroll
            for (int nf = 0; nf < 4; ++nf) {
                acc[mf][nf] = __builtin_amdgcn_mfma_f32_16x16x32_bf16(ah[mf], bh[nf], acc[mf][nf], 0, 0, 0);
                acc[mf][nf] = __builtin_amdgcn_mfma_f32_16x16x32_bf16(ah[mf], bl[nf], acc[mf][nf], 0, 0, 0);
                acc[mf][nf] = __builtin_amdgcn_mfma_f32_16x16x32_bf16(al[mf], bh[nf], acc[mf][nf], 0, 0, 0);
            }
        __syncthreads();  // drains vmcnt(0): next buf ready; LDS safe to overwrite
    }

    const int cr = (lane >> 4) * 4, cc = lane & 15;
#pragma unroll
    for (int mf = 0; mf < 2; ++mf)
#pragma unroll
        for (int nf = 0; nf < 4; ++nf)
#pragma unroll
            for (int j = 0; j < 4; ++j)
                C[(size_t)(bm0 + wm * 32 + mf * 16 + cr + j) * N + bn0 + wn * 64 + nf * 16 + cc] =
                    acc[mf][nf][j];
}

// ---------------- fp32 GEMM (fallback only) ----------------
#define BM 128
#define BN 64
#define BK 16
#define AS_LD 132

__global__ __launch_bounds__(256) void gemm_f32(const float* __restrict__ A,
                                                const float* __restrict__ B,
                                                float* __restrict__ C,
                                                int M, int K, int N) {
    __shared__ float As[BK * AS_LD];
    __shared__ float Bs[BK * BN];
    const int tid = threadIdx.x;
    const int bm0 = blockIdx.y * BM;
    const int bn0 = blockIdx.x * BN;
    const int ty = tid >> 4;
    const int tx = tid & 15;

    float acc[8][4];
#pragma unroll
    for (int i = 0; i < 8; ++i)
#pragma unroll
        for (int j = 0; j < 4; ++j) acc[i][j] = 0.f;

    for (int k0 = 0; k0 < K; k0 += BK) {
#pragma unroll
        for (int it = 0; it < 2; ++it) {
            const int f = tid + it * 256;
            const int r = f >> 2;
            const int c4 = (f & 3) << 2;
            const float4 v = *reinterpret_cast<const float4*>(
                A + (long long)(bm0 + r) * K + k0 + c4);
            As[(c4 + 0) * AS_LD + r] = v.x;
            As[(c4 + 1) * AS_LD + r] = v.y;
            As[(c4 + 2) * AS_LD + r] = v.z;
            As[(c4 + 3) * AS_LD + r] = v.w;
        }
        {
            const int r = tid >> 4;
            const int c4 = (tid & 15) << 2;
            const float4 v = *reinterpret_cast<const float4*>(
                B + (long long)(k0 + r) * N + bn0 + c4);
            *reinterpret_cast<float4*>(&Bs[r * BN + c4]) = v;
        }
        __syncthreads();
#pragma unroll
        for (int k = 0; k < BK; ++k) {
            const float4 a0 = *reinterpret_cast<const float4*>(&As[k * AS_LD + ty * 8]);
            const float4 a1 = *reinterpret_cast<const float4*>(&As[k * AS_LD + ty * 8 + 4]);
            const float4 b4 = *reinterpret_cast<const float4*>(&Bs[k * BN + tx * 4]);
            const float a[8] = {a0.x, a0.y, a0.z, a0.w, a1.x, a1.y, a1.z, a1.w};
            const float bb[4] = {b4.x, b4.y, b4.z, b4.w};
#pragma unroll
            for (int i = 0; i < 8; ++i)
#pragma unroll
                for (int j = 0; j < 4; ++j) acc[i][j] = fmaf(a[i], bb[j], acc[i][j]);
        }
        __syncthreads();
    }
#pragma unroll
    for (int i = 0; i < 8; ++i) {
        float4 v = make_float4(acc[i][0], acc[i][1], acc[i][2], acc[i][3]);
        *reinterpret_cast<float4*>(C + (long long)(bm0 + ty * 8 + i) * N + bn0 + tx * 4) = v;
    }
}

// ---------------- batched CSR build (4 graphs) ----------------
struct GraphPtrs {
    const int* r[4];
    const int* c[4];
    const float* v[4];
};

__global__ __launch_bounds__(256) void hist4(GraphPtrs p, int* __restrict__ cnt4) {
    const int g = blockIdx.y;
    const int e = blockIdx.x * 256 + threadIdx.x;
    atomicAdd(&cnt4[g * N_NODES + p.r[g][e]], 1);
}

__global__ __launch_bounds__(256) void scan4(const int* __restrict__ cnt4,
                                             int* __restrict__ rs4,
                                             int* __restrict__ cur4) {
    const int g = blockIdx.x;
    const int* cnt = cnt4 + g * N_NODES;
    int* row_start = rs4 + (size_t)g * (N_NODES + 1);
    int* cursor = cur4 + g * N_NODES;
    __shared__ int ssum[256];
    const int t = threadIdx.x;
    int local[32];
    int s = 0;
#pragma unroll
    for (int j = 0; j < 32; ++j) { local[j] = cnt[t * 32 + j]; s += local[j]; }
    ssum[t] = s;
    __syncthreads();
    for (int off = 1; off < 256; off <<= 1) {
        const int v = ssum[t];
        const int add = (t >= off) ? ssum[t - off] : 0;
        __syncthreads();
        ssum[t] = v + add;
        __syncthreads();
    }
    int run = (t == 0) ? 0 : ssum[t - 1];
#pragma unroll
    for (int j = 0; j < 32; ++j) {
        row_start[t * 32 + j] = run;
        cursor[t * 32 + j] = run;
        run += local[j];
    }
    if (t == 255) row_start[N_NODES] = run;
}

__global__ __launch_bounds__(256) void scatter4(GraphPtrs p, int* __restrict__ cur4,
                                                int* __restrict__ pcol4,
                                                float* __restrict__ pval4) {
    const int g = blockIdx.y;
    const int e = blockIdx.x * 256 + threadIdx.x;
    const int r = p.r[g][e];
    const int pos = atomicAdd(&cur4[g * N_NODES + r], 1);
    pcol4[(size_t)g * N_EDGES + pos] = p.c[g][e];
    pval4[(size_t)g * N_EDGES + pos] = p.v[g][e];
}

// ---------------- gather SpMM, one wave per row, fused epilogue ----------------
// MODE 0: h = lrelu(spmm + bias); OSPLIT ? write hi/lo bf16 : write f32
// MODE 1: Outf = (first?0:Outf) + 0.25*lrelu(spmm + bias)
template <int NC, int MODE, int OSPLIT>
__global__ __launch_bounds__(256) void spmm_gather(const int* __restrict__ row_start,
                                                   const int* __restrict__ pcol,
                                                   const float* __restrict__ pval,
                                                   const float* __restrict__ Y,
                                                   const float* __restrict__ bias,
                                                   float* __restrict__ Outf,
                                                   unsigned short* __restrict__ Ohi,
                                                   unsigned short* __restrict__ Olo,
                                                   int first) {
    constexpr int PL = NC / 64;
    const int row = (blockIdx.x * 256 + threadIdx.x) >> 6;
    const int lane = threadIdx.x & 63;
    const int s = row_start[row];
    const int e1 = row_start[row + 1];
    const int base = lane * PL;
    float acc[PL];
#pragma unroll
    for (int j = 0; j < PL; ++j) acc[j] = 0.f;

    for (int e = s; e < e1; ++e) {
        const int c = pcol[e];
        const float v = pval[e];
        const float* y = Y + (size_t)c * NC + base;
        if constexpr (PL >= 4) {
#pragma unroll
            for (int q = 0; q < PL / 4; ++q) {
                const float4 a = *reinterpret_cast<const float4*>(y + q * 4);
                acc[q * 4 + 0] = fmaf(v, a.x, acc[q * 4 + 0]);
                acc[q * 4 + 1] = fmaf(v, a.y, acc[q * 4 + 1]);
                acc[q * 4 + 2] = fmaf(v, a.z, acc[q * 4 + 2]);
                acc[q * 4 + 3] = fmaf(v, a.w, acc[q * 4 + 3]);
            }
        } else {
            const float2 a = *reinterpret_cast<const float2*>(y);
            acc[0] = fmaf(v, a.x, acc[0]);
            acc[1] = fmaf(v, a.y, acc[1]);
        }
    }

    float r[PL];
#pragma unroll
    for (int j = 0; j < PL; ++j) {
        float x = lrelu(acc[j] + bias[base + j]);
        if (MODE == 1) x *= 0.25f;
        r[j] = x;
    }

    if constexpr (MODE == 0 && OSPLIT) {
        unsigned short h[PL], l[PL];
#pragma unroll
        for (int j = 0; j < PL; ++j) bsplit(r[j], h[j], l[j]);
        if constexpr (PL == 8) {
            bf16x8 vh, vl;
#pragma unroll
            for (int j = 0; j < 8; ++j) { vh[j] = (short)h[j]; vl[j] = (short)l[j]; }
            *reinterpret_cast<bf16x8*>(Ohi + (size_t)row * NC + base) = vh;
            *reinterpret_cast<bf16x8*>(Olo + (size_t)row * NC + base) = vl;
        } else {
            ushort4 vh = {h[0], h[1], h[2], h[3]};
            ushort4 vl = {l[0], l[1], l[2], l[3]};
            *reinterpret_cast<ushort4*>(Ohi + (size_t)row * NC + base) = vh;
            *reinterpret_cast<ushort4*>(Olo + (size_t)row * NC + base) = vl;
        }
        return;
    }

    float* o = Outf + (size_t)row * NC + base;
    if constexpr (MODE == 1) {
        if (!first) {
#pragma unroll
            for (int j = 0; j < PL; ++j) r[j] += o[j];
        }
    }
    if constexpr (PL >= 4) {
#pragma unroll
        for (int q = 0; q < PL / 4; ++q)
            *reinterpret_cast<float4*>(o + q * 4) =
                make_float4(r[q * 4], r[q * 4 + 1], r[q * 4 + 2], r[q * 4 + 3]);
    } else {
        *reinterpret_cast<float2*>(o) = make_float2(r[0], r[1]);
    }
}

extern "C" void kernel_launch(void* const* d_in, const int* in_sizes, int n_in,
                              void* d_out, int out_size, void* d_ws, size_t ws_size,
                              hipStream_t stream) {
    const float* X[4]    = {(const float*)d_in[0], (const float*)d_in[1],
                            (const float*)d_in[2], (const float*)d_in[3]};
    GraphPtrs gp;
    for (int b = 0; b < 4; ++b) {
        gp.r[b] = (const int*)d_in[4 + 3 * b];
        gp.c[b] = (const int*)d_in[5 + 3 * b];
        gp.v[b] = (const float*)d_in[6 + 3 * b];
    }
    const float *w1[4], *b1[4], *w2[4], *b2[4];
    for (int b = 0; b < 4; ++b) {
        w1[b] = (const float*)d_in[16 + 4 * b + 0];
        b1[b] = (const float*)d_in[16 + 4 * b + 1];
        w2[b] = (const float*)d_in[16 + 4 * b + 2];
        b2[b] = (const float*)d_in[16 + 4 * b + 3];
    }
    const int din[4] = {4096, 4096, 4096, 1024};
    const int dh[4]  = {512, 512, 512, 256};

    // ---- workspace carve-up (16B-aligned) ----
    char* wsc = (char*)d_ws;
    size_t off = 0;
    auto carve = [&](size_t bytes) { void* p = wsc + off; off += (bytes + 15) & ~(size_t)15; return p; };
    float* Y1            = (float*)carve((size_t)N_NODES * 512 * 4);
    unsigned short* H1hi = (unsigned short*)carve((size_t)N_NODES * 512 * 2);
    unsigned short* H1lo = (unsigned short*)carve((size_t)N_NODES * 512 * 2);
    float* H1f32         = (float*)H1hi;  // fallback alias (spans H1hi+H1lo)
    float* Y2            = (float*)carve((size_t)N_NODES * 128 * 4);
    int*   cnt4          = (int*)carve((size_t)4 * N_NODES * 4);
    int*   rs4           = (int*)carve((size_t)4 * (N_NODES + 1) * 4);
    int*   cur4          = (int*)carve((size_t)4 * N_NODES * 4);
    int*   pcol4         = (int*)carve((size_t)4 * N_EDGES * 4);
    float* pval4         = (float*)carve((size_t)4 * N_EDGES * 4);
    unsigned short* Xhi  = (unsigned short*)carve((size_t)N_NODES * 4096 * 2);
    unsigned short* Xlo  = (unsigned short*)carve((size_t)N_NODES * 4096 * 2);
    unsigned short* WTh  = (unsigned short*)carve((size_t)512 * 4096 * 2);
    unsigned short* WTl  = (unsigned short*)carve((size_t)512 * 4096 * 2);
    unsigned short* W2Th = (unsigned short*)carve((size_t)128 * 512 * 2);
    unsigned short* W2Tl = (unsigned short*)carve((size_t)128 * 512 * 2);
    const bool use_mfma = (off <= ws_size);
    float* out = (float*)d_out;

    // ---- batched CSR build for all 4 graphs ----
    hipMemsetAsync(cnt4, 0, (size_t)4 * N_NODES * sizeof(int), stream);
    {
        dim3 g(N_EDGES / 256, 4);
        hist4<<<g, 256, 0, stream>>>(gp, cnt4);
        scan4<<<4, 256, 0, stream>>>(cnt4, rs4, cur4);
        scatter4<<<g, 256, 0, stream>>>(gp, cur4, pcol4, pval4);
    }

    for (int b = 0; b < 4; ++b) {
        const int K1 = din[b], N1 = dh[b];
        const int* row_start = rs4 + (size_t)b * (N_NODES + 1);
        const int* pcol = pcol4 + (size_t)b * N_EDGES;
        const float* pval = pval4 + (size_t)b * N_EDGES;

        if (use_mfma) {
            // --- Y1 = X @ W1 (split-bf16 MFMA) ---
            const long long n4 = (long long)N_NODES * K1 / 4;
            split_f32<<<(int)(n4 / 256), 256, 0, stream>>>(X[b], Xhi, Xlo, n4);
            dim3 tg(K1 / 32, N1 / 32);
            transpose_split<<<tg, 256, 0, stream>>>(w1[b], WTh, WTl, K1, N1);
            dim3 grid(N_NODES / 64, N1 / 128);
            gemm_split<<<grid, 256, 0, stream>>>(Xhi, Xlo, WTh, WTl, Y1, N_NODES, K1, N1);

            // --- H1(split) = lrelu(spmm(Y1) + b1) ---
            if (N1 == 512)
                spmm_gather<512, 0, 1><<<N_NODES / 4, 256, 0, stream>>>(
                    row_start, pcol, pval, Y1, b1[b], nullptr, H1hi, H1lo, 0);
            else
                spmm_gather<256, 0, 1><<<N_NODES / 4, 256, 0, stream>>>(
                    row_start, pcol, pval, Y1, b1[b], nullptr, H1hi, H1lo, 0);

            // --- Y2 = H1 @ W2 (split-bf16 MFMA) ---
            dim3 tg2(N1 / 32, 128 / 32);
            transpose_split<<<tg2, 256, 0, stream>>>(w2[b], W2Th, W2Tl, N1, 128);
            dim3 grid2(N_NODES / 64, 1);
            gemm_split<<<grid2, 256, 0, stream>>>(H1hi, H1lo, W2Th, W2Tl, Y2, N_NODES, N1, 128);
        } else {
            // --- fp32 fallback path ---
            dim3 grid(N1 / BN, N_NODES / BM);
            gemm_f32<<<grid, 256, 0, stream>>>(X[b], w1[b], Y1, N_NODES, K1, N1);
            if (N1 == 512)
                spmm_gather<512, 0, 0><<<N_NODES / 4, 256, 0, stream>>>(
                    row_start, pcol, pval, Y1, b1[b], H1f32, nullptr, nullptr, 0);
            else
                spmm_gather<256, 0, 0><<<N_NODES / 4, 256, 0, stream>>>(
                    row_start, pcol, pval, Y1, b1[b], H1f32, nullptr, nullptr, 0);
            dim3 grid2(128 / BN, N_NODES / BM);
            gemm_f32<<<grid2, 256, 0, stream>>>(H1f32, w2[b], Y2, N_NODES, N1, 128);
        }

        // --- out (+)= 0.25 * lrelu(spmm(Y2) + b2) ---
        spmm_gather<128, 1, 0><<<N_NODES / 4, 256, 0, stream>>>(
            row_start, pcol, pval, Y2, b2[b], out, nullptr, nullptr, b == 0);
    }
}

// Round 5
// 970.605 us; speedup vs baseline: 10.0900x; 1.2477x over previous
//
#include <hip/hip_runtime.h>

#define N_NODES 8192
#define N_EDGES 262144
#define SLOPE 0.25f

typedef __attribute__((ext_vector_type(8))) short bf16x8;
typedef __attribute__((ext_vector_type(4))) float f32x4;

__device__ __forceinline__ float lrelu(float x) { return x >= 0.f ? x : SLOPE * x; }

__device__ __forceinline__ unsigned short bf16_rne(float x) {
    unsigned u = __float_as_uint(x);
    return (unsigned short)((u + 0x7FFFu + ((u >> 16) & 1u)) >> 16);
}
__device__ __forceinline__ void bsplit(float x, unsigned short& h, unsigned short& l) {
    h = bf16_rne(x);
    float res = x - __uint_as_float(((unsigned)h) << 16);
    l = bf16_rne(res);
}

#define GLDS16(g, l)                                                              \
    __builtin_amdgcn_global_load_lds((const __attribute__((address_space(1))) void*)(g), \
                                     (__attribute__((address_space(3))) void*)(l), 16, 0, 0)

// ---------------- batched round: X f32 -> bf16 ----------------
struct RoundB { const float* src[4]; unsigned short* dst[4]; long long n4[4]; };

__global__ __launch_bounds__(256) void round_bf16(RoundB rb) {
    const int z = blockIdx.y;
    const long long i = (long long)blockIdx.x * 256 + threadIdx.x;
    if (i >= rb.n4[z]) return;
    const float4 a = reinterpret_cast<const float4*>(rb.src[z])[i];
    ushort4 h = {bf16_rne(a.x), bf16_rne(a.y), bf16_rne(a.z), bf16_rne(a.w)};
    reinterpret_cast<ushort4*>(rb.dst[z])[i] = h;
}

// ---------------- batched W [K,N] f32 -> WT hi/lo bf16 [N,K] ----------------
struct TransB { const float* W[4]; unsigned short* Th[4]; unsigned short* Tl[4]; int K[4]; int N[4]; };

__global__ __launch_bounds__(256) void tsplit(TransB tb) {
    const int z = blockIdx.z;
    const int K = tb.K[z], N = tb.N[z];
    const int k0 = blockIdx.x * 32, n0 = blockIdx.y * 32;
    if (k0 >= K || n0 >= N) return;
    __shared__ float t[32][33];
    const int tx = threadIdx.x & 31, ty = threadIdx.x >> 5;
    const float* W = tb.W[z];
#pragma unroll
    for (int i = 0; i < 32; i += 8)
        t[ty + i][tx] = W[(size_t)(k0 + ty + i) * N + n0 + tx];
    __syncthreads();
#pragma unroll
    for (int i = 0; i < 32; i += 8) {
        const int n = ty + i;
        unsigned short h, l;
        bsplit(t[tx][n], h, l);
        tb.Th[z][(size_t)(n0 + n) * K + k0 + tx] = h;
        tb.Tl[z][(size_t)(n0 + n) * K + k0 + tx] = l;
    }
}

// ---------------- batched GEMM: C = A(bf16) @ [Bh+Bl]^T, 2 MFMA products ----------------
// Block 64Mx128Nx32K, 4 waves 2x2, wave tile 32x64. A LDS [64][32] bf16 linear (64B rows,
// bank-balanced for the frag pattern). B LDS [128][hi64B|lo64B] XOR-swizzled ((row&7)<<4).
struct GemmB {
    const unsigned short* A[4];   // [M,K] bf16
    const unsigned short* Bh[4];  // [N,K] bf16
    const unsigned short* Bl[4];
    float* C[4];
    int K[4];
    int NT[4];  // N/128 tiles
};

__global__ __launch_bounds__(256) void gemm_bf16s(GemmB gb) {
    // bijective XCD-chunked swizzle (nwg divisible by 8 in all our launches)
    const int nwg = gridDim.x * gridDim.y * gridDim.z;
    int id = (blockIdx.z * gridDim.y + blockIdx.y) * gridDim.x + blockIdx.x;
    const int cpx = nwg >> 3;
    id = (id & 7) * cpx + (id >> 3);
    const int bx = id % gridDim.x;
    const int rest = id / gridDim.x;
    const int by = rest % gridDim.y;
    const int z = rest / gridDim.y;

    const int nt = gb.NT[z];
    if (by >= nt) return;
    const int K = gb.K[z];
    const int N = nt * 128;
    const unsigned short* __restrict__ A = gb.A[z];
    const unsigned short* __restrict__ Bh = gb.Bh[z];
    const unsigned short* __restrict__ Bl = gb.Bl[z];
    float* __restrict__ C = gb.C[z];

    __shared__ unsigned short As[2][64 * 32];    // 4 KB each
    __shared__ unsigned short Bs[2][128 * 64];   // 16 KB each
    const int tid = threadIdx.x;
    const int w = tid >> 6, lane = tid & 63;
    const int wm = w >> 1, wn = w & 1;
    const int bm0 = bx * 64, bn0 = by * 128;

    auto stage = [&](int buf, int k0) {
        {   // A tile: 4 KB, one 16B granule per thread
            const int f = w * 64 + lane;   // granule id
            const int row = f >> 2, g = f & 3;
            GLDS16(A + (size_t)(bm0 + row) * K + k0 + g * 8, &As[buf][w * 512]);
        }
#pragma unroll
        for (int i = 0; i < 4; ++i) {   // B tile: 16 KB
            const int o = (w * 4 + i) * 1024 + lane * 16;
            const int row = o >> 7;
            const int c = (o & 127) ^ ((row & 7) << 4);
            const unsigned short* g =
                (c < 64) ? Bh + (size_t)(bn0 + row) * K + k0 + (c >> 1)
                         : Bl + (size_t)(bn0 + row) * K + k0 + ((c - 64) >> 1);
            GLDS16(g, &Bs[buf][(w * 4 + i) * 512]);
        }
    };

    f32x4 acc[2][4];
#pragma unroll
    for (int mf = 0; mf < 2; ++mf)
#pragma unroll
        for (int nf = 0; nf < 4; ++nf) acc[mf][nf] = (f32x4){0.f, 0.f, 0.f, 0.f};

    stage(0, 0);
    __syncthreads();

    const int nk = K >> 5;
    for (int t = 0; t < nk; ++t) {
        const int cur = t & 1;
        if (t + 1 < nk) stage(cur ^ 1, (t + 1) << 5);

        const int kb = (lane >> 4) * 16;   // byte offset of lane's k-group
        bf16x8 a[2], bh[4], bl[4];
#pragma unroll
        for (int mf = 0; mf < 2; ++mf) {
            const int r = wm * 32 + mf * 16 + (lane & 15);
            a[mf] = *reinterpret_cast<const bf16x8*>(&As[cur][r * 32 + (kb >> 1)]);
        }
#pragma unroll
        for (int nf = 0; nf < 4; ++nf) {
            const int r = wn * 64 + nf * 16 + (lane & 15);
            const int sw = (r & 7) << 4;
            bh[nf] = *reinterpret_cast<const bf16x8*>(&Bs[cur][r * 64 + ((kb ^ sw) >> 1)]);
            bl[nf] = *reinterpret_cast<const bf16x8*>(&Bs[cur][r * 64 + (((64 + kb) ^ sw) >> 1)]);
        }
#pragma unroll
        for (int mf = 0; mf < 2; ++mf)
#pragma unroll
            for (int nf = 0; nf < 4; ++nf) {
                acc[mf][nf] = __builtin_amdgcn_mfma_f32_16x16x32_bf16(a[mf], bh[nf], acc[mf][nf], 0, 0, 0);
                acc[mf][nf] = __builtin_amdgcn_mfma_f32_16x16x32_bf16(a[mf], bl[nf], acc[mf][nf], 0, 0, 0);
            }
        __syncthreads();
    }

    const int cr = (lane >> 4) * 4, cc = lane & 15;
#pragma unroll
    for (int mf = 0; mf < 2; ++mf)
#pragma unroll
        for (int nf = 0; nf < 4; ++nf)
#pragma unroll
            for (int j = 0; j < 4; ++j)
                C[(size_t)(bm0 + wm * 32 + mf * 16 + cr + j) * N + bn0 + wn * 64 + nf * 16 + cc] =
                    acc[mf][nf][j];
}

// ---------------- batched CSR build (4 graphs) ----------------
struct GraphPtrs {
    const int* r[4];
    const int* c[4];
    const float* v[4];
};

__global__ __launch_bounds__(256) void hist4(GraphPtrs p, int* __restrict__ cnt4) {
    const int g = blockIdx.y;
    const int e = blockIdx.x * 256 + threadIdx.x;
    atomicAdd(&cnt4[g * N_NODES + p.r[g][e]], 1);
}

__global__ __launch_bounds__(256) void scan4(const int* __restrict__ cnt4,
                                             int* __restrict__ rs4,
                                             int* __restrict__ cur4) {
    const int g = blockIdx.x;
    const int* cnt = cnt4 + g * N_NODES;
    int* row_start = rs4 + (size_t)g * (N_NODES + 1);
    int* cursor = cur4 + g * N_NODES;
    __shared__ int ssum[256];
    const int t = threadIdx.x;
    int local[32];
    int s = 0;
#pragma unroll
    for (int j = 0; j < 32; ++j) { local[j] = cnt[t * 32 + j]; s += local[j]; }
    ssum[t] = s;
    __syncthreads();
    for (int off = 1; off < 256; off <<= 1) {
        const int v = ssum[t];
        const int add = (t >= off) ? ssum[t - off] : 0;
        __syncthreads();
        ssum[t] = v + add;
        __syncthreads();
    }
    int run = (t == 0) ? 0 : ssum[t - 1];
#pragma unroll
    for (int j = 0; j < 32; ++j) {
        row_start[t * 32 + j] = run;
        cursor[t * 32 + j] = run;
        run += local[j];
    }
    if (t == 255) row_start[N_NODES] = run;
}

__global__ __launch_bounds__(256) void scatter4(GraphPtrs p, int* __restrict__ cur4,
                                                int* __restrict__ pcol4,
                                                float* __restrict__ pval4) {
    const int g = blockIdx.y;
    const int e = blockIdx.x * 256 + threadIdx.x;
    const int r = p.r[g][e];
    const int pos = atomicAdd(&cur4[g * N_NODES + r], 1);
    pcol4[(size_t)g * N_EDGES + pos] = p.c[g][e];
    pval4[(size_t)g * N_EDGES + pos] = p.v[g][e];
}

// ---------------- gather SpMM layer 1 (batched): H = bf16(lrelu(spmm + bias)) ----------------
struct SpmmB {
    const int* rs[4];
    const int* pc[4];
    const float* pv[4];
    const float* Y[4];
    const float* bi[4];
    unsigned short* H[4];
};

template <int NC>
__global__ __launch_bounds__(256) void spmm_h1(SpmmB sb) {
    constexpr int PL = NC / 64;
    const int z = blockIdx.y;
    const int row = (blockIdx.x * 256 + threadIdx.x) >> 6;
    const int lane = threadIdx.x & 63;
    const int* rs = sb.rs[z];
    const int s = rs[row], e1 = rs[row + 1];
    const int* pc = sb.pc[z];
    const float* pv = sb.pv[z];
    const float* Y = sb.Y[z];
    const int base = lane * PL;

    float acc[PL];
#pragma unroll
    for (int j = 0; j < PL; ++j) acc[j] = 0.f;
    for (int e = s; e < e1; ++e) {
        const int c = pc[e];
        const float v = pv[e];
        const float* y = Y + (size_t)c * NC + base;
#pragma unroll
        for (int q = 0; q < PL / 4; ++q) {
            const float4 a = *reinterpret_cast<const float4*>(y + q * 4);
            acc[q * 4 + 0] = fmaf(v, a.x, acc[q * 4 + 0]);
            acc[q * 4 + 1] = fmaf(v, a.y, acc[q * 4 + 1]);
            acc[q * 4 + 2] = fmaf(v, a.z, acc[q * 4 + 2]);
            acc[q * 4 + 3] = fmaf(v, a.w, acc[q * 4 + 3]);
        }
    }
    const float* bi = sb.bi[z];
    unsigned short h[PL];
#pragma unroll
    for (int j = 0; j < PL; ++j) h[j] = bf16_rne(lrelu(acc[j] + bi[base + j]));
    unsigned short* H = sb.H[z] + (size_t)row * NC + base;
    if constexpr (PL == 8) {
        bf16x8 vh;
#pragma unroll
        for (int j = 0; j < 8; ++j) vh[j] = (short)h[j];
        *reinterpret_cast<bf16x8*>(H) = vh;
    } else {
        ushort4 vh = {h[0], h[1], h[2], h[3]};
        *reinterpret_cast<ushort4*>(H) = vh;
    }
}

// ---------------- gather SpMM layer 2: out (+)= 0.25*lrelu(spmm + bias) ----------------
__global__ __launch_bounds__(256) void spmm_out(const int* __restrict__ rs,
                                                const int* __restrict__ pc,
                                                const float* __restrict__ pv,
                                                const float* __restrict__ Y,
                                                const float* __restrict__ bias,
                                                float* __restrict__ out,
                                                int first) {
    const int row = (blockIdx.x * 256 + threadIdx.x) >> 6;
    const int lane = threadIdx.x & 63;
    const int s = rs[row], e1 = rs[row + 1];
    const int base = lane * 2;
    float a0 = 0.f, a1 = 0.f;
    for (int e = s; e < e1; ++e) {
        const float v = pv[e];
        const float2 a = *reinterpret_cast<const float2*>(Y + (size_t)pc[e] * 128 + base);
        a0 = fmaf(v, a.x, a0);
        a1 = fmaf(v, a.y, a1);
    }
    float r0 = 0.25f * lrelu(a0 + bias[base]);
    float r1 = 0.25f * lrelu(a1 + bias[base + 1]);
    float* o = out + (size_t)row * 128 + base;
    if (!first) {
        const float2 p = *reinterpret_cast<const float2*>(o);
        r0 += p.x;
        r1 += p.y;
    }
    *reinterpret_cast<float2*>(o) = make_float2(r0, r1);
}

extern "C" void kernel_launch(void* const* d_in, const int* in_sizes, int n_in,
                              void* d_out, int out_size, void* d_ws, size_t ws_size,
                              hipStream_t stream) {
    const float* X[4] = {(const float*)d_in[0], (const float*)d_in[1],
                         (const float*)d_in[2], (const float*)d_in[3]};
    GraphPtrs gp;
    for (int b = 0; b < 4; ++b) {
        gp.r[b] = (const int*)d_in[4 + 3 * b];
        gp.c[b] = (const int*)d_in[5 + 3 * b];
        gp.v[b] = (const float*)d_in[6 + 3 * b];
    }
    const float *w1[4], *b1[4], *w2[4], *b2[4];
    for (int b = 0; b < 4; ++b) {
        w1[b] = (const float*)d_in[16 + 4 * b + 0];
        b1[b] = (const float*)d_in[16 + 4 * b + 1];
        w2[b] = (const float*)d_in[16 + 4 * b + 2];
        b2[b] = (const float*)d_in[16 + 4 * b + 3];
    }
    const int din[4] = {4096, 4096, 4096, 1024};
    const int dh[4] = {512, 512, 512, 256};
    float* out = (float*)d_out;

    // ---- CSR working set (both tiers) ----
    char* wsc = (char*)d_ws;
    size_t off = 0;
    auto carve = [&](size_t bytes) {
        void* p = wsc + off;
        off += (bytes + 255) & ~(size_t)255;
        return p;
    };
    int* cnt4 = (int*)carve((size_t)4 * N_NODES * 4);
    int* rs4 = (int*)carve((size_t)4 * (N_NODES + 1) * 4);
    int* cur4 = (int*)carve((size_t)4 * N_NODES * 4);
    int* pcol4 = (int*)carve((size_t)4 * N_EDGES * 4);
    float* pval4 = (float*)carve((size_t)4 * N_EDGES * 4);

    // ---- tier-1 carve: everything for all 4 branches resident ----
    size_t tier1_base = off;
    unsigned short *Xbf[4], *W1h[4], *W1l[4], *W2h[4], *W2l[4], *H1[4];
    float *Y1[4], *Y2[4];
    for (int b = 0; b < 4; ++b) Xbf[b] = (unsigned short*)carve((size_t)N_NODES * din[b] * 2);
    for (int b = 0; b < 4; ++b) W1h[b] = (unsigned short*)carve((size_t)dh[b] * din[b] * 2);
    for (int b = 0; b < 4; ++b) W1l[b] = (unsigned short*)carve((size_t)dh[b] * din[b] * 2);
    for (int b = 0; b < 4; ++b) W2h[b] = (unsigned short*)carve((size_t)128 * dh[b] * 2);
    for (int b = 0; b < 4; ++b) W2l[b] = (unsigned short*)carve((size_t)128 * dh[b] * 2);
    for (int b = 0; b < 4; ++b) Y1[b] = (float*)carve((size_t)N_NODES * dh[b] * 4);
    for (int b = 0; b < 4; ++b) H1[b] = (unsigned short*)carve((size_t)N_NODES * dh[b] * 2);
    for (int b = 0; b < 4; ++b) Y2[b] = (float*)carve((size_t)N_NODES * 128 * 4);
    const bool tier1 = (off <= ws_size);
    if (!tier1) {
        // sequential tier: shared single-branch buffers (max sizes)
        off = tier1_base;
        unsigned short* xb = (unsigned short*)carve((size_t)N_NODES * 4096 * 2);
        unsigned short* w1h = (unsigned short*)carve((size_t)512 * 4096 * 2);
        unsigned short* w1l = (unsigned short*)carve((size_t)512 * 4096 * 2);
        unsigned short* w2h = (unsigned short*)carve((size_t)128 * 512 * 2);
        unsigned short* w2l = (unsigned short*)carve((size_t)128 * 512 * 2);
        float* y1 = (float*)carve((size_t)N_NODES * 512 * 4);
        unsigned short* h1 = (unsigned short*)carve((size_t)N_NODES * 512 * 2);
        float* y2 = (float*)carve((size_t)N_NODES * 128 * 4);
        for (int b = 0; b < 4; ++b) {
            Xbf[b] = xb; W1h[b] = w1h; W1l[b] = w1l; W2h[b] = w2h; W2l[b] = w2l;
            Y1[b] = y1; H1[b] = h1; Y2[b] = y2;
        }
    }

    // ---- batched CSR build ----
    hipMemsetAsync(cnt4, 0, (size_t)4 * N_NODES * sizeof(int), stream);
    {
        dim3 g(N_EDGES / 256, 4);
        hist4<<<g, 256, 0, stream>>>(gp, cnt4);
        scan4<<<4, 256, 0, stream>>>(cnt4, rs4, cur4);
        scatter4<<<g, 256, 0, stream>>>(gp, cur4, pcol4, pval4);
    }

    if (tier1) {
        // round all X
        RoundB rb;
        for (int b = 0; b < 4; ++b) {
            rb.src[b] = X[b];
            rb.dst[b] = Xbf[b];
            rb.n4[b] = (long long)N_NODES * din[b] / 4;
        }
        round_bf16<<<dim3(32768, 4), 256, 0, stream>>>(rb);
        // transpose+split W1
        TransB t1;
        for (int b = 0; b < 4; ++b) {
            t1.W[b] = w1[b]; t1.Th[b] = W1h[b]; t1.Tl[b] = W1l[b];
            t1.K[b] = din[b]; t1.N[b] = dh[b];
        }
        tsplit<<<dim3(128, 16, 4), 256, 0, stream>>>(t1);
        // layer-1 GEMM, all branches
        GemmB g1;
        for (int b = 0; b < 4; ++b) {
            g1.A[b] = Xbf[b]; g1.Bh[b] = W1h[b]; g1.Bl[b] = W1l[b];
            g1.C[b] = Y1[b]; g1.K[b] = din[b]; g1.NT[b] = dh[b] / 128;
        }
        gemm_bf16s<<<dim3(128, 4, 4), 256, 0, stream>>>(g1);
        // spmm1, big branches + mic
        SpmmB s1;
        for (int b = 0; b < 4; ++b) {
            s1.rs[b] = rs4 + (size_t)b * (N_NODES + 1);
            s1.pc[b] = pcol4 + (size_t)b * N_EDGES;
            s1.pv[b] = pval4 + (size_t)b * N_EDGES;
            s1.Y[b] = Y1[b]; s1.bi[b] = b1[b]; s1.H[b] = H1[b];
        }
        spmm_h1<512><<<dim3(N_NODES / 4, 3), 256, 0, stream>>>(s1);
        SpmmB s1m = s1;
        s1m.rs[0] = s1.rs[3]; s1m.pc[0] = s1.pc[3]; s1m.pv[0] = s1.pv[3];
        s1m.Y[0] = s1.Y[3]; s1m.bi[0] = s1.bi[3]; s1m.H[0] = s1.H[3];
        spmm_h1<256><<<dim3(N_NODES / 4, 1), 256, 0, stream>>>(s1m);
        // transpose+split W2
        TransB t2;
        for (int b = 0; b < 4; ++b) {
            t2.W[b] = w2[b]; t2.Th[b] = W2h[b]; t2.Tl[b] = W2l[b];
            t2.K[b] = dh[b]; t2.N[b] = 128;
        }
        tsplit<<<dim3(16, 4, 4), 256, 0, stream>>>(t2);
        // layer-2 GEMM, all branches
        GemmB g2;
        for (int b = 0; b < 4; ++b) {
            g2.A[b] = H1[b]; g2.Bh[b] = W2h[b]; g2.Bl[b] = W2l[b];
            g2.C[b] = Y2[b]; g2.K[b] = dh[b]; g2.NT[b] = 1;
        }
        gemm_bf16s<<<dim3(128, 1, 4), 256, 0, stream>>>(g2);
        // spmm2 + output accumulate (sequential: read-modify-write on out)
        for (int b = 0; b < 4; ++b)
            spmm_out<<<N_NODES / 4, 256, 0, stream>>>(
                rs4 + (size_t)b * (N_NODES + 1), pcol4 + (size_t)b * N_EDGES,
                pval4 + (size_t)b * N_EDGES, Y2[b], b2[b], out, b == 0);
    } else {
        // sequential per-branch (same kernels, singleton batches)
        for (int b = 0; b < 4; ++b) {
            RoundB rb;
            rb.src[0] = X[b]; rb.dst[0] = Xbf[b];
            rb.n4[0] = (long long)N_NODES * din[b] / 4;
            round_bf16<<<dim3((unsigned)(rb.n4[0] / 256), 1), 256, 0, stream>>>(rb);
            TransB t1;
            t1.W[0] = w1[b]; t1.Th[0] = W1h[b]; t1.Tl[0] = W1l[b];
            t1.K[0] = din[b]; t1.N[0] = dh[b];
            tsplit<<<dim3(din[b] / 32, dh[b] / 32, 1), 256, 0, stream>>>(t1);
            GemmB g1;
            g1.A[0] = Xbf[b]; g1.Bh[0] = W1h[b]; g1.Bl[0] = W1l[b];
            g1.C[0] = Y1[b]; g1.K[0] = din[b]; g1.NT[0] = dh[b] / 128;
            gemm_bf16s<<<dim3(128, dh[b] / 128, 1), 256, 0, stream>>>(g1);
            SpmmB s1;
            s1.rs[0] = rs4 + (size_t)b * (N_NODES + 1);
            s1.pc[0] = pcol4 + (size_t)b * N_EDGES;
            s1.pv[0] = pval4 + (size_t)b * N_EDGES;
            s1.Y[0] = Y1[b]; s1.bi[0] = b1[b]; s1.H[0] = H1[b];
            if (dh[b] == 512)
                spmm_h1<512><<<dim3(N_NODES / 4, 1), 256, 0, stream>>>(s1);
            else
                spmm_h1<256><<<dim3(N_NODES / 4, 1), 256, 0, stream>>>(s1);
            TransB t2;
            t2.W[0] = w2[b]; t2.Th[0] = W2h[b]; t2.Tl[0] = W2l[b];
            t2.K[0] = dh[b]; t2.N[0] = 128;
            tsplit<<<dim3(dh[b] / 32, 4, 1), 256, 0, stream>>>(t2);
            GemmB g2;
            g2.A[0] = H1[b]; g2.Bh[0] = W2h[b]; g2.Bl[0] = W2l[b];
            g2.C[0] = Y2[b]; g2.K[0] = dh[b]; g2.NT[0] = 1;
            gemm_bf16s<<<dim3(128, 1, 1), 256, 0, stream>>>(g2);
            spmm_out<<<N_NODES / 4, 256, 0, stream>>>(
                rs4 + (size_t)b * (N_NODES + 1), pcol4 + (size_t)b * N_EDGES,
                pval4 + (size_t)b * N_EDGES, Y2[b], b2[b], out, b == 0);
        }
    }
}

// Round 6
// 783.144 us; speedup vs baseline: 12.5052x; 1.2394x over previous
//
#include <hip/hip_runtime.h>

#define N_NODES 8192
#define N_EDGES 262144
#define SLOPE 0.25f

typedef __attribute__((ext_vector_type(8))) short bf16x8;
typedef __attribute__((ext_vector_type(4))) float f32x4;

__device__ __forceinline__ float lrelu(float x) { return x >= 0.f ? x : SLOPE * x; }

__device__ __forceinline__ unsigned short bf16_rne(float x) {
    unsigned u = __float_as_uint(x);
    return (unsigned short)((u + 0x7FFFu + ((u >> 16) & 1u)) >> 16);
}
__device__ __forceinline__ float bf2f(unsigned short h) {
    return __uint_as_float(((unsigned)h) << 16);
}
__device__ __forceinline__ void bsplit(float x, unsigned short& h, unsigned short& l) {
    h = bf16_rne(x);
    l = bf16_rne(x - __uint_as_float(((unsigned)h) << 16));
}

#define GLDS16(g, l)                                                              \
    __builtin_amdgcn_global_load_lds((const __attribute__((address_space(1))) void*)(g), \
                                     (__attribute__((address_space(3))) void*)(l), 16, 0, 0)

// ---------------- batched round: X f32 -> bf16 ----------------
struct RoundB { const float* src[4]; unsigned short* dst[4]; long long n4[4]; };

__global__ __launch_bounds__(256) void round_bf16(RoundB rb) {
    const int z = blockIdx.y;
    const long long i = (long long)blockIdx.x * 256 + threadIdx.x;
    if (i >= rb.n4[z]) return;
    const float4 a = reinterpret_cast<const float4*>(rb.src[z])[i];
    ushort4 h = {bf16_rne(a.x), bf16_rne(a.y), bf16_rne(a.z), bf16_rne(a.w)};
    reinterpret_cast<ushort4*>(rb.dst[z])[i] = h;
}

// ---------------- batched W [K,N] f32 -> WT hi/lo bf16 [N,K] ----------------
struct TransB { const float* W[4]; unsigned short* Th[4]; unsigned short* Tl[4]; int K[4]; int N[4]; };

__global__ __launch_bounds__(256) void tsplit(TransB tb) {
    const int z = blockIdx.z;
    const int K = tb.K[z], N = tb.N[z];
    const int k0 = blockIdx.x * 32, n0 = blockIdx.y * 32;
    if (k0 >= K || n0 >= N) return;
    __shared__ float t[32][33];
    const int tx = threadIdx.x & 31, ty = threadIdx.x >> 5;
    const float* W = tb.W[z];
#pragma unroll
    for (int i = 0; i < 32; i += 8)
        t[ty + i][tx] = W[(size_t)(k0 + ty + i) * N + n0 + tx];
    __syncthreads();
#pragma unroll
    for (int i = 0; i < 32; i += 8) {
        const int n = ty + i;
        unsigned short h, l;
        bsplit(t[tx][n], h, l);
        tb.Th[z][(size_t)(n0 + n) * K + k0 + tx] = h;
        tb.Tl[z][(size_t)(n0 + n) * K + k0 + tx] = l;
    }
}

// ---------------- batched GEMM: C(bf16) = A(bf16) @ [Bh+Bl]^T, 2 MFMA products ----------------
// Block 128Mx128Nx32K, 4 waves (2x2), wave tile 64x64.
// A LDS [128 rows][64 B]: granule (row,kg) at slot kg^((row>>1)&3)  -> 8-bank spread, 2-way free.
// B LDS [128 rows][hi64B|lo64B] XOR-swizzled ((row&7)<<4)           -> 2-way free (verified R3/R4).
struct GemmB {
    const unsigned short* A[4];   // [M,K] bf16
    const unsigned short* Bh[4];  // [N,K] bf16
    const unsigned short* Bl[4];
    unsigned short* C[4];         // [M,N] bf16
    int K[4];
    int NT[4];                    // N/128 tiles
};

__global__ __launch_bounds__(256) void gemm_bf16s(GemmB gb) {
    // bijective XCD-chunked swizzle (nwg divisible by 8 in all launches here)
    const int nwg = gridDim.x * gridDim.y * gridDim.z;
    int id = (blockIdx.z * gridDim.y + blockIdx.y) * gridDim.x + blockIdx.x;
    const int cpx = nwg >> 3;
    id = (id & 7) * cpx + (id >> 3);
    const int bx = id % gridDim.x;
    const int rest = id / gridDim.x;
    const int by = rest % gridDim.y;
    const int z = rest / gridDim.y;

    const int nt = gb.NT[z];
    if (by >= nt) return;
    const int K = gb.K[z];
    const int N = nt * 128;
    const unsigned short* __restrict__ A = gb.A[z];
    const unsigned short* __restrict__ Bh = gb.Bh[z];
    const unsigned short* __restrict__ Bl = gb.Bl[z];
    unsigned short* __restrict__ C = gb.C[z];

    __shared__ unsigned short As[2][128 * 32];   // 8 KB each
    __shared__ unsigned short Bs[2][128 * 64];   // 16 KB each
    const int tid = threadIdx.x;
    const int w = tid >> 6, lane = tid & 63;
    const int wm = w >> 1, wn = w & 1;
    const int bm0 = bx * 128, bn0 = by * 128;

    auto stage = [&](int buf, int k0) {
#pragma unroll
        for (int i = 0; i < 2; ++i) {   // A: 512 granules, 2/thread
            const int f = (w * 2 + i) * 64 + lane;
            const int row = f >> 2, s = f & 3;
            const int kg = s ^ ((row >> 1) & 3);
            GLDS16(A + (size_t)(bm0 + row) * K + k0 + kg * 8, &As[buf][(w * 2 + i) * 512]);
        }
#pragma unroll
        for (int i = 0; i < 4; ++i) {   // B: 1024 granules, 4/thread
            const int o = ((w * 4 + i) * 64 + lane) * 16;
            const int row = o >> 7;
            const int c = (o & 127) ^ ((row & 7) << 4);
            const unsigned short* g =
                (c < 64) ? Bh + (size_t)(bn0 + row) * K + k0 + (c >> 1)
                         : Bl + (size_t)(bn0 + row) * K + k0 + ((c - 64) >> 1);
            GLDS16(g, &Bs[buf][(w * 4 + i) * 512]);
        }
    };

    f32x4 acc[4][4];
#pragma unroll
    for (int mf = 0; mf < 4; ++mf)
#pragma unroll
        for (int nf = 0; nf < 4; ++nf) acc[mf][nf] = (f32x4){0.f, 0.f, 0.f, 0.f};

    stage(0, 0);
    __syncthreads();

    const int nk = K >> 5;
    for (int t = 0; t < nk; ++t) {
        const int cur = t & 1;
        if (t + 1 < nk) stage(cur ^ 1, (t + 1) << 5);

        const int kq = lane >> 4;         // k-group 0..3
        const int kb = kq * 16;           // byte offset
        bf16x8 a[4], bh[4], bl[4];
#pragma unroll
        for (int mf = 0; mf < 4; ++mf) {
            const int r = wm * 64 + mf * 16 + (lane & 15);
            a[mf] = *reinterpret_cast<const bf16x8*>(
                &As[cur][r * 32 + ((kq ^ ((r >> 1) & 3)) << 3)]);
        }
#pragma unroll
        for (int nf = 0; nf < 4; ++nf) {
            const int r = wn * 64 + nf * 16 + (lane & 15);
            const int sw = (r & 7) << 4;
            bh[nf] = *reinterpret_cast<const bf16x8*>(&Bs[cur][r * 64 + ((kb ^ sw) >> 1)]);
            bl[nf] = *reinterpret_cast<const bf16x8*>(&Bs[cur][r * 64 + (((64 + kb) ^ sw) >> 1)]);
        }
#pragma unroll
        for (int mf = 0; mf < 4; ++mf)
#pragma unroll
            for (int nf = 0; nf < 4; ++nf) {
                acc[mf][nf] = __builtin_amdgcn_mfma_f32_16x16x32_bf16(a[mf], bh[nf], acc[mf][nf], 0, 0, 0);
                acc[mf][nf] = __builtin_amdgcn_mfma_f32_16x16x32_bf16(a[mf], bl[nf], acc[mf][nf], 0, 0, 0);
            }
        __syncthreads();
    }

    const int cr = (lane >> 4) * 4, cc = lane & 15;
#pragma unroll
    for (int mf = 0; mf < 4; ++mf)
#pragma unroll
        for (int nf = 0; nf < 4; ++nf)
#pragma unroll
            for (int j = 0; j < 4; ++j)
                C[(size_t)(bm0 + wm * 64 + mf * 16 + cr + j) * N + bn0 + wn * 64 + nf * 16 + cc] =
                    bf16_rne(acc[mf][nf][j]);
}

// ---------------- batched CSR build (4 graphs) ----------------
struct GraphPtrs {
    const int* r[4];
    const int* c[4];
    const float* v[4];
};

__global__ __launch_bounds__(256) void hist4(GraphPtrs p, int* __restrict__ cnt4) {
    const int g = blockIdx.y;
    const int e = blockIdx.x * 256 + threadIdx.x;
    atomicAdd(&cnt4[g * N_NODES + p.r[g][e]], 1);
}

__global__ __launch_bounds__(256) void scan4(const int* __restrict__ cnt4,
                                             int* __restrict__ rs4,
                                             int* __restrict__ cur4) {
    const int g = blockIdx.x;
    const int* cnt = cnt4 + g * N_NODES;
    int* row_start = rs4 + (size_t)g * (N_NODES + 1);
    int* cursor = cur4 + g * N_NODES;
    __shared__ int ssum[256];
    const int t = threadIdx.x;
    int local[32];
    int s = 0;
#pragma unroll
    for (int j = 0; j < 32; ++j) { local[j] = cnt[t * 32 + j]; s += local[j]; }
    ssum[t] = s;
    __syncthreads();
    for (int off = 1; off < 256; off <<= 1) {
        const int v = ssum[t];
        const int add = (t >= off) ? ssum[t - off] : 0;
        __syncthreads();
        ssum[t] = v + add;
        __syncthreads();
    }
    int run = (t == 0) ? 0 : ssum[t - 1];
#pragma unroll
    for (int j = 0; j < 32; ++j) {
        row_start[t * 32 + j] = run;
        cursor[t * 32 + j] = run;
        run += local[j];
    }
    if (t == 255) row_start[N_NODES] = run;
}

__global__ __launch_bounds__(256) void scatter4(GraphPtrs p, int* __restrict__ cur4,
                                                int* __restrict__ pcol4,
                                                float* __restrict__ pval4) {
    const int g = blockIdx.y;
    const int e = blockIdx.x * 256 + threadIdx.x;
    const int r = p.r[g][e];
    const int pos = atomicAdd(&cur4[g * N_NODES + r], 1);
    pcol4[(size_t)g * N_EDGES + pos] = p.c[g][e];
    pval4[(size_t)g * N_EDGES + pos] = p.v[g][e];
}

// ---------------- gather SpMM layer 1 (batched): H = bf16(lrelu(spmm(Y) + bias)) ----------------
struct SpmmB {
    const int* rs[4];
    const int* pc[4];
    const float* pv[4];
    const unsigned short* Y[4];   // bf16
    const float* bi[4];
    unsigned short* H[4];
};

template <int NC>
__global__ __launch_bounds__(256) void spmm_h1(SpmmB sb) {
    constexpr int PL = NC / 64;
    const int z = blockIdx.y;
    const int row = (blockIdx.x * 256 + threadIdx.x) >> 6;
    const int lane = threadIdx.x & 63;
    const int* rs = sb.rs[z];
    const int s = rs[row], e1 = rs[row + 1];
    const int* pc = sb.pc[z];
    const float* pv = sb.pv[z];
    const unsigned short* Y = sb.Y[z];
    const int base = lane * PL;

    float acc[PL];
#pragma unroll
    for (int j = 0; j < PL; ++j) acc[j] = 0.f;
    for (int e = s; e < e1; ++e) {
        const int c = pc[e];
        const float v = pv[e];
        const unsigned short* y = Y + (size_t)c * NC + base;
        if constexpr (PL == 8) {
            const bf16x8 raw = *reinterpret_cast<const bf16x8*>(y);
#pragma unroll
            for (int j = 0; j < 8; ++j)
                acc[j] = fmaf(v, bf2f((unsigned short)raw[j]), acc[j]);
        } else {
            const ushort4 raw = *reinterpret_cast<const ushort4*>(y);
            acc[0] = fmaf(v, bf2f(raw.x), acc[0]);
            acc[1] = fmaf(v, bf2f(raw.y), acc[1]);
            acc[2] = fmaf(v, bf2f(raw.z), acc[2]);
            acc[3] = fmaf(v, bf2f(raw.w), acc[3]);
        }
    }
    const float* bi = sb.bi[z];
    unsigned short* H = sb.H[z] + (size_t)row * NC + base;
    if constexpr (PL == 8) {
        bf16x8 vh;
#pragma unroll
        for (int j = 0; j < 8; ++j) vh[j] = (short)bf16_rne(lrelu(acc[j] + bi[base + j]));
        *reinterpret_cast<bf16x8*>(H) = vh;
    } else {
        ushort4 vh;
        vh.x = bf16_rne(lrelu(acc[0] + bi[base + 0]));
        vh.y = bf16_rne(lrelu(acc[1] + bi[base + 1]));
        vh.z = bf16_rne(lrelu(acc[2] + bi[base + 2]));
        vh.w = bf16_rne(lrelu(acc[3] + bi[base + 3]));
        *reinterpret_cast<ushort4*>(H) = vh;
    }
}

// ---------------- fused output: out[row] = 0.25 * sum_b lrelu(spmm_b(Y2_b)[row] + b2_b) ----------------
struct Out4 { const float* b2[4]; };

__global__ __launch_bounds__(256) void spmm_out4(const int* __restrict__ rs4,
                                                 const int* __restrict__ pc4,
                                                 const float* __restrict__ pv4,
                                                 const unsigned short* __restrict__ Y2all,
                                                 Out4 ob, float* __restrict__ out) {
    const int row = (blockIdx.x * 256 + threadIdx.x) >> 6;
    const int lane = threadIdx.x & 63;
    const int base = lane * 2;
    float r0 = 0.f, r1 = 0.f;
#pragma unroll
    for (int b = 0; b < 4; ++b) {
        const int* rs = rs4 + (size_t)b * (N_NODES + 1);
        const int s = rs[row], e1 = rs[row + 1];
        const int* pc = pc4 + (size_t)b * N_EDGES;
        const float* pv = pv4 + (size_t)b * N_EDGES;
        const unsigned short* Y = Y2all + (size_t)b * N_NODES * 128;
        float a0 = 0.f, a1 = 0.f;
        for (int e = s; e < e1; ++e) {
            const float v = pv[e];
            const unsigned u = *reinterpret_cast<const unsigned*>(Y + (size_t)pc[e] * 128 + base);
            a0 = fmaf(v, __uint_as_float(u << 16), a0);
            a1 = fmaf(v, __uint_as_float(u & 0xFFFF0000u), a1);
        }
        const float* bi = ob.b2[b];
        r0 += lrelu(a0 + bi[base]);
        r1 += lrelu(a1 + bi[base + 1]);
    }
    *reinterpret_cast<float2*>(out + (size_t)row * 128 + base) =
        make_float2(0.25f * r0, 0.25f * r1);
}

// tier-2 single-branch output accumulate
__global__ __launch_bounds__(256) void spmm_out1(const int* __restrict__ rs,
                                                 const int* __restrict__ pc,
                                                 const float* __restrict__ pv,
                                                 const unsigned short* __restrict__ Y,
                                                 const float* __restrict__ bias,
                                                 float* __restrict__ out, int first) {
    const int row = (blockIdx.x * 256 + threadIdx.x) >> 6;
    const int lane = threadIdx.x & 63;
    const int base = lane * 2;
    const int s = rs[row], e1 = rs[row + 1];
    float a0 = 0.f, a1 = 0.f;
    for (int e = s; e < e1; ++e) {
        const float v = pv[e];
        const unsigned u = *reinterpret_cast<const unsigned*>(Y + (size_t)pc[e] * 128 + base);
        a0 = fmaf(v, __uint_as_float(u << 16), a0);
        a1 = fmaf(v, __uint_as_float(u & 0xFFFF0000u), a1);
    }
    float r0 = 0.25f * lrelu(a0 + bias[base]);
    float r1 = 0.25f * lrelu(a1 + bias[base + 1]);
    float* o = out + (size_t)row * 128 + base;
    if (!first) {
        const float2 p = *reinterpret_cast<const float2*>(o);
        r0 += p.x;
        r1 += p.y;
    }
    *reinterpret_cast<float2*>(o) = make_float2(r0, r1);
}

extern "C" void kernel_launch(void* const* d_in, const int* in_sizes, int n_in,
                              void* d_out, int out_size, void* d_ws, size_t ws_size,
                              hipStream_t stream) {
    const float* X[4] = {(const float*)d_in[0], (const float*)d_in[1],
                         (const float*)d_in[2], (const float*)d_in[3]};
    GraphPtrs gp;
    for (int b = 0; b < 4; ++b) {
        gp.r[b] = (const int*)d_in[4 + 3 * b];
        gp.c[b] = (const int*)d_in[5 + 3 * b];
        gp.v[b] = (const float*)d_in[6 + 3 * b];
    }
    const float *w1[4], *b1[4], *w2[4], *b2[4];
    for (int b = 0; b < 4; ++b) {
        w1[b] = (const float*)d_in[16 + 4 * b + 0];
        b1[b] = (const float*)d_in[16 + 4 * b + 1];
        w2[b] = (const float*)d_in[16 + 4 * b + 2];
        b2[b] = (const float*)d_in[16 + 4 * b + 3];
    }
    const int din[4] = {4096, 4096, 4096, 1024};
    const int dh[4] = {512, 512, 512, 256};
    float* out = (float*)d_out;

    char* wsc = (char*)d_ws;
    size_t off = 0;
    auto carve = [&](size_t bytes) {
        void* p = wsc + off;
        off += (bytes + 255) & ~(size_t)255;
        return p;
    };
    int* cnt4 = (int*)carve((size_t)4 * N_NODES * 4);
    int* rs4 = (int*)carve((size_t)4 * (N_NODES + 1) * 4);
    int* cur4 = (int*)carve((size_t)4 * N_NODES * 4);
    int* pcol4 = (int*)carve((size_t)4 * N_EDGES * 4);
    float* pval4 = (float*)carve((size_t)4 * N_EDGES * 4);

    // tier-1 carve: all 4 branches resident (bf16 intermediates)
    size_t tier1_base = off;
    unsigned short *Xbf[4], *W1h[4], *W1l[4], *W2h[4], *W2l[4], *Y1[4], *H1[4];
    for (int b = 0; b < 4; ++b) Xbf[b] = (unsigned short*)carve((size_t)N_NODES * din[b] * 2);
    for (int b = 0; b < 4; ++b) W1h[b] = (unsigned short*)carve((size_t)dh[b] * din[b] * 2);
    for (int b = 0; b < 4; ++b) W1l[b] = (unsigned short*)carve((size_t)dh[b] * din[b] * 2);
    for (int b = 0; b < 4; ++b) W2h[b] = (unsigned short*)carve((size_t)128 * dh[b] * 2);
    for (int b = 0; b < 4; ++b) W2l[b] = (unsigned short*)carve((size_t)128 * dh[b] * 2);
    for (int b = 0; b < 4; ++b) Y1[b] = (unsigned short*)carve((size_t)N_NODES * dh[b] * 2);
    for (int b = 0; b < 4; ++b) H1[b] = (unsigned short*)carve((size_t)N_NODES * dh[b] * 2);
    unsigned short* Y2all = (unsigned short*)carve((size_t)4 * N_NODES * 128 * 2);
    const bool tier1 = (off <= ws_size);
    unsigned short* Y2s[4];
    if (tier1) {
        for (int b = 0; b < 4; ++b) Y2s[b] = Y2all + (size_t)b * N_NODES * 128;
    } else {
        off = tier1_base;
        unsigned short* xb = (unsigned short*)carve((size_t)N_NODES * 4096 * 2);
        unsigned short* w1h = (unsigned short*)carve((size_t)512 * 4096 * 2);
        unsigned short* w1l = (unsigned short*)carve((size_t)512 * 4096 * 2);
        unsigned short* w2h = (unsigned short*)carve((size_t)128 * 512 * 2);
        unsigned short* w2l = (unsigned short*)carve((size_t)128 * 512 * 2);
        unsigned short* y1 = (unsigned short*)carve((size_t)N_NODES * 512 * 2);
        unsigned short* h1 = (unsigned short*)carve((size_t)N_NODES * 512 * 2);
        unsigned short* y2 = (unsigned short*)carve((size_t)N_NODES * 128 * 2);
        for (int b = 0; b < 4; ++b) {
            Xbf[b] = xb; W1h[b] = w1h; W1l[b] = w1l; W2h[b] = w2h; W2l[b] = w2l;
            Y1[b] = y1; H1[b] = h1; Y2s[b] = y2;
        }
    }

    // ---- batched CSR build ----
    hipMemsetAsync(cnt4, 0, (size_t)4 * N_NODES * sizeof(int), stream);
    {
        dim3 g(N_EDGES / 256, 4);
        hist4<<<g, 256, 0, stream>>>(gp, cnt4);
        scan4<<<4, 256, 0, stream>>>(cnt4, rs4, cur4);
        scatter4<<<g, 256, 0, stream>>>(gp, cur4, pcol4, pval4);
    }

    if (tier1) {
        RoundB rb;
        for (int b = 0; b < 4; ++b) {
            rb.src[b] = X[b];
            rb.dst[b] = Xbf[b];
            rb.n4[b] = (long long)N_NODES * din[b] / 4;
        }
        round_bf16<<<dim3(32768, 4), 256, 0, stream>>>(rb);

        TransB t1;
        for (int b = 0; b < 4; ++b) {
            t1.W[b] = w1[b]; t1.Th[b] = W1h[b]; t1.Tl[b] = W1l[b];
            t1.K[b] = din[b]; t1.N[b] = dh[b];
        }
        tsplit<<<dim3(128, 16, 4), 256, 0, stream>>>(t1);

        GemmB g1;
        for (int b = 0; b < 4; ++b) {
            g1.A[b] = Xbf[b]; g1.Bh[b] = W1h[b]; g1.Bl[b] = W1l[b];
            g1.C[b] = Y1[b]; g1.K[b] = din[b]; g1.NT[b] = dh[b] / 128;
        }
        gemm_bf16s<<<dim3(64, 4, 4), 256, 0, stream>>>(g1);

        SpmmB s1;
        for (int b = 0; b < 4; ++b) {
            s1.rs[b] = rs4 + (size_t)b * (N_NODES + 1);
            s1.pc[b] = pcol4 + (size_t)b * N_EDGES;
            s1.pv[b] = pval4 + (size_t)b * N_EDGES;
            s1.Y[b] = Y1[b]; s1.bi[b] = b1[b]; s1.H[b] = H1[b];
        }
        spmm_h1<512><<<dim3(N_NODES / 4, 3), 256, 0, stream>>>(s1);
        SpmmB s1m = s1;
        s1m.rs[0] = s1.rs[3]; s1m.pc[0] = s1.pc[3]; s1m.pv[0] = s1.pv[3];
        s1m.Y[0] = s1.Y[3]; s1m.bi[0] = s1.bi[3]; s1m.H[0] = s1.H[3];
        spmm_h1<256><<<dim3(N_NODES / 4, 1), 256, 0, stream>>>(s1m);

        TransB t2;
        for (int b = 0; b < 4; ++b) {
            t2.W[b] = w2[b]; t2.Th[b] = W2h[b]; t2.Tl[b] = W2l[b];
            t2.K[b] = dh[b]; t2.N[b] = 128;
        }
        tsplit<<<dim3(16, 4, 4), 256, 0, stream>>>(t2);

        GemmB g2;
        for (int b = 0; b < 4; ++b) {
            g2.A[b] = H1[b]; g2.Bh[b] = W2h[b]; g2.Bl[b] = W2l[b];
            g2.C[b] = Y2s[b]; g2.K[b] = dh[b]; g2.NT[b] = 1;
        }
        gemm_bf16s<<<dim3(64, 1, 4), 256, 0, stream>>>(g2);

        Out4 ob;
        for (int b = 0; b < 4; ++b) ob.b2[b] = b2[b];
        spmm_out4<<<N_NODES / 4, 256, 0, stream>>>(rs4, pcol4, pval4, Y2all, ob, out);
    } else {
        for (int b = 0; b < 4; ++b) {
            RoundB rb;
            rb.src[0] = X[b]; rb.dst[0] = Xbf[b];
            rb.n4[0] = (long long)N_NODES * din[b] / 4;
            round_bf16<<<dim3((unsigned)(rb.n4[0] / 256), 1), 256, 0, stream>>>(rb);
            TransB t1;
            t1.W[0] = w1[b]; t1.Th[0] = W1h[b]; t1.Tl[0] = W1l[b];
            t1.K[0] = din[b]; t1.N[0] = dh[b];
            tsplit<<<dim3(din[b] / 32, dh[b] / 32, 1), 256, 0, stream>>>(t1);
            GemmB g1;
            g1.A[0] = Xbf[b]; g1.Bh[0] = W1h[b]; g1.Bl[0] = W1l[b];
            g1.C[0] = Y1[b]; g1.K[0] = din[b]; g1.NT[0] = dh[b] / 128;
            gemm_bf16s<<<dim3(64, dh[b] / 128, 1), 256, 0, stream>>>(g1);
            SpmmB s1;
            s1.rs[0] = rs4 + (size_t)b * (N_NODES + 1);
            s1.pc[0] = pcol4 + (size_t)b * N_EDGES;
            s1.pv[0] = pval4 + (size_t)b * N_EDGES;
            s1.Y[0] = Y1[b]; s1.bi[0] = b1[b]; s1.H[0] = H1[b];
            if (dh[b] == 512)
                spmm_h1<512><<<dim3(N_NODES / 4, 1), 256, 0, stream>>>(s1);
            else
                spmm_h1<256><<<dim3(N_NODES / 4, 1), 256, 0, stream>>>(s1);
            TransB t2;
            t2.W[0] = w2[b]; t2.Th[0] = W2h[b]; t2.Tl[0] = W2l[b];
            t2.K[0] = dh[b]; t2.N[0] = 128;
            tsplit<<<dim3(dh[b] / 32, 4, 1), 256, 0, stream>>>(t2);
            GemmB g2;
            g2.A[0] = H1[b]; g2.Bh[0] = W2h[b]; g2.Bl[0] = W2l[b];
            g2.C[0] = Y2s[b]; g2.K[0] = dh[b]; g2.NT[0] = 1;
            gemm_bf16s<<<dim3(64, 1, 1), 256, 0, stream>>>(g2);
            spmm_out1<<<N_NODES / 4, 256, 0, stream>>>(
                rs4 + (size_t)b * (N_NODES + 1), pcol4 + (size_t)b * N_EDGES,
                pval4 + (size_t)b * N_EDGES, Y2s[b], b2[b], out, b == 0);
        }
    }
}

// Round 7
// 691.754 us; speedup vs baseline: 14.1573x; 1.1321x over previous
//
#include <hip/hip_runtime.h>

#define N_NODES 8192
#define N_EDGES 262144
#define SLOPE 0.25f

typedef __attribute__((ext_vector_type(8))) short bf16x8;
typedef __attribute__((ext_vector_type(4))) float f32x4;

__device__ __forceinline__ float lrelu(float x) { return x >= 0.f ? x : SLOPE * x; }

__device__ __forceinline__ unsigned short bf16_rne(float x) {
    unsigned u = __float_as_uint(x);
    return (unsigned short)((u + 0x7FFFu + ((u >> 16) & 1u)) >> 16);
}
__device__ __forceinline__ float bf2f(unsigned short h) {
    return __uint_as_float(((unsigned)h) << 16);
}

#define GLDS16(g, l)                                                              \
    __builtin_amdgcn_global_load_lds((const __attribute__((address_space(1))) void*)(g), \
                                     (__attribute__((address_space(3))) void*)(l), 16, 0, 0)

// ---------------- batched round: X f32 -> bf16 ----------------
struct RoundB { const float* src[4]; unsigned short* dst[4]; long long n4[4]; };

__global__ __launch_bounds__(256) void round_bf16(RoundB rb) {
    const int z = blockIdx.y;
    const long long i = (long long)blockIdx.x * 256 + threadIdx.x;
    if (i >= rb.n4[z]) return;
    const float4 a = reinterpret_cast<const float4*>(rb.src[z])[i];
    ushort4 h = {bf16_rne(a.x), bf16_rne(a.y), bf16_rne(a.z), bf16_rne(a.w)};
    reinterpret_cast<ushort4*>(rb.dst[z])[i] = h;
}

// ---------------- batched W [K,N] f32 -> WT bf16 [N,K] (transpose + round) ----------------
struct TransB { const float* W[4]; unsigned short* Th[4]; int K[4]; int N[4]; };

__global__ __launch_bounds__(256) void tsplit(TransB tb) {
    const int z = blockIdx.z;
    const int K = tb.K[z], N = tb.N[z];
    const int k0 = blockIdx.x * 32, n0 = blockIdx.y * 32;
    if (k0 >= K || n0 >= N) return;
    __shared__ float t[32][33];
    const int tx = threadIdx.x & 31, ty = threadIdx.x >> 5;
    const float* W = tb.W[z];
#pragma unroll
    for (int i = 0; i < 32; i += 8)
        t[ty + i][tx] = W[(size_t)(k0 + ty + i) * N + n0 + tx];
    __syncthreads();
#pragma unroll
    for (int i = 0; i < 32; i += 8) {
        const int n = ty + i;
        tb.Th[z][(size_t)(n0 + n) * K + k0 + tx] = bf16_rne(t[tx][n]);
    }
}

// ---------------- batched GEMM: C(bf16) = A(bf16) @ B(bf16)^T ----------------
// Block 128Mx128Nx32K, 4 waves (2x2), wave tile 64x64, 16 MFMA/K-step.
// A and B LDS: [128 rows][64 B]; granule (row,kg) stored at slot kg^((row>>1)&3)
// (8-bank spread on frag reads, 2-way residual = free; verified R6: 0 conflicts).
// K-loop: counted s_waitcnt vmcnt(4) + raw s_barrier -> prefetch stays in flight.
struct GemmB {
    const unsigned short* A[4];   // [M,K] bf16
    const unsigned short* Bh[4];  // [N,K] bf16
    unsigned short* C[4];         // [M,N] bf16
    int K[4];
    int NT[4];                    // N/128 tiles
};

__global__ __launch_bounds__(256) void gemm_bf16s(GemmB gb) {
    // bijective XCD-chunked swizzle (nwg divisible by 8 in all launches here)
    const int nwg = gridDim.x * gridDim.y * gridDim.z;
    int id = (blockIdx.z * gridDim.y + blockIdx.y) * gridDim.x + blockIdx.x;
    const int cpx = nwg >> 3;
    id = (id & 7) * cpx + (id >> 3);
    // by (N-tile) fastest: consecutive work-ids share the same A M-panel (L2 reuse)
    const int by = id % gridDim.y;
    const int rest = id / gridDim.y;
    const int bx = rest % gridDim.x;
    const int z = rest / gridDim.x;

    const int nt = gb.NT[z];
    if (by >= nt) return;
    const int K = gb.K[z];
    const int N = nt * 128;
    const unsigned short* __restrict__ A = gb.A[z];
    const unsigned short* __restrict__ Bh = gb.Bh[z];
    unsigned short* __restrict__ C = gb.C[z];

    __shared__ unsigned short As[2][128 * 32];   // 8 KB each
    __shared__ unsigned short Bs[2][128 * 32];   // 8 KB each
    const int tid = threadIdx.x;
    const int w = tid >> 6, lane = tid & 63;
    const int wm = w >> 1, wn = w & 1;
    const int bm0 = bx * 128, bn0 = by * 128;

    auto stage = [&](int buf, int k0) {
#pragma unroll
        for (int i = 0; i < 2; ++i) {   // A: 512 granules, 2/thread
            const int f = (w * 2 + i) * 64 + lane;
            const int row = f >> 2, s = f & 3;
            const int kg = s ^ ((row >> 1) & 3);
            GLDS16(A + (size_t)(bm0 + row) * K + k0 + kg * 8, &As[buf][(w * 2 + i) * 512]);
        }
#pragma unroll
        for (int i = 0; i < 2; ++i) {   // B: 512 granules, 2/thread
            const int f = (w * 2 + i) * 64 + lane;
            const int row = f >> 2, s = f & 3;
            const int kg = s ^ ((row >> 1) & 3);
            GLDS16(Bh + (size_t)(bn0 + row) * K + k0 + kg * 8, &Bs[buf][(w * 2 + i) * 512]);
        }
    };

    f32x4 acc[4][4];
#pragma unroll
    for (int mf = 0; mf < 4; ++mf)
#pragma unroll
        for (int nf = 0; nf < 4; ++nf) acc[mf][nf] = (f32x4){0.f, 0.f, 0.f, 0.f};

    stage(0, 0);

    const int nk = K >> 5;
    for (int t = 0; t < nk; ++t) {
        const int cur = t & 1;
        if (t + 1 < nk) {
            stage(cur ^ 1, (t + 1) << 5);                 // 4 loads in flight
            asm volatile("s_waitcnt vmcnt(4)" ::: "memory");  // wait only for cur's loads
        } else {
            asm volatile("s_waitcnt vmcnt(0)" ::: "memory");
        }
        __builtin_amdgcn_s_barrier();        // raw: does NOT drain the prefetch
        __builtin_amdgcn_sched_barrier(0);   // keep ds_reads below the barrier

        const int kq = lane >> 4;
        bf16x8 a[4], b[4];
#pragma unroll
        for (int mf = 0; mf < 4; ++mf) {
            const int r = wm * 64 + mf * 16 + (lane & 15);
            a[mf] = *reinterpret_cast<const bf16x8*>(
                &As[cur][r * 32 + ((kq ^ ((r >> 1) & 3)) << 3)]);
        }
#pragma unroll
        for (int nf = 0; nf < 4; ++nf) {
            const int r = wn * 64 + nf * 16 + (lane & 15);
            b[nf] = *reinterpret_cast<const bf16x8*>(
                &Bs[cur][r * 32 + ((kq ^ ((r >> 1) & 3)) << 3)]);
        }
#pragma unroll
        for (int mf = 0; mf < 4; ++mf)
#pragma unroll
            for (int nf = 0; nf < 4; ++nf)
                acc[mf][nf] = __builtin_amdgcn_mfma_f32_16x16x32_bf16(a[mf], b[nf], acc[mf][nf], 0, 0, 0);

        __builtin_amdgcn_s_barrier();        // all waves done reading cur before overwrite
    }

    const int cr = (lane >> 4) * 4, cc = lane & 15;
#pragma unroll
    for (int mf = 0; mf < 4; ++mf)
#pragma unroll
        for (int nf = 0; nf < 4; ++nf)
#pragma unroll
            for (int j = 0; j < 4; ++j)
                C[(size_t)(bm0 + wm * 64 + mf * 16 + cr + j) * N + bn0 + wn * 64 + nf * 16 + cc] =
                    bf16_rne(acc[mf][nf][j]);
}

// ---------------- batched CSR build (4 graphs) ----------------
struct GraphPtrs {
    const int* r[4];
    const int* c[4];
    const float* v[4];
};

__global__ __launch_bounds__(256) void hist4(GraphPtrs p, int* __restrict__ cnt4) {
    const int g = blockIdx.y;
    const int e = blockIdx.x * 256 + threadIdx.x;
    atomicAdd(&cnt4[g * N_NODES + p.r[g][e]], 1);
}

__global__ __launch_bounds__(256) void scan4(const int* __restrict__ cnt4,
                                             int* __restrict__ rs4,
                                             int* __restrict__ cur4) {
    const int g = blockIdx.x;
    const int* cnt = cnt4 + g * N_NODES;
    int* row_start = rs4 + (size_t)g * (N_NODES + 1);
    int* cursor = cur4 + g * N_NODES;
    __shared__ int ssum[256];
    const int t = threadIdx.x;
    int local[32];
    int s = 0;
#pragma unroll
    for (int j = 0; j < 32; ++j) { local[j] = cnt[t * 32 + j]; s += local[j]; }
    ssum[t] = s;
    __syncthreads();
    for (int off = 1; off < 256; off <<= 1) {
        const int v = ssum[t];
        const int add = (t >= off) ? ssum[t - off] : 0;
        __syncthreads();
        ssum[t] = v + add;
        __syncthreads();
    }
    int run = (t == 0) ? 0 : ssum[t - 1];
#pragma unroll
    for (int j = 0; j < 32; ++j) {
        row_start[t * 32 + j] = run;
        cursor[t * 32 + j] = run;
        run += local[j];
    }
    if (t == 255) row_start[N_NODES] = run;
}

__global__ __launch_bounds__(256) void scatter4(GraphPtrs p, int* __restrict__ cur4,
                                                int* __restrict__ pcol4,
                                                float* __restrict__ pval4) {
    const int g = blockIdx.y;
    const int e = blockIdx.x * 256 + threadIdx.x;
    const int r = p.r[g][e];
    const int pos = atomicAdd(&cur4[g * N_NODES + r], 1);
    pcol4[(size_t)g * N_EDGES + pos] = p.c[g][e];
    pval4[(size_t)g * N_EDGES + pos] = p.v[g][e];
}

// ---------------- gather SpMM layer 1 (batched): H = bf16(lrelu(spmm(Y) + bias)) ----------------
struct SpmmB {
    const int* rs[4];
    const int* pc[4];
    const float* pv[4];
    const unsigned short* Y[4];   // bf16
    const float* bi[4];
    unsigned short* H[4];
};

template <int NC>
__global__ __launch_bounds__(256) void spmm_h1(SpmmB sb) {
    constexpr int PL = NC / 64;
    const int z = blockIdx.y;
    const int row = (blockIdx.x * 256 + threadIdx.x) >> 6;
    const int lane = threadIdx.x & 63;
    const int* rs = sb.rs[z];
    const int s = rs[row], e1 = rs[row + 1];
    const int* pc = sb.pc[z];
    const float* pv = sb.pv[z];
    const unsigned short* Y = sb.Y[z];
    const int base = lane * PL;

    float acc[PL];
#pragma unroll
    for (int j = 0; j < PL; ++j) acc[j] = 0.f;
    for (int e = s; e < e1; ++e) {
        const int c = pc[e];
        const float v = pv[e];
        const unsigned short* y = Y + (size_t)c * NC + base;
        if constexpr (PL == 8) {
            const bf16x8 raw = *reinterpret_cast<const bf16x8*>(y);
#pragma unroll
            for (int j = 0; j < 8; ++j)
                acc[j] = fmaf(v, bf2f((unsigned short)raw[j]), acc[j]);
        } else {
            const ushort4 raw = *reinterpret_cast<const ushort4*>(y);
            acc[0] = fmaf(v, bf2f(raw.x), acc[0]);
            acc[1] = fmaf(v, bf2f(raw.y), acc[1]);
            acc[2] = fmaf(v, bf2f(raw.z), acc[2]);
            acc[3] = fmaf(v, bf2f(raw.w), acc[3]);
        }
    }
    const float* bi = sb.bi[z];
    unsigned short* H = sb.H[z] + (size_t)row * NC + base;
    if constexpr (PL == 8) {
        bf16x8 vh;
#pragma unroll
        for (int j = 0; j < 8; ++j) vh[j] = (short)bf16_rne(lrelu(acc[j] + bi[base + j]));
        *reinterpret_cast<bf16x8*>(H) = vh;
    } else {
        ushort4 vh;
        vh.x = bf16_rne(lrelu(acc[0] + bi[base + 0]));
        vh.y = bf16_rne(lrelu(acc[1] + bi[base + 1]));
        vh.z = bf16_rne(lrelu(acc[2] + bi[base + 2]));
        vh.w = bf16_rne(lrelu(acc[3] + bi[base + 3]));
        *reinterpret_cast<ushort4*>(H) = vh;
    }
}

// ---------------- fused output: out[row] = 0.25 * sum_b lrelu(spmm_b(Y2_b)[row] + b2_b) ----------------
struct Out4 { const float* b2[4]; };

__global__ __launch_bounds__(256) void spmm_out4(const int* __restrict__ rs4,
                                                 const int* __restrict__ pc4,
                                                 const float* __restrict__ pv4,
                                                 const unsigned short* __restrict__ Y2all,
                                                 Out4 ob, float* __restrict__ out) {
    const int row = (blockIdx.x * 256 + threadIdx.x) >> 6;
    const int lane = threadIdx.x & 63;
    const int base = lane * 2;
    float r0 = 0.f, r1 = 0.f;
#pragma unroll
    for (int b = 0; b < 4; ++b) {
        const int* rs = rs4 + (size_t)b * (N_NODES + 1);
        const int s = rs[row], e1 = rs[row + 1];
        const int* pc = pc4 + (size_t)b * N_EDGES;
        const float* pv = pv4 + (size_t)b * N_EDGES;
        const unsigned short* Y = Y2all + (size_t)b * N_NODES * 128;
        float a0 = 0.f, a1 = 0.f;
        for (int e = s; e < e1; ++e) {
            const float v = pv[e];
            const unsigned u = *reinterpret_cast<const unsigned*>(Y + (size_t)pc[e] * 128 + base);
            a0 = fmaf(v, __uint_as_float(u << 16), a0);
            a1 = fmaf(v, __uint_as_float(u & 0xFFFF0000u), a1);
        }
        const float* bi = ob.b2[b];
        r0 += lrelu(a0 + bi[base]);
        r1 += lrelu(a1 + bi[base + 1]);
    }
    *reinterpret_cast<float2*>(out + (size_t)row * 128 + base) =
        make_float2(0.25f * r0, 0.25f * r1);
}

// tier-2 single-branch output accumulate
__global__ __launch_bounds__(256) void spmm_out1(const int* __restrict__ rs,
                                                 const int* __restrict__ pc,
                                                 const float* __restrict__ pv,
                                                 const unsigned short* __restrict__ Y,
                                                 const float* __restrict__ bias,
                                                 float* __restrict__ out, int first) {
    const int row = (blockIdx.x * 256 + threadIdx.x) >> 6;
    const int lane = threadIdx.x & 63;
    const int base = lane * 2;
    const int s = rs[row], e1 = rs[row + 1];
    float a0 = 0.f, a1 = 0.f;
    for (int e = s; e < e1; ++e) {
        const float v = pv[e];
        const unsigned u = *reinterpret_cast<const unsigned*>(Y + (size_t)pc[e] * 128 + base);
        a0 = fmaf(v, __uint_as_float(u << 16), a0);
        a1 = fmaf(v, __uint_as_float(u & 0xFFFF0000u), a1);
    }
    float r0 = 0.25f * lrelu(a0 + bias[base]);
    float r1 = 0.25f * lrelu(a1 + bias[base + 1]);
    float* o = out + (size_t)row * 128 + base;
    if (!first) {
        const float2 p = *reinterpret_cast<const float2*>(o);
        r0 += p.x;
        r1 += p.y;
    }
    *reinterpret_cast<float2*>(o) = make_float2(r0, r1);
}

extern "C" void kernel_launch(void* const* d_in, const int* in_sizes, int n_in,
                              void* d_out, int out_size, void* d_ws, size_t ws_size,
                              hipStream_t stream) {
    const float* X[4] = {(const float*)d_in[0], (const float*)d_in[1],
                         (const float*)d_in[2], (const float*)d_in[3]};
    GraphPtrs gp;
    for (int b = 0; b < 4; ++b) {
        gp.r[b] = (const int*)d_in[4 + 3 * b];
        gp.c[b] = (const int*)d_in[5 + 3 * b];
        gp.v[b] = (const float*)d_in[6 + 3 * b];
    }
    const float *w1[4], *b1[4], *w2[4], *b2[4];
    for (int b = 0; b < 4; ++b) {
        w1[b] = (const float*)d_in[16 + 4 * b + 0];
        b1[b] = (const float*)d_in[16 + 4 * b + 1];
        w2[b] = (const float*)d_in[16 + 4 * b + 2];
        b2[b] = (const float*)d_in[16 + 4 * b + 3];
    }
    const int din[4] = {4096, 4096, 4096, 1024};
    const int dh[4] = {512, 512, 512, 256};
    float* out = (float*)d_out;

    char* wsc = (char*)d_ws;
    size_t off = 0;
    auto carve = [&](size_t bytes) {
        void* p = wsc + off;
        off += (bytes + 255) & ~(size_t)255;
        return p;
    };
    int* cnt4 = (int*)carve((size_t)4 * N_NODES * 4);
    int* rs4 = (int*)carve((size_t)4 * (N_NODES + 1) * 4);
    int* cur4 = (int*)carve((size_t)4 * N_NODES * 4);
    int* pcol4 = (int*)carve((size_t)4 * N_EDGES * 4);
    float* pval4 = (float*)carve((size_t)4 * N_EDGES * 4);

    // tier-1 carve: all 4 branches resident (bf16 everywhere)
    size_t tier1_base = off;
    unsigned short *Xbf[4], *W1h[4], *W2h[4], *Y1[4], *H1[4];
    for (int b = 0; b < 4; ++b) Xbf[b] = (unsigned short*)carve((size_t)N_NODES * din[b] * 2);
    for (int b = 0; b < 4; ++b) W1h[b] = (unsigned short*)carve((size_t)dh[b] * din[b] * 2);
    for (int b = 0; b < 4; ++b) W2h[b] = (unsigned short*)carve((size_t)128 * dh[b] * 2);
    for (int b = 0; b < 4; ++b) Y1[b] = (unsigned short*)carve((size_t)N_NODES * dh[b] * 2);
    for (int b = 0; b < 4; ++b) H1[b] = (unsigned short*)carve((size_t)N_NODES * dh[b] * 2);
    unsigned short* Y2all = (unsigned short*)carve((size_t)4 * N_NODES * 128 * 2);
    const bool tier1 = (off <= ws_size);
    unsigned short* Y2s[4];
    if (tier1) {
        for (int b = 0; b < 4; ++b) Y2s[b] = Y2all + (size_t)b * N_NODES * 128;
    } else {
        off = tier1_base;
        unsigned short* xb = (unsigned short*)carve((size_t)N_NODES * 4096 * 2);
        unsigned short* w1h = (unsigned short*)carve((size_t)512 * 4096 * 2);
        unsigned short* w2h = (unsigned short*)carve((size_t)128 * 512 * 2);
        unsigned short* y1 = (unsigned short*)carve((size_t)N_NODES * 512 * 2);
        unsigned short* h1 = (unsigned short*)carve((size_t)N_NODES * 512 * 2);
        unsigned short* y2 = (unsigned short*)carve((size_t)N_NODES * 128 * 2);
        for (int b = 0; b < 4; ++b) {
            Xbf[b] = xb; W1h[b] = w1h; W2h[b] = w2h;
            Y1[b] = y1; H1[b] = h1; Y2s[b] = y2;
        }
    }

    // ---- batched CSR build ----
    hipMemsetAsync(cnt4, 0, (size_t)4 * N_NODES * sizeof(int), stream);
    {
        dim3 g(N_EDGES / 256, 4);
        hist4<<<g, 256, 0, stream>>>(gp, cnt4);
        scan4<<<4, 256, 0, stream>>>(cnt4, rs4, cur4);
        scatter4<<<g, 256, 0, stream>>>(gp, cur4, pcol4, pval4);
    }

    if (tier1) {
        RoundB rb;
        for (int b = 0; b < 4; ++b) {
            rb.src[b] = X[b];
            rb.dst[b] = Xbf[b];
            rb.n4[b] = (long long)N_NODES * din[b] / 4;
        }
        round_bf16<<<dim3(32768, 4), 256, 0, stream>>>(rb);

        TransB t1;
        for (int b = 0; b < 4; ++b) {
            t1.W[b] = w1[b]; t1.Th[b] = W1h[b];
            t1.K[b] = din[b]; t1.N[b] = dh[b];
        }
        tsplit<<<dim3(128, 16, 4), 256, 0, stream>>>(t1);

        GemmB g1;
        for (int b = 0; b < 4; ++b) {
            g1.A[b] = Xbf[b]; g1.Bh[b] = W1h[b];
            g1.C[b] = Y1[b]; g1.K[b] = din[b]; g1.NT[b] = dh[b] / 128;
        }
        gemm_bf16s<<<dim3(64, 4, 4), 256, 0, stream>>>(g1);

        SpmmB s1;
        for (int b = 0; b < 4; ++b) {
            s1.rs[b] = rs4 + (size_t)b * (N_NODES + 1);
            s1.pc[b] = pcol4 + (size_t)b * N_EDGES;
            s1.pv[b] = pval4 + (size_t)b * N_EDGES;
            s1.Y[b] = Y1[b]; s1.bi[b] = b1[b]; s1.H[b] = H1[b];
        }
        spmm_h1<512><<<dim3(N_NODES / 4, 3), 256, 0, stream>>>(s1);
        SpmmB s1m = s1;
        s1m.rs[0] = s1.rs[3]; s1m.pc[0] = s1.pc[3]; s1m.pv[0] = s1.pv[3];
        s1m.Y[0] = s1.Y[3]; s1m.bi[0] = s1.bi[3]; s1m.H[0] = s1.H[3];
        spmm_h1<256><<<dim3(N_NODES / 4, 1), 256, 0, stream>>>(s1m);

        TransB t2;
        for (int b = 0; b < 4; ++b) {
            t2.W[b] = w2[b]; t2.Th[b] = W2h[b];
            t2.K[b] = dh[b]; t2.N[b] = 128;
        }
        tsplit<<<dim3(16, 4, 4), 256, 0, stream>>>(t2);

        GemmB g2;
        for (int b = 0; b < 4; ++b) {
            g2.A[b] = H1[b]; g2.Bh[b] = W2h[b];
            g2.C[b] = Y2s[b]; g2.K[b] = dh[b]; g2.NT[b] = 1;
        }
        gemm_bf16s<<<dim3(64, 1, 4), 256, 0, stream>>>(g2);

        Out4 ob;
        for (int b = 0; b < 4; ++b) ob.b2[b] = b2[b];
        spmm_out4<<<N_NODES / 4, 256, 0, stream>>>(rs4, pcol4, pval4, Y2all, ob, out);
    } else {
        for (int b = 0; b < 4; ++b) {
            RoundB rb;
            rb.src[0] = X[b]; rb.dst[0] = Xbf[b];
            rb.n4[0] = (long long)N_NODES * din[b] / 4;
            round_bf16<<<dim3((unsigned)(rb.n4[0] / 256), 1), 256, 0, stream>>>(rb);
            TransB t1;
            t1.W[0] = w1[b]; t1.Th[0] = W1h[b];
            t1.K[0] = din[b]; t1.N[0] = dh[b];
            tsplit<<<dim3(din[b] / 32, dh[b] / 32, 1), 256, 0, stream>>>(t1);
            GemmB g1;
            g1.A[0] = Xbf[b]; g1.Bh[0] = W1h[b];
            g1.C[0] = Y1[b]; g1.K[0] = din[b]; g1.NT[0] = dh[b] / 128;
            gemm_bf16s<<<dim3(64, dh[b] / 128, 1), 256, 0, stream>>>(g1);
            SpmmB s1;
            s1.rs[0] = rs4 + (size_t)b * (N_NODES + 1);
            s1.pc[0] = pcol4 + (size_t)b * N_EDGES;
            s1.pv[0] = pval4 + (size_t)b * N_EDGES;
            s1.Y[0] = Y1[b]; s1.bi[0] = b1[b]; s1.H[0] = H1[b];
            if (dh[b] == 512)
                spmm_h1<512><<<dim3(N_NODES / 4, 1), 256, 0, stream>>>(s1);
            else
                spmm_h1<256><<<dim3(N_NODES / 4, 1), 256, 0, stream>>>(s1);
            TransB t2;
            t2.W[0] = w2[b]; t2.Th[0] = W2h[b];
            t2.K[0] = dh[b]; t2.N[0] = 128;
            tsplit<<<dim3(dh[b] / 32, 4, 1), 256, 0, stream>>>(t2);
            GemmB g2;
            g2.A[0] = H1[b]; g2.Bh[0] = W2h[b];
            g2.C[0] = Y2s[b]; g2.K[0] = dh[b]; g2.NT[0] = 1;
            gemm_bf16s<<<dim3(64, 1, 1), 256, 0, stream>>>(g2);
            spmm_out1<<<N_NODES / 4, 256, 0, stream>>>(
                rs4 + (size_t)b * (N_NODES + 1), pcol4 + (size_t)b * N_EDGES,
                pval4 + (size_t)b * N_EDGES, Y2s[b], b2[b], out, b == 0);
        }
    }
}

// Round 9
// 621.300 us; speedup vs baseline: 15.7628x; 1.1134x over previous
//
#include <hip/hip_runtime.h>

#define N_NODES 8192
#define N_EDGES 262144
#define SLOPE 0.25f

typedef __attribute__((ext_vector_type(8))) short bf16x8;
typedef __attribute__((ext_vector_type(4))) float f32x4;

__device__ __forceinline__ float lrelu(float x) { return x >= 0.f ? x : SLOPE * x; }

__device__ __forceinline__ unsigned short bf16_rne(float x) {
    unsigned u = __float_as_uint(x);
    return (unsigned short)((u + 0x7FFFu + ((u >> 16) & 1u)) >> 16);
}
__device__ __forceinline__ float bf2f(unsigned short h) {
    return __uint_as_float(((unsigned)h) << 16);
}

#define GLDS16(g, l)                                                              \
    __builtin_amdgcn_global_load_lds((const __attribute__((address_space(1))) void*)(g), \
                                     (__attribute__((address_space(3))) void*)(l), 16, 0, 0)

// ---------------- batched round: X f32 -> bf16 ----------------
struct RoundB { const float* src[4]; unsigned short* dst[4]; long long n4[4]; };

__global__ __launch_bounds__(256) void round_bf16(RoundB rb) {
    const int z = blockIdx.y;
    const long long i = (long long)blockIdx.x * 256 + threadIdx.x;
    if (i >= rb.n4[z]) return;
    const float4 a = reinterpret_cast<const float4*>(rb.src[z])[i];
    ushort4 h = {bf16_rne(a.x), bf16_rne(a.y), bf16_rne(a.z), bf16_rne(a.w)};
    reinterpret_cast<ushort4*>(rb.dst[z])[i] = h;
}

// ---------------- batched W [K,N] f32 -> WT bf16 [N,K] (transpose + round) ----------------
struct TransB { const float* W[4]; unsigned short* Th[4]; int K[4]; int N[4]; };

__global__ __launch_bounds__(256) void tsplit(TransB tb) {
    const int z = blockIdx.z;
    const int K = tb.K[z], N = tb.N[z];
    const int k0 = blockIdx.x * 32, n0 = blockIdx.y * 32;
    if (k0 >= K || n0 >= N) return;
    __shared__ float t[32][33];
    const int tx = threadIdx.x & 31, ty = threadIdx.x >> 5;
    const float* W = tb.W[z];
#pragma unroll
    for (int i = 0; i < 32; i += 8)
        t[ty + i][tx] = W[(size_t)(k0 + ty + i) * N + n0 + tx];
    __syncthreads();
#pragma unroll
    for (int i = 0; i < 32; i += 8) {
        const int n = ty + i;
        tb.Th[z][(size_t)(n0 + n) * K + k0 + tx] = bf16_rne(t[tx][n]);
    }
}

// ---------------- batched GEMM: C(bf16) = A(bf16) @ B(bf16)^T ----------------
// template NF: wave-tile = 64(M) x NF*16(N); block = 128(M) x NF*32(N); 4 waves (2x2).
// Depth-2 prefetch, 3 LDS buffers, counted vmcnt (never 0 in main loop).
// A/B LDS: [rows][64 B]; granule (row,kg) at slot kg^((row>>1)&3) (0 conflicts, verified R6/R7).
struct GemmB {
    const unsigned short* A[4];   // [M,K] bf16
    const unsigned short* Bh[4];  // [N,K] bf16
    unsigned short* C[4];         // [M,N] bf16
    int K[4];
    int NT[4];                    // N / (NF*32) tiles
};

template <int NF>
__global__ __launch_bounds__(256, 2) void gemm_bf16s(GemmB gb) {
    constexpr int BN = NF * 32;             // block N span
    constexpr int BROWS = BN;               // B rows staged
    constexpr int BGR_PER_THREAD = NF / 2;  // B granules per thread per stage
    // bijective XCD-chunked swizzle (nwg divisible by 8 in all launches here)
    const int nwg = gridDim.x * gridDim.y * gridDim.z;
    int id = (blockIdx.z * gridDim.y + blockIdx.y) * gridDim.x + blockIdx.x;
    const int cpx = nwg >> 3;
    id = (id & 7) * cpx + (id >> 3);
    // by (N-tile) fastest: consecutive work-ids share the same A M-panel (L2 reuse)
    const int by = id % gridDim.y;
    const int rest = id / gridDim.y;
    const int bx = rest % gridDim.x;
    const int z = rest / gridDim.x;

    const int nt = gb.NT[z];
    if (by >= nt) return;
    const int K = gb.K[z];
    const int N = nt * BN;
    const unsigned short* __restrict__ A = gb.A[z];
    const unsigned short* __restrict__ Bh = gb.Bh[z];
    unsigned short* __restrict__ C = gb.C[z];

    __shared__ unsigned short As[3 * 128 * 32];      // 3 x 8 KB
    __shared__ unsigned short Bs[3 * BROWS * 32];    // 3 x (BN*64B)
    const int tid = threadIdx.x;
    const int w = tid >> 6, lane = tid & 63;
    const int wm = w >> 1, wn = w & 1;
    const int bm0 = bx * 128, bn0 = by * BN;

    auto stage = [&](int buf, int kt) {
        const int k0 = kt << 5;
#pragma unroll
        for (int i = 0; i < 2; ++i) {   // A: 512 granules, 2/thread
            const int f = (w * 2 + i) * 64 + lane;
            const int row = f >> 2, s = f & 3;
            const int kg = s ^ ((row >> 1) & 3);
            GLDS16(A + (size_t)(bm0 + row) * K + k0 + kg * 8,
                   &As[buf * 4096 + (w * 2 + i) * 512]);
        }
#pragma unroll
        for (int i = 0; i < BGR_PER_THREAD; ++i) {   // B: BN*4 granules
            const int f = (w * BGR_PER_THREAD + i) * 64 + lane;
            const int row = f >> 2, s = f & 3;
            const int kg = s ^ ((row >> 1) & 3);
            GLDS16(Bh + (size_t)(bn0 + row) * K + k0 + kg * 8,
                   &Bs[buf * (BROWS * 32) + (w * BGR_PER_THREAD + i) * 512]);
        }
    };

    f32x4 acc[4][NF];
#pragma unroll
    for (int mf = 0; mf < 4; ++mf)
#pragma unroll
        for (int nf = 0; nf < NF; ++nf) acc[mf][nf] = (f32x4){0.f, 0.f, 0.f, 0.f};

    const int nk = K >> 5;   // >= 8 in all uses
    stage(0, 0);
    stage(1, 1);

    int c0 = 0, c1 = 1, c2 = 2;
    for (int t = 0; t < nk; ++t) {
        if (t + 2 < nk) {
            stage(c2, t + 2);
            if constexpr (NF == 8)
                asm volatile("s_waitcnt vmcnt(12)" ::: "memory");
            else
                asm volatile("s_waitcnt vmcnt(8)" ::: "memory");
        } else if (t + 1 < nk) {
            if constexpr (NF == 8)
                asm volatile("s_waitcnt vmcnt(6)" ::: "memory");
            else
                asm volatile("s_waitcnt vmcnt(4)" ::: "memory");
        } else {
            asm volatile("s_waitcnt vmcnt(0)" ::: "memory");
        }
        __builtin_amdgcn_s_barrier();        // all waves' t-loads arrived
        __builtin_amdgcn_sched_barrier(0);   // keep ds_reads below the barrier

        const int kq = lane >> 4;
        bf16x8 a[4], b[NF];
#pragma unroll
        for (int mf = 0; mf < 4; ++mf) {
            const int r = wm * 64 + mf * 16 + (lane & 15);
            a[mf] = *reinterpret_cast<const bf16x8*>(
                &As[c0 * 4096 + r * 32 + ((kq ^ ((r >> 1) & 3)) << 3)]);
        }
#pragma unroll
        for (int nf = 0; nf < NF; ++nf) {
            const int r = wn * (NF * 16) + nf * 16 + (lane & 15);
            b[nf] = *reinterpret_cast<const bf16x8*>(
                &Bs[c0 * (BROWS * 32) + r * 32 + ((kq ^ ((r >> 1) & 3)) << 3)]);
        }
        __builtin_amdgcn_s_setprio(1);
#pragma unroll
        for (int mf = 0; mf < 4; ++mf)
#pragma unroll
            for (int nf = 0; nf < NF; ++nf)
                acc[mf][nf] = __builtin_amdgcn_mfma_f32_16x16x32_bf16(a[mf], b[nf], acc[mf][nf], 0, 0, 0);
        __builtin_amdgcn_s_setprio(0);

        __builtin_amdgcn_s_barrier();        // reads of buffer c0 done before its reuse
        const int tmp = c0; c0 = c1; c1 = c2; c2 = tmp;
    }

    const int cr = (lane >> 4) * 4, cc = lane & 15;
#pragma unroll
    for (int mf = 0; mf < 4; ++mf)
#pragma unroll
        for (int nf = 0; nf < NF; ++nf)
#pragma unroll
            for (int j = 0; j < 4; ++j)
                C[(size_t)(bm0 + wm * 64 + mf * 16 + cr + j) * N + bn0 + wn * (NF * 16) + nf * 16 + cc] =
                    bf16_rne(acc[mf][nf][j]);
}

// ---------------- batched CSR build (4 graphs) ----------------
struct GraphPtrs {
    const int* r[4];
    const int* c[4];
    const float* v[4];
};

__global__ __launch_bounds__(256) void hist4(GraphPtrs p, int* __restrict__ cnt4) {
    const int g = blockIdx.y;
    const int e = blockIdx.x * 256 + threadIdx.x;
    atomicAdd(&cnt4[g * N_NODES + p.r[g][e]], 1);
}

__global__ __launch_bounds__(256) void scan4(const int* __restrict__ cnt4,
                                             int* __restrict__ rs4,
                                             int* __restrict__ cur4) {
    const int g = blockIdx.x;
    const int* cnt = cnt4 + g * N_NODES;
    int* row_start = rs4 + (size_t)g * (N_NODES + 1);
    int* cursor = cur4 + g * N_NODES;
    __shared__ int ssum[256];
    const int t = threadIdx.x;
    int local[32];
    int s = 0;
#pragma unroll
    for (int j = 0; j < 32; ++j) { local[j] = cnt[t * 32 + j]; s += local[j]; }
    ssum[t] = s;
    __syncthreads();
    for (int off = 1; off < 256; off <<= 1) {
        const int v = ssum[t];
        const int add = (t >= off) ? ssum[t - off] : 0;
        __syncthreads();
        ssum[t] = v + add;
        __syncthreads();
    }
    int run = (t == 0) ? 0 : ssum[t - 1];
#pragma unroll
    for (int j = 0; j < 32; ++j) {
        row_start[t * 32 + j] = run;
        cursor[t * 32 + j] = run;
        run += local[j];
    }
    if (t == 255) row_start[N_NODES] = run;
}

__global__ __launch_bounds__(256) void scatter4(GraphPtrs p, int* __restrict__ cur4,
                                                int* __restrict__ pcol4,
                                                float* __restrict__ pval4) {
    const int g = blockIdx.y;
    const int e = blockIdx.x * 256 + threadIdx.x;
    const int r = p.r[g][e];
    const int pos = atomicAdd(&cur4[g * N_NODES + r], 1);
    pcol4[(size_t)g * N_EDGES + pos] = p.c[g][e];
    pval4[(size_t)g * N_EDGES + pos] = p.v[g][e];
}

// ---------------- gather SpMM layer 1 (batched): H = bf16(lrelu(spmm(Y) + bias)) ----------------
struct SpmmB {
    const int* rs[4];
    const int* pc[4];
    const float* pv[4];
    const unsigned short* Y[4];   // bf16
    const float* bi[4];
    unsigned short* H[4];
};

template <int NC>
__global__ __launch_bounds__(256) void spmm_h1(SpmmB sb) {
    constexpr int PL = NC / 64;
    const int z = blockIdx.y;
    const int row = (blockIdx.x * 256 + threadIdx.x) >> 6;
    const int lane = threadIdx.x & 63;
    const int* rs = sb.rs[z];
    const int s = rs[row], e1 = rs[row + 1];
    const int* pc = sb.pc[z];
    const float* pv = sb.pv[z];
    const unsigned short* Y = sb.Y[z];
    const int base = lane * PL;

    float acc[PL];
#pragma unroll
    for (int j = 0; j < PL; ++j) acc[j] = 0.f;
    for (int e = s; e < e1; ++e) {
        const int c = pc[e];
        const float v = pv[e];
        const unsigned short* y = Y + (size_t)c * NC + base;
        if constexpr (PL == 8) {
            const bf16x8 raw = *reinterpret_cast<const bf16x8*>(y);
#pragma unroll
            for (int j = 0; j < 8; ++j)
                acc[j] = fmaf(v, bf2f((unsigned short)raw[j]), acc[j]);
        } else {
            const ushort4 raw = *reinterpret_cast<const ushort4*>(y);
            acc[0] = fmaf(v, bf2f(raw.x), acc[0]);
            acc[1] = fmaf(v, bf2f(raw.y), acc[1]);
            acc[2] = fmaf(v, bf2f(raw.z), acc[2]);
            acc[3] = fmaf(v, bf2f(raw.w), acc[3]);
        }
    }
    const float* bi = sb.bi[z];
    unsigned short* H = sb.H[z] + (size_t)row * NC + base;
    if constexpr (PL == 8) {
        bf16x8 vh;
#pragma unroll
        for (int j = 0; j < 8; ++j) vh[j] = (short)bf16_rne(lrelu(acc[j] + bi[base + j]));
        *reinterpret_cast<bf16x8*>(H) = vh;
    } else {
        ushort4 vh;
        vh.x = bf16_rne(lrelu(acc[0] + bi[base + 0]));
        vh.y = bf16_rne(lrelu(acc[1] + bi[base + 1]));
        vh.z = bf16_rne(lrelu(acc[2] + bi[base + 2]));
        vh.w = bf16_rne(lrelu(acc[3] + bi[base + 3]));
        *reinterpret_cast<ushort4*>(H) = vh;
    }
}

// ---------------- fused output: out[row] = 0.25 * sum_b lrelu(spmm_b(Y2_b)[row] + b2_b) ----------------
struct Out4 { const float* b2[4]; };

__global__ __launch_bounds__(256) void spmm_out4(const int* __restrict__ rs4,
                                                 const int* __restrict__ pc4,
                                                 const float* __restrict__ pv4,
                                                 const unsigned short* __restrict__ Y2all,
                                                 Out4 ob, float* __restrict__ out) {
    const int row = (blockIdx.x * 256 + threadIdx.x) >> 6;
    const int lane = threadIdx.x & 63;
    const int base = lane * 2;
    float r0 = 0.f, r1 = 0.f;
#pragma unroll
    for (int b = 0; b < 4; ++b) {
        const int* rs = rs4 + (size_t)b * (N_NODES + 1);
        const int s = rs[row], e1 = rs[row + 1];
        const int* pc = pc4 + (size_t)b * N_EDGES;
        const float* pv = pv4 + (size_t)b * N_EDGES;
        const unsigned short* Y = Y2all + (size_t)b * N_NODES * 128;
        float a0 = 0.f, a1 = 0.f;
        for (int e = s; e < e1; ++e) {
            const float v = pv[e];
            const unsigned u = *reinterpret_cast<const unsigned*>(Y + (size_t)pc[e] * 128 + base);
            a0 = fmaf(v, __uint_as_float(u << 16), a0);
            a1 = fmaf(v, __uint_as_float(u & 0xFFFF0000u), a1);
        }
        const float* bi = ob.b2[b];
        r0 += lrelu(a0 + bi[base]);
        r1 += lrelu(a1 + bi[base + 1]);
    }
    *reinterpret_cast<float2*>(out + (size_t)row * 128 + base) =
        make_float2(0.25f * r0, 0.25f * r1);
}

// tier-2 single-branch output accumulate
__global__ __launch_bounds__(256) void spmm_out1(const int* __restrict__ rs,
                                                 const int* __restrict__ pc,
                                                 const float* __restrict__ pv,
                                                 const unsigned short* __restrict__ Y,
                                                 const float* __restrict__ bias,
                                                 float* __restrict__ out, int first) {
    const int row = (blockIdx.x * 256 + threadIdx.x) >> 6;
    const int lane = threadIdx.x & 63;
    const int base = lane * 2;
    const int s = rs[row], e1 = rs[row + 1];
    float a0 = 0.f, a1 = 0.f;
    for (int e = s; e < e1; ++e) {
        const float v = pv[e];
        const unsigned u = *reinterpret_cast<const unsigned*>(Y + (size_t)pc[e] * 128 + base);
        a0 = fmaf(v, __uint_as_float(u << 16), a0);
        a1 = fmaf(v, __uint_as_float(u & 0xFFFF0000u), a1);
    }
    float r0 = 0.25f * lrelu(a0 + bias[base]);
    float r1 = 0.25f * lrelu(a1 + bias[base + 1]);
    float* o = out + (size_t)row * 128 + base;
    if (!first) {
        const float2 p = *reinterpret_cast<const float2*>(o);
        r0 += p.x;
        r1 += p.y;
    }
    *reinterpret_cast<float2*>(o) = make_float2(r0, r1);
}

extern "C" void kernel_launch(void* const* d_in, const int* in_sizes, int n_in,
                              void* d_out, int out_size, void* d_ws, size_t ws_size,
                              hipStream_t stream) {
    const float* X[4] = {(const float*)d_in[0], (const float*)d_in[1],
                         (const float*)d_in[2], (const float*)d_in[3]};
    GraphPtrs gp;
    for (int b = 0; b < 4; ++b) {
        gp.r[b] = (const int*)d_in[4 + 3 * b];
        gp.c[b] = (const int*)d_in[5 + 3 * b];
        gp.v[b] = (const float*)d_in[6 + 3 * b];
    }
    const float *w1[4], *b1[4], *w2[4], *b2[4];
    for (int b = 0; b < 4; ++b) {
        w1[b] = (const float*)d_in[16 + 4 * b + 0];
        b1[b] = (const float*)d_in[16 + 4 * b + 1];
        w2[b] = (const float*)d_in[16 + 4 * b + 2];
        b2[b] = (const float*)d_in[16 + 4 * b + 3];
    }
    const int din[4] = {4096, 4096, 4096, 1024};
    const int dh[4] = {512, 512, 512, 256};
    float* out = (float*)d_out;

    char* wsc = (char*)d_ws;
    size_t off = 0;
    auto carve = [&](size_t bytes) {
        void* p = wsc + off;
        off += (bytes + 255) & ~(size_t)255;
        return p;
    };
    int* cnt4 = (int*)carve((size_t)4 * N_NODES * 4);
    int* rs4 = (int*)carve((size_t)4 * (N_NODES + 1) * 4);
    int* cur4 = (int*)carve((size_t)4 * N_NODES * 4);
    int* pcol4 = (int*)carve((size_t)4 * N_EDGES * 4);
    float* pval4 = (float*)carve((size_t)4 * N_EDGES * 4);

    // tier-1 carve: all 4 branches resident (bf16 everywhere)
    size_t tier1_base = off;
    unsigned short *Xbf[4], *W1h[4], *W2h[4], *Y1[4], *H1[4];
    for (int b = 0; b < 4; ++b) Xbf[b] = (unsigned short*)carve((size_t)N_NODES * din[b] * 2);
    for (int b = 0; b < 4; ++b) W1h[b] = (unsigned short*)carve((size_t)dh[b] * din[b] * 2);
    for (int b = 0; b < 4; ++b) W2h[b] = (unsigned short*)carve((size_t)128 * dh[b] * 2);
    for (int b = 0; b < 4; ++b) Y1[b] = (unsigned short*)carve((size_t)N_NODES * dh[b] * 2);
    for (int b = 0; b < 4; ++b) H1[b] = (unsigned short*)carve((size_t)N_NODES * dh[b] * 2);
    unsigned short* Y2all = (unsigned short*)carve((size_t)4 * N_NODES * 128 * 2);
    const bool tier1 = (off <= ws_size);
    unsigned short* Y2s[4];
    if (tier1) {
        for (int b = 0; b < 4; ++b) Y2s[b] = Y2all + (size_t)b * N_NODES * 128;
    } else {
        off = tier1_base;
        unsigned short* xb = (unsigned short*)carve((size_t)N_NODES * 4096 * 2);
        unsigned short* w1h = (unsigned short*)carve((size_t)512 * 4096 * 2);
        unsigned short* w2h = (unsigned short*)carve((size_t)128 * 512 * 2);
        unsigned short* y1 = (unsigned short*)carve((size_t)N_NODES * 512 * 2);
        unsigned short* h1 = (unsigned short*)carve((size_t)N_NODES * 512 * 2);
        unsigned short* y2 = (unsigned short*)carve((size_t)N_NODES * 128 * 2);
        for (int b = 0; b < 4; ++b) {
            Xbf[b] = xb; W1h[b] = w1h; W2h[b] = w2h;
            Y1[b] = y1; H1[b] = h1; Y2s[b] = y2;
        }
    }

    // ---- batched CSR build ----
    hipMemsetAsync(cnt4, 0, (size_t)4 * N_NODES * sizeof(int), stream);
    {
        dim3 g(N_EDGES / 256, 4);
        hist4<<<g, 256, 0, stream>>>(gp, cnt4);
        scan4<<<4, 256, 0, stream>>>(cnt4, rs4, cur4);
        scatter4<<<g, 256, 0, stream>>>(gp, cur4, pcol4, pval4);
    }

    if (tier1) {
        RoundB rb;
        for (int b = 0; b < 4; ++b) {
            rb.src[b] = X[b];
            rb.dst[b] = Xbf[b];
            rb.n4[b] = (long long)N_NODES * din[b] / 4;
        }
        round_bf16<<<dim3(32768, 4), 256, 0, stream>>>(rb);

        TransB t1;
        for (int b = 0; b < 4; ++b) {
            t1.W[b] = w1[b]; t1.Th[b] = W1h[b];
            t1.K[b] = din[b]; t1.N[b] = dh[b];
        }
        tsplit<<<dim3(128, 16, 4), 256, 0, stream>>>(t1);

        GemmB g1;
        for (int b = 0; b < 4; ++b) {
            g1.A[b] = Xbf[b]; g1.Bh[b] = W1h[b];
            g1.C[b] = Y1[b]; g1.K[b] = din[b]; g1.NT[b] = dh[b] / 256;
        }
        gemm_bf16s<8><<<dim3(64, 2, 4), 256, 0, stream>>>(g1);

        SpmmB s1;
        for (int b = 0; b < 4; ++b) {
            s1.rs[b] = rs4 + (size_t)b * (N_NODES + 1);
            s1.pc[b] = pcol4 + (size_t)b * N_EDGES;
            s1.pv[b] = pval4 + (size_t)b * N_EDGES;
            s1.Y[b] = Y1[b]; s1.bi[b] = b1[b]; s1.H[b] = H1[b];
        }
        spmm_h1<512><<<dim3(N_NODES / 4, 3), 256, 0, stream>>>(s1);
        SpmmB s1m = s1;
        s1m.rs[0] = s1.rs[3]; s1m.pc[0] = s1.pc[3]; s1m.pv[0] = s1.pv[3];
        s1m.Y[0] = s1.Y[3]; s1m.bi[0] = s1.bi[3]; s1m.H[0] = s1.H[3];
        spmm_h1<256><<<dim3(N_NODES / 4, 1), 256, 0, stream>>>(s1m);

        TransB t2;
        for (int b = 0; b < 4; ++b) {
            t2.W[b] = w2[b]; t2.Th[b] = W2h[b];
            t2.K[b] = dh[b]; t2.N[b] = 128;
        }
        tsplit<<<dim3(16, 4, 4), 256, 0, stream>>>(t2);

        GemmB g2;
        for (int b = 0; b < 4; ++b) {
            g2.A[b] = H1[b]; g2.Bh[b] = W2h[b];
            g2.C[b] = Y2s[b]; g2.K[b] = dh[b]; g2.NT[b] = 1;
        }
        gemm_bf16s<4><<<dim3(64, 1, 4), 256, 0, stream>>>(g2);

        Out4 ob;
        for (int b = 0; b < 4; ++b) ob.b2[b] = b2[b];
        spmm_out4<<<N_NODES / 4, 256, 0, stream>>>(rs4, pcol4, pval4, Y2all, ob, out);
    } else {
        for (int b = 0; b < 4; ++b) {
            RoundB rb;
            rb.src[0] = X[b]; rb.dst[0] = Xbf[b];
            rb.n4[0] = (long long)N_NODES * din[b] / 4;
            round_bf16<<<dim3((unsigned)(rb.n4[0] / 256), 1), 256, 0, stream>>>(rb);
            TransB t1;
            t1.W[0] = w1[b]; t1.Th[0] = W1h[b];
            t1.K[0] = din[b]; t1.N[0] = dh[b];
            tsplit<<<dim3(din[b] / 32, dh[b] / 32, 1), 256, 0, stream>>>(t1);
            GemmB g1;
            g1.A[0] = Xbf[b]; g1.Bh[0] = W1h[b];
            g1.C[0] = Y1[b]; g1.K[0] = din[b]; g1.NT[0] = dh[b] / 256;
            gemm_bf16s<8><<<dim3(64, dh[b] / 256, 1), 256, 0, stream>>>(g1);
            SpmmB s1;
            s1.rs[0] = rs4 + (size_t)b * (N_NODES + 1);
            s1.pc[0] = pcol4 + (size_t)b * N_EDGES;
            s1.pv[0] = pval4 + (size_t)b * N_EDGES;
            s1.Y[0] = Y1[b]; s1.bi[0] = b1[b]; s1.H[0] = H1[b];
            if (dh[b] == 512)
                spmm_h1<512><<<dim3(N_NODES / 4, 1), 256, 0, stream>>>(s1);
            else
                spmm_h1<256><<<dim3(N_NODES / 4, 1), 256, 0, stream>>>(s1);
            TransB t2;
            t2.W[0] = w2[b]; t2.Th[0] = W2h[b];
            t2.K[0] = dh[b]; t2.N[0] = 128;
            tsplit<<<dim3(dh[b] / 32, 4, 1), 256, 0, stream>>>(t2);
            GemmB g2;
            g2.A[0] = H1[b]; g2.Bh[0] = W2h[b];
            g2.C[0] = Y2s[b]; g2.K[0] = dh[b]; g2.NT[0] = 1;
            gemm_bf16s<4><<<dim3(64, 1, 1), 256, 0, stream>>>(g2);
            spmm_out1<<<N_NODES / 4, 256, 0, stream>>>(
                rs4 + (size_t)b * (N_NODES + 1), pcol4 + (size_t)b * N_EDGES,
                pval4 + (size_t)b * N_EDGES, Y2s[b], b2[b], out, b == 0);
        }
    }
}

// Round 10
// 533.054 us; speedup vs baseline: 18.3723x; 1.1655x over previous
//
#include <hip/hip_runtime.h>

#define N_NODES 8192
#define N_EDGES 262144
#define SLOPE 0.25f

typedef __attribute__((ext_vector_type(8))) short bf16x8;
typedef __attribute__((ext_vector_type(4))) float f32x4;

__device__ __forceinline__ float lrelu(float x) { return x >= 0.f ? x : SLOPE * x; }

__device__ __forceinline__ unsigned short bf16_rne(float x) {
    unsigned u = __float_as_uint(x);
    return (unsigned short)((u + 0x7FFFu + ((u >> 16) & 1u)) >> 16);
}
__device__ __forceinline__ float bf2f(unsigned short h) {
    return __uint_as_float(((unsigned)h) << 16);
}
__device__ __forceinline__ bf16x8 pack8(const float4& a, const float4& b) {
    bf16x8 r;
    r[0] = (short)bf16_rne(a.x); r[1] = (short)bf16_rne(a.y);
    r[2] = (short)bf16_rne(a.z); r[3] = (short)bf16_rne(a.w);
    r[4] = (short)bf16_rne(b.x); r[5] = (short)bf16_rne(b.y);
    r[6] = (short)bf16_rne(b.z); r[7] = (short)bf16_rne(b.w);
    return r;
}

#define GLDS16(g, l)                                                              \
    __builtin_amdgcn_global_load_lds((const __attribute__((address_space(1))) void*)(g), \
                                     (__attribute__((address_space(3))) void*)(l), 16, 0, 0)

// ---------------- batched W [K,N] f32 -> WT bf16 [N,K] (transpose + round) ----------------
struct TransB { const float* W[4]; unsigned short* Th[4]; int K[4]; int N[4]; };

__global__ __launch_bounds__(256) void tsplit(TransB tb) {
    const int z = blockIdx.z;
    const int K = tb.K[z], N = tb.N[z];
    const int k0 = blockIdx.x * 32, n0 = blockIdx.y * 32;
    if (k0 >= K || n0 >= N) return;
    __shared__ float t[32][33];
    const int tx = threadIdx.x & 31, ty = threadIdx.x >> 5;
    const float* W = tb.W[z];
#pragma unroll
    for (int i = 0; i < 32; i += 8)
        t[ty + i][tx] = W[(size_t)(k0 + ty + i) * N + n0 + tx];
    __syncthreads();
#pragma unroll
    for (int i = 0; i < 32; i += 8) {
        const int n = ty + i;
        tb.Th[z][(size_t)(n0 + n) * K + k0 + tx] = bf16_rne(t[tx][n]);
    }
}

// ---------------- batched GEMM: C(bf16) = A @ B(bf16)^T ----------------
// NF: wave-tile 64(M) x NF*16(N); block 128(M) x NF*32(N); 4 waves (2x2).
// AF32=1: A is f32, reg-staged (loads 2 iters ahead, cvt+ds_write after barrier).
// AF32=0: A is bf16, staged via global_load_lds (R9-verified path).
// B always bf16 via global_load_lds, depth-2, 3 LDS buffers, counted vmcnt.
// LDS layout both operands: [rows][64B]; granule (row,s), source k-group kg = s ^ ((row>>1)&3).
struct GemmB {
    const void* A[4];             // [M,K] f32 (AF32=1) or bf16 (AF32=0)
    const unsigned short* Bh[4];  // [N,K] bf16
    unsigned short* C[4];         // [M,N] bf16
    int K[4];
    int NT[4];                    // N / (NF*32) tiles
};

template <int NF, int AF32>
__global__ __launch_bounds__(256, 2) void gemm_bf16s(GemmB gb) {
    constexpr int BGR = NF / 2;  // B granules per thread per stage
    // bijective XCD-chunked swizzle (nwg divisible by 8 in all launches here)
    const int nwg = gridDim.x * gridDim.y * gridDim.z;
    int id = (blockIdx.z * gridDim.y + blockIdx.y) * gridDim.x + blockIdx.x;
    const int cpx = nwg >> 3;
    id = (id & 7) * cpx + (id >> 3);
    // by (N-tile) fastest: consecutive work-ids share the same A M-panel (L2 reuse)
    const int by = id % gridDim.y;
    const int rest = id / gridDim.y;
    const int bx = rest % gridDim.x;
    const int z = rest / gridDim.x;

    const int nt = gb.NT[z];
    if (by >= nt) return;
    const int K = gb.K[z];
    const int N = nt * (NF * 32);
    const float* __restrict__ Af = (const float*)gb.A[z];
    const unsigned short* __restrict__ Ab = (const unsigned short*)gb.A[z];
    const unsigned short* __restrict__ Bh = gb.Bh[z];
    unsigned short* __restrict__ C = gb.C[z];

    __shared__ unsigned short As[3 * 4096];        // 3 x 8 KB
    __shared__ unsigned short Bs[3 * NF * 1024];   // 3 x (NF*2 KB)
    const int tid = threadIdx.x;
    const int w = tid >> 6, lane = tid & 63;
    const int wm = w >> 1, wn = w & 1;
    const int bm0 = bx * 128, bn0 = by * (NF * 32);

    auto stageB = [&](int buf, int kt) {
        const int k0 = kt << 5;
#pragma unroll
        for (int i = 0; i < BGR; ++i) {
            const int f = (w * BGR + i) * 64 + lane;
            const int row = f >> 2, s = f & 3;
            const int kg = s ^ ((row >> 1) & 3);
            GLDS16(Bh + (size_t)(bn0 + row) * K + k0 + kg * 8,
                   &Bs[buf * (NF * 1024) + (w * BGR + i) * 512]);
        }
    };
    auto stageAglds = [&](int buf, int kt) {
        const int k0 = kt << 5;
#pragma unroll
        for (int i = 0; i < 2; ++i) {
            const int f = (w * 2 + i) * 64 + lane;
            const int row = f >> 2, s = f & 3;
            const int kg = s ^ ((row >> 1) & 3);
            GLDS16(Ab + (size_t)(bm0 + row) * K + k0 + kg * 8,
                   &As[buf * 4096 + (w * 2 + i) * 512]);
        }
    };
    auto issueA = [&](float4 (&ar)[2][2], int kt) {
        const int k0 = kt << 5;
#pragma unroll
        for (int i = 0; i < 2; ++i) {
            const int f = i * 256 + tid;
            const int row = f >> 2, s = f & 3;
            const int kg = s ^ ((row >> 1) & 3);
            const float* src = Af + (size_t)(bm0 + row) * K + k0 + kg * 8;
            ar[i][0] = *reinterpret_cast<const float4*>(src);
            ar[i][1] = *reinterpret_cast<const float4*>(src + 4);
        }
    };
    auto writeA = [&](float4 (&ar)[2][2], int buf) {
#pragma unroll
        for (int i = 0; i < 2; ++i)
            *reinterpret_cast<bf16x8*>(&As[buf * 4096 + (i * 256 + tid) * 8]) =
                pack8(ar[i][0], ar[i][1]);
    };

    f32x4 acc[4][NF];
#pragma unroll
    for (int mf = 0; mf < 4; ++mf)
#pragma unroll
        for (int nf = 0; nf < NF; ++nf) acc[mf][nf] = (f32x4){0.f, 0.f, 0.f, 0.f};

    const int nk = K >> 5;  // even, >= 16 in all uses
    float4 aE[2][2], aO[2][2];

    if constexpr (AF32) {
        issueA(aE, 0); stageB(0, 0);
        issueA(aO, 1); stageB(1, 1);
        asm volatile("s_waitcnt vmcnt(12)" ::: "memory");  // A(0) regs ready
        writeA(aE, 0);
        asm volatile("s_waitcnt lgkmcnt(0)" ::: "memory");
    } else {
        stageAglds(0, 0); stageB(0, 0);
        stageAglds(1, 1); stageB(1, 1);
    }

    auto body = [&](int t, float4 (&iset)[2][2], float4 (&wset)[2][2]) {
        const int cb = t % 3;
        if (t + 2 < nk) {
            if constexpr (AF32) issueA(iset, t + 2);
            else stageAglds((t + 2) % 3, t + 2);
            stageB((t + 2) % 3, t + 2);
            if constexpr (AF32) asm volatile("s_waitcnt vmcnt(16)" ::: "memory");
            else asm volatile("s_waitcnt vmcnt(8)" ::: "memory");
        } else if (t + 1 < nk) {
            if constexpr (AF32) asm volatile("s_waitcnt vmcnt(8)" ::: "memory");
            else asm volatile("s_waitcnt vmcnt(4)" ::: "memory");
        } else {
            asm volatile("s_waitcnt vmcnt(0)" ::: "memory");
        }
        __builtin_amdgcn_s_barrier();       // all waves' tile-t staging arrived
        __builtin_amdgcn_sched_barrier(0);

        if constexpr (AF32) {
            if (t + 1 < nk) {
                if (t + 2 < nk) asm volatile("s_waitcnt vmcnt(12)" ::: "memory");
                else asm volatile("s_waitcnt vmcnt(4)" ::: "memory");
                writeA(wset, (t + 1) % 3);  // A(t+1) -> its buffer (disjoint from cb)
            }
        }

        const int kq = lane >> 4;
        bf16x8 a[4], b[NF];
#pragma unroll
        for (int mf = 0; mf < 4; ++mf) {
            const int r = wm * 64 + mf * 16 + (lane & 15);
            a[mf] = *reinterpret_cast<const bf16x8*>(
                &As[cb * 4096 + r * 32 + ((kq ^ ((r >> 1) & 3)) << 3)]);
        }
#pragma unroll
        for (int nf = 0; nf < NF; ++nf) {
            const int r = wn * (NF * 16) + nf * 16 + (lane & 15);
            b[nf] = *reinterpret_cast<const bf16x8*>(
                &Bs[cb * (NF * 1024) + r * 32 + ((kq ^ ((r >> 1) & 3)) << 3)]);
        }
        __builtin_amdgcn_s_setprio(1);
#pragma unroll
        for (int mf = 0; mf < 4; ++mf)
#pragma unroll
            for (int nf = 0; nf < NF; ++nf)
                acc[mf][nf] = __builtin_amdgcn_mfma_f32_16x16x32_bf16(a[mf], b[nf], acc[mf][nf], 0, 0, 0);
        __builtin_amdgcn_s_setprio(0);

        asm volatile("s_waitcnt lgkmcnt(0)" ::: "memory");  // ds_writes visible
        __builtin_amdgcn_s_barrier();       // all waves done reading cb
    };

    for (int t = 0; t < nk; t += 2) {
        body(t, aE, aO);
        body(t + 1, aO, aE);
    }

    const int cr = (lane >> 4) * 4, cc = lane & 15;
#pragma unroll
    for (int mf = 0; mf < 4; ++mf)
#pragma unroll
        for (int nf = 0; nf < NF; ++nf)
#pragma unroll
            for (int j = 0; j < 4; ++j)
                C[(size_t)(bm0 + wm * 64 + mf * 16 + cr + j) * N + bn0 + wn * (NF * 16) + nf * 16 + cc] =
                    bf16_rne(acc[mf][nf][j]);
}

// ---------------- batched CSR build (4 graphs), packed (col,val) edges ----------------
struct GraphPtrs {
    const int* r[4];
    const int* c[4];
    const float* v[4];
};

__global__ __launch_bounds__(256) void hist4(GraphPtrs p, int* __restrict__ cnt4) {
    const int g = blockIdx.y;
    const int e = blockIdx.x * 256 + threadIdx.x;
    atomicAdd(&cnt4[g * N_NODES + p.r[g][e]], 1);
}

__global__ __launch_bounds__(256) void scan4(const int* __restrict__ cnt4,
                                             int* __restrict__ rs4,
                                             int* __restrict__ cur4) {
    const int g = blockIdx.x;
    const int* cnt = cnt4 + g * N_NODES;
    int* row_start = rs4 + (size_t)g * (N_NODES + 1);
    int* cursor = cur4 + g * N_NODES;
    __shared__ int ssum[256];
    const int t = threadIdx.x;
    int local[32];
    int s = 0;
#pragma unroll
    for (int j = 0; j < 32; ++j) { local[j] = cnt[t * 32 + j]; s += local[j]; }
    ssum[t] = s;
    __syncthreads();
    for (int off = 1; off < 256; off <<= 1) {
        const int v = ssum[t];
        const int add = (t >= off) ? ssum[t - off] : 0;
        __syncthreads();
        ssum[t] = v + add;
        __syncthreads();
    }
    int run = (t == 0) ? 0 : ssum[t - 1];
#pragma unroll
    for (int j = 0; j < 32; ++j) {
        row_start[t * 32 + j] = run;
        cursor[t * 32 + j] = run;
        run += local[j];
    }
    if (t == 255) row_start[N_NODES] = run;
}

__global__ __launch_bounds__(256) void scatter4(GraphPtrs p, int* __restrict__ cur4,
                                                unsigned long long* __restrict__ pe4) {
    const int g = blockIdx.y;
    const int e = blockIdx.x * 256 + threadIdx.x;
    const int r = p.r[g][e];
    const int pos = atomicAdd(&cur4[g * N_NODES + r], 1);
    pe4[(size_t)g * N_EDGES + pos] =
        (unsigned long long)(unsigned)p.c[g][e] |
        ((unsigned long long)__float_as_uint(p.v[g][e]) << 32);
}

// ---------------- gather SpMM layer 1 (batched): H = bf16(lrelu(spmm(Y) + bias)) ----------------
struct SpmmB {
    const int* rs[4];
    const unsigned long long* pe[4];
    const unsigned short* Y[4];   // bf16
    const float* bi[4];
    unsigned short* H[4];
};

template <int NC>
__global__ __launch_bounds__(256) void spmm_h1(SpmmB sb) {
    constexpr int PL = NC / 64;
    const int z = blockIdx.y;
    const int row = (blockIdx.x * 256 + threadIdx.x) >> 6;
    const int lane = threadIdx.x & 63;
    const int* rs = sb.rs[z];
    const int s = rs[row], e1 = rs[row + 1];
    const unsigned long long* pe = sb.pe[z];
    const unsigned short* Y = sb.Y[z];
    const int base = lane * PL;

    float acc[PL];
#pragma unroll
    for (int j = 0; j < PL; ++j) acc[j] = 0.f;
    for (int e = s; e < e1; ++e) {
        const unsigned long long ev = pe[e];
        const int c = (int)(unsigned)ev;
        const float v = __uint_as_float((unsigned)(ev >> 32));
        const unsigned short* y = Y + (size_t)c * NC + base;
        if constexpr (PL == 8) {
            const bf16x8 raw = *reinterpret_cast<const bf16x8*>(y);
#pragma unroll
            for (int j = 0; j < 8; ++j)
                acc[j] = fmaf(v, bf2f((unsigned short)raw[j]), acc[j]);
        } else {
            const ushort4 raw = *reinterpret_cast<const ushort4*>(y);
            acc[0] = fmaf(v, bf2f(raw.x), acc[0]);
            acc[1] = fmaf(v, bf2f(raw.y), acc[1]);
            acc[2] = fmaf(v, bf2f(raw.z), acc[2]);
            acc[3] = fmaf(v, bf2f(raw.w), acc[3]);
        }
    }
    const float* bi = sb.bi[z];
    unsigned short* H = sb.H[z] + (size_t)row * NC + base;
    if constexpr (PL == 8) {
        bf16x8 vh;
#pragma unroll
        for (int j = 0; j < 8; ++j) vh[j] = (short)bf16_rne(lrelu(acc[j] + bi[base + j]));
        *reinterpret_cast<bf16x8*>(H) = vh;
    } else {
        ushort4 vh;
        vh.x = bf16_rne(lrelu(acc[0] + bi[base + 0]));
        vh.y = bf16_rne(lrelu(acc[1] + bi[base + 1]));
        vh.z = bf16_rne(lrelu(acc[2] + bi[base + 2]));
        vh.w = bf16_rne(lrelu(acc[3] + bi[base + 3]));
        *reinterpret_cast<ushort4*>(H) = vh;
    }
}

// ---------------- fused output: out[row] = 0.25 * sum_b lrelu(spmm_b(Y2_b)[row] + b2_b) ----------------
struct Out4 { const float* b2[4]; };

__global__ __launch_bounds__(256) void spmm_out4(const int* __restrict__ rs4,
                                                 const unsigned long long* __restrict__ pe4,
                                                 const unsigned short* __restrict__ Y2all,
                                                 Out4 ob, float* __restrict__ out) {
    const int row = (blockIdx.x * 256 + threadIdx.x) >> 6;
    const int lane = threadIdx.x & 63;
    const int base = lane * 2;
    float r0 = 0.f, r1 = 0.f;
#pragma unroll
    for (int b = 0; b < 4; ++b) {
        const int* rs = rs4 + (size_t)b * (N_NODES + 1);
        const int s = rs[row], e1 = rs[row + 1];
        const unsigned long long* pe = pe4 + (size_t)b * N_EDGES;
        const unsigned short* Y = Y2all + (size_t)b * N_NODES * 128;
        float a0 = 0.f, a1 = 0.f;
        for (int e = s; e < e1; ++e) {
            const unsigned long long ev = pe[e];
            const float v = __uint_as_float((unsigned)(ev >> 32));
            const unsigned u = *reinterpret_cast<const unsigned*>(
                Y + (size_t)(unsigned)ev * 128 + base);
            a0 = fmaf(v, __uint_as_float(u << 16), a0);
            a1 = fmaf(v, __uint_as_float(u & 0xFFFF0000u), a1);
        }
        const float* bi = ob.b2[b];
        r0 += lrelu(a0 + bi[base]);
        r1 += lrelu(a1 + bi[base + 1]);
    }
    *reinterpret_cast<float2*>(out + (size_t)row * 128 + base) =
        make_float2(0.25f * r0, 0.25f * r1);
}

// tier-2 single-branch output accumulate
__global__ __launch_bounds__(256) void spmm_out1(const int* __restrict__ rs,
                                                 const unsigned long long* __restrict__ pe,
                                                 const unsigned short* __restrict__ Y,
                                                 const float* __restrict__ bias,
                                                 float* __restrict__ out, int first) {
    const int row = (blockIdx.x * 256 + threadIdx.x) >> 6;
    const int lane = threadIdx.x & 63;
    const int base = lane * 2;
    const int s = rs[row], e1 = rs[row + 1];
    float a0 = 0.f, a1 = 0.f;
    for (int e = s; e < e1; ++e) {
        const unsigned long long ev = pe[e];
        const float v = __uint_as_float((unsigned)(ev >> 32));
        const unsigned u = *reinterpret_cast<const unsigned*>(
            Y + (size_t)(unsigned)ev * 128 + base);
        a0 = fmaf(v, __uint_as_float(u << 16), a0);
        a1 = fmaf(v, __uint_as_float(u & 0xFFFF0000u), a1);
    }
    float r0 = 0.25f * lrelu(a0 + bias[base]);
    float r1 = 0.25f * lrelu(a1 + bias[base + 1]);
    float* o = out + (size_t)row * 128 + base;
    if (!first) {
        const float2 p = *reinterpret_cast<const float2*>(o);
        r0 += p.x;
        r1 += p.y;
    }
    *reinterpret_cast<float2*>(o) = make_float2(r0, r1);
}

extern "C" void kernel_launch(void* const* d_in, const int* in_sizes, int n_in,
                              void* d_out, int out_size, void* d_ws, size_t ws_size,
                              hipStream_t stream) {
    const float* X[4] = {(const float*)d_in[0], (const float*)d_in[1],
                         (const float*)d_in[2], (const float*)d_in[3]};
    GraphPtrs gp;
    for (int b = 0; b < 4; ++b) {
        gp.r[b] = (const int*)d_in[4 + 3 * b];
        gp.c[b] = (const int*)d_in[5 + 3 * b];
        gp.v[b] = (const float*)d_in[6 + 3 * b];
    }
    const float *w1[4], *b1[4], *w2[4], *b2[4];
    for (int b = 0; b < 4; ++b) {
        w1[b] = (const float*)d_in[16 + 4 * b + 0];
        b1[b] = (const float*)d_in[16 + 4 * b + 1];
        w2[b] = (const float*)d_in[16 + 4 * b + 2];
        b2[b] = (const float*)d_in[16 + 4 * b + 3];
    }
    const int din[4] = {4096, 4096, 4096, 1024};
    const int dh[4] = {512, 512, 512, 256};
    float* out = (float*)d_out;

    char* wsc = (char*)d_ws;
    size_t off = 0;
    auto carve = [&](size_t bytes) {
        void* p = wsc + off;
        off += (bytes + 255) & ~(size_t)255;
        return p;
    };
    int* cnt4 = (int*)carve((size_t)4 * N_NODES * 4);
    int* rs4 = (int*)carve((size_t)4 * (N_NODES + 1) * 4);
    int* cur4 = (int*)carve((size_t)4 * N_NODES * 4);
    unsigned long long* pe4 = (unsigned long long*)carve((size_t)4 * N_EDGES * 8);

    // tier-1 carve: all 4 branches resident (bf16 intermediates; no Xbf needed)
    size_t tier1_base = off;
    unsigned short *W1h[4], *W2h[4], *Y1[4], *H1[4];
    for (int b = 0; b < 4; ++b) W1h[b] = (unsigned short*)carve((size_t)dh[b] * din[b] * 2);
    for (int b = 0; b < 4; ++b) W2h[b] = (unsigned short*)carve((size_t)128 * dh[b] * 2);
    for (int b = 0; b < 4; ++b) Y1[b] = (unsigned short*)carve((size_t)N_NODES * dh[b] * 2);
    for (int b = 0; b < 4; ++b) H1[b] = (unsigned short*)carve((size_t)N_NODES * dh[b] * 2);
    unsigned short* Y2all = (unsigned short*)carve((size_t)4 * N_NODES * 128 * 2);
    const bool tier1 = (off <= ws_size);
    unsigned short* Y2s[4];
    if (tier1) {
        for (int b = 0; b < 4; ++b) Y2s[b] = Y2all + (size_t)b * N_NODES * 128;
    } else {
        off = tier1_base;
        unsigned short* w1h = (unsigned short*)carve((size_t)512 * 4096 * 2);
        unsigned short* w2h = (unsigned short*)carve((size_t)128 * 512 * 2);
        unsigned short* y1 = (unsigned short*)carve((size_t)N_NODES * 512 * 2);
        unsigned short* h1 = (unsigned short*)carve((size_t)N_NODES * 512 * 2);
        unsigned short* y2 = (unsigned short*)carve((size_t)N_NODES * 128 * 2);
        for (int b = 0; b < 4; ++b) {
            W1h[b] = w1h; W2h[b] = w2h;
            Y1[b] = y1; H1[b] = h1; Y2s[b] = y2;
        }
    }

    // ---- batched CSR build ----
    hipMemsetAsync(cnt4, 0, (size_t)4 * N_NODES * sizeof(int), stream);
    {
        dim3 g(N_EDGES / 256, 4);
        hist4<<<g, 256, 0, stream>>>(gp, cnt4);
        scan4<<<4, 256, 0, stream>>>(cnt4, rs4, cur4);
        scatter4<<<g, 256, 0, stream>>>(gp, cur4, pe4);
    }

    if (tier1) {
        TransB t1;
        for (int b = 0; b < 4; ++b) {
            t1.W[b] = w1[b]; t1.Th[b] = W1h[b];
            t1.K[b] = din[b]; t1.N[b] = dh[b];
        }
        tsplit<<<dim3(128, 16, 4), 256, 0, stream>>>(t1);

        GemmB g1;
        for (int b = 0; b < 4; ++b) {
            g1.A[b] = X[b]; g1.Bh[b] = W1h[b];
            g1.C[b] = Y1[b]; g1.K[b] = din[b]; g1.NT[b] = dh[b] / 256;
        }
        gemm_bf16s<8, 1><<<dim3(64, 2, 4), 256, 0, stream>>>(g1);

        SpmmB s1;
        for (int b = 0; b < 4; ++b) {
            s1.rs[b] = rs4 + (size_t)b * (N_NODES + 1);
            s1.pe[b] = pe4 + (size_t)b * N_EDGES;
            s1.Y[b] = Y1[b]; s1.bi[b] = b1[b]; s1.H[b] = H1[b];
        }
        spmm_h1<512><<<dim3(N_NODES / 4, 3), 256, 0, stream>>>(s1);
        SpmmB s1m = s1;
        s1m.rs[0] = s1.rs[3]; s1m.pe[0] = s1.pe[3];
        s1m.Y[0] = s1.Y[3]; s1m.bi[0] = s1.bi[3]; s1m.H[0] = s1.H[3];
        spmm_h1<256><<<dim3(N_NODES / 4, 1), 256, 0, stream>>>(s1m);

        TransB t2;
        for (int b = 0; b < 4; ++b) {
            t2.W[b] = w2[b]; t2.Th[b] = W2h[b];
            t2.K[b] = dh[b]; t2.N[b] = 128;
        }
        tsplit<<<dim3(16, 4, 4), 256, 0, stream>>>(t2);

        GemmB g2;
        for (int b = 0; b < 4; ++b) {
            g2.A[b] = H1[b]; g2.Bh[b] = W2h[b];
            g2.C[b] = Y2s[b]; g2.K[b] = dh[b]; g2.NT[b] = 1;
        }
        gemm_bf16s<4, 0><<<dim3(64, 1, 4), 256, 0, stream>>>(g2);

        Out4 ob;
        for (int b = 0; b < 4; ++b) ob.b2[b] = b2[b];
        spmm_out4<<<N_NODES / 4, 256, 0, stream>>>(rs4, pe4, Y2all, ob, out);
    } else {
        for (int b = 0; b < 4; ++b) {
            TransB t1;
            t1.W[0] = w1[b]; t1.Th[0] = W1h[b];
            t1.K[0] = din[b]; t1.N[0] = dh[b];
            tsplit<<<dim3(din[b] / 32, dh[b] / 32, 1), 256, 0, stream>>>(t1);
            GemmB g1;
            g1.A[0] = X[b]; g1.Bh[0] = W1h[b];
            g1.C[0] = Y1[b]; g1.K[0] = din[b]; g1.NT[0] = dh[b] / 256;
            gemm_bf16s<8, 1><<<dim3(64, dh[b] / 256, 1), 256, 0, stream>>>(g1);
            SpmmB s1;
            s1.rs[0] = rs4 + (size_t)b * (N_NODES + 1);
            s1.pe[0] = pe4 + (size_t)b * N_EDGES;
            s1.Y[0] = Y1[b]; s1.bi[0] = b1[b]; s1.H[0] = H1[b];
            if (dh[b] == 512)
                spmm_h1<512><<<dim3(N_NODES / 4, 1), 256, 0, stream>>>(s1);
            else
                spmm_h1<256><<<dim3(N_NODES / 4, 1), 256, 0, stream>>>(s1);
            TransB t2;
            t2.W[0] = w2[b]; t2.Th[0] = W2h[b];
            t2.K[0] = dh[b]; t2.N[0] = 128;
            tsplit<<<dim3(dh[b] / 32, 4, 1), 256, 0, stream>>>(t2);
            GemmB g2;
            g2.A[0] = H1[b]; g2.Bh[0] = W2h[b];
            g2.C[0] = Y2s[b]; g2.K[0] = dh[b]; g2.NT[0] = 1;
            gemm_bf16s<4, 0><<<dim3(64, 1, 1), 256, 0, stream>>>(g2);
            spmm_out1<<<N_NODES / 4, 256, 0, stream>>>(
                rs4 + (size_t)b * (N_NODES + 1), pe4 + (size_t)b * N_EDGES,
                Y2s[b], b2[b], out, b == 0);
        }
    }
}

// Round 11
// 526.717 us; speedup vs baseline: 18.5933x; 1.0120x over previous
//
#include <hip/hip_runtime.h>

#define N_NODES 8192
#define N_EDGES 262144
#define SLOPE 0.25f

typedef __attribute__((ext_vector_type(8))) short bf16x8;
typedef __attribute__((ext_vector_type(4))) float f32x4;

__device__ __forceinline__ float lrelu(float x) { return x >= 0.f ? x : SLOPE * x; }

__device__ __forceinline__ unsigned short bf16_rne(float x) {
    unsigned u = __float_as_uint(x);
    return (unsigned short)((u + 0x7FFFu + ((u >> 16) & 1u)) >> 16);
}
__device__ __forceinline__ float bf2f(unsigned short h) {
    return __uint_as_float(((unsigned)h) << 16);
}
__device__ __forceinline__ bf16x8 pack8(const float4& a, const float4& b) {
    bf16x8 r;
    r[0] = (short)bf16_rne(a.x); r[1] = (short)bf16_rne(a.y);
    r[2] = (short)bf16_rne(a.z); r[3] = (short)bf16_rne(a.w);
    r[4] = (short)bf16_rne(b.x); r[5] = (short)bf16_rne(b.y);
    r[6] = (short)bf16_rne(b.z); r[7] = (short)bf16_rne(b.w);
    return r;
}

#define GLDS16(g, l)                                                              \
    __builtin_amdgcn_global_load_lds((const __attribute__((address_space(1))) void*)(g), \
                                     (__attribute__((address_space(3))) void*)(l), 16, 0, 0)

// ---------------- batched W [K,N] f32 -> WT bf16 [N,K] (transpose + round) ----------------
struct TransB { const float* W[4]; unsigned short* Th[4]; int K[4]; int N[4]; };

__global__ __launch_bounds__(256) void tsplit(TransB tb) {
    const int z = blockIdx.z;
    const int K = tb.K[z], N = tb.N[z];
    const int k0 = blockIdx.x * 32, n0 = blockIdx.y * 32;
    if (k0 >= K || n0 >= N) return;
    __shared__ float t[32][33];
    const int tx = threadIdx.x & 31, ty = threadIdx.x >> 5;
    const float* W = tb.W[z];
#pragma unroll
    for (int i = 0; i < 32; i += 8)
        t[ty + i][tx] = W[(size_t)(k0 + ty + i) * N + n0 + tx];
    __syncthreads();
#pragma unroll
    for (int i = 0; i < 32; i += 8) {
        const int n = ty + i;
        tb.Th[z][(size_t)(n0 + n) * K + k0 + tx] = bf16_rne(t[tx][n]);
    }
}

// ---------------- batched GEMM: C(bf16) = A @ B(bf16)^T  (R10-verified) ----------------
struct GemmB {
    const void* A[4];             // [M,K] f32 (AF32=1) or bf16 (AF32=0)
    const unsigned short* Bh[4];  // [N,K] bf16
    unsigned short* C[4];         // [M,N] bf16
    int K[4];
    int NT[4];                    // N / (NF*32) tiles
};

template <int NF, int AF32>
__global__ __launch_bounds__(256, 2) void gemm_bf16s(GemmB gb) {
    constexpr int BGR = NF / 2;
    const int nwg = gridDim.x * gridDim.y * gridDim.z;
    int id = (blockIdx.z * gridDim.y + blockIdx.y) * gridDim.x + blockIdx.x;
    const int cpx = nwg >> 3;
    id = (id & 7) * cpx + (id >> 3);
    const int by = id % gridDim.y;
    const int rest = id / gridDim.y;
    const int bx = rest % gridDim.x;
    const int z = rest / gridDim.x;

    const int nt = gb.NT[z];
    if (by >= nt) return;
    const int K = gb.K[z];
    const int N = nt * (NF * 32);
    const float* __restrict__ Af = (const float*)gb.A[z];
    const unsigned short* __restrict__ Ab = (const unsigned short*)gb.A[z];
    const unsigned short* __restrict__ Bh = gb.Bh[z];
    unsigned short* __restrict__ C = gb.C[z];

    __shared__ unsigned short As[3 * 4096];
    __shared__ unsigned short Bs[3 * NF * 1024];
    const int tid = threadIdx.x;
    const int w = tid >> 6, lane = tid & 63;
    const int wm = w >> 1, wn = w & 1;
    const int bm0 = bx * 128, bn0 = by * (NF * 32);

    auto stageB = [&](int buf, int kt) {
        const int k0 = kt << 5;
#pragma unroll
        for (int i = 0; i < BGR; ++i) {
            const int f = (w * BGR + i) * 64 + lane;
            const int row = f >> 2, s = f & 3;
            const int kg = s ^ ((row >> 1) & 3);
            GLDS16(Bh + (size_t)(bn0 + row) * K + k0 + kg * 8,
                   &Bs[buf * (NF * 1024) + (w * BGR + i) * 512]);
        }
    };
    auto stageAglds = [&](int buf, int kt) {
        const int k0 = kt << 5;
#pragma unroll
        for (int i = 0; i < 2; ++i) {
            const int f = (w * 2 + i) * 64 + lane;
            const int row = f >> 2, s = f & 3;
            const int kg = s ^ ((row >> 1) & 3);
            GLDS16(Ab + (size_t)(bm0 + row) * K + k0 + kg * 8,
                   &As[buf * 4096 + (w * 2 + i) * 512]);
        }
    };
    auto issueA = [&](float4 (&ar)[2][2], int kt) {
        const int k0 = kt << 5;
#pragma unroll
        for (int i = 0; i < 2; ++i) {
            const int f = i * 256 + tid;
            const int row = f >> 2, s = f & 3;
            const int kg = s ^ ((row >> 1) & 3);
            const float* src = Af + (size_t)(bm0 + row) * K + k0 + kg * 8;
            ar[i][0] = *reinterpret_cast<const float4*>(src);
            ar[i][1] = *reinterpret_cast<const float4*>(src + 4);
        }
    };
    auto writeA = [&](float4 (&ar)[2][2], int buf) {
#pragma unroll
        for (int i = 0; i < 2; ++i)
            *reinterpret_cast<bf16x8*>(&As[buf * 4096 + (i * 256 + tid) * 8]) =
                pack8(ar[i][0], ar[i][1]);
    };

    f32x4 acc[4][NF];
#pragma unroll
    for (int mf = 0; mf < 4; ++mf)
#pragma unroll
        for (int nf = 0; nf < NF; ++nf) acc[mf][nf] = (f32x4){0.f, 0.f, 0.f, 0.f};

    const int nk = K >> 5;
    float4 aE[2][2], aO[2][2];

    if constexpr (AF32) {
        issueA(aE, 0); stageB(0, 0);
        issueA(aO, 1); stageB(1, 1);
        asm volatile("s_waitcnt vmcnt(12)" ::: "memory");
        writeA(aE, 0);
        asm volatile("s_waitcnt lgkmcnt(0)" ::: "memory");
    } else {
        stageAglds(0, 0); stageB(0, 0);
        stageAglds(1, 1); stageB(1, 1);
    }

    auto body = [&](int t, float4 (&iset)[2][2], float4 (&wset)[2][2]) {
        const int cb = t % 3;
        if (t + 2 < nk) {
            if constexpr (AF32) issueA(iset, t + 2);
            else stageAglds((t + 2) % 3, t + 2);
            stageB((t + 2) % 3, t + 2);
            if constexpr (AF32) asm volatile("s_waitcnt vmcnt(16)" ::: "memory");
            else asm volatile("s_waitcnt vmcnt(8)" ::: "memory");
        } else if (t + 1 < nk) {
            if constexpr (AF32) asm volatile("s_waitcnt vmcnt(8)" ::: "memory");
            else asm volatile("s_waitcnt vmcnt(4)" ::: "memory");
        } else {
            asm volatile("s_waitcnt vmcnt(0)" ::: "memory");
        }
        __builtin_amdgcn_s_barrier();
        __builtin_amdgcn_sched_barrier(0);

        if constexpr (AF32) {
            if (t + 1 < nk) {
                if (t + 2 < nk) asm volatile("s_waitcnt vmcnt(12)" ::: "memory");
                else asm volatile("s_waitcnt vmcnt(4)" ::: "memory");
                writeA(wset, (t + 1) % 3);
            }
        }

        const int kq = lane >> 4;
        bf16x8 a[4], b[NF];
#pragma unroll
        for (int mf = 0; mf < 4; ++mf) {
            const int r = wm * 64 + mf * 16 + (lane & 15);
            a[mf] = *reinterpret_cast<const bf16x8*>(
                &As[cb * 4096 + r * 32 + ((kq ^ ((r >> 1) & 3)) << 3)]);
        }
#pragma unroll
        for (int nf = 0; nf < NF; ++nf) {
            const int r = wn * (NF * 16) + nf * 16 + (lane & 15);
            b[nf] = *reinterpret_cast<const bf16x8*>(
                &Bs[cb * (NF * 1024) + r * 32 + ((kq ^ ((r >> 1) & 3)) << 3)]);
        }
        __builtin_amdgcn_s_setprio(1);
#pragma unroll
        for (int mf = 0; mf < 4; ++mf)
#pragma unroll
            for (int nf = 0; nf < NF; ++nf)
                acc[mf][nf] = __builtin_amdgcn_mfma_f32_16x16x32_bf16(a[mf], b[nf], acc[mf][nf], 0, 0, 0);
        __builtin_amdgcn_s_setprio(0);

        asm volatile("s_waitcnt lgkmcnt(0)" ::: "memory");
        __builtin_amdgcn_s_barrier();
    };

    for (int t = 0; t < nk; t += 2) {
        body(t, aE, aO);
        body(t + 1, aO, aE);
    }

    const int cr = (lane >> 4) * 4, cc = lane & 15;
#pragma unroll
    for (int mf = 0; mf < 4; ++mf)
#pragma unroll
        for (int nf = 0; nf < NF; ++nf)
#pragma unroll
            for (int j = 0; j < 4; ++j)
                C[(size_t)(bm0 + wm * 64 + mf * 16 + cr + j) * N + bn0 + wn * (NF * 16) + nf * 16 + cc] =
                    bf16_rne(acc[mf][nf][j]);
}

// ---------------- batched CSR build (4 graphs), packed (col,val) edges ----------------
struct GraphPtrs {
    const int* r[4];
    const int* c[4];
    const float* v[4];
};

__global__ __launch_bounds__(256) void hist4(GraphPtrs p, int* __restrict__ cnt4) {
    const int g = blockIdx.y;
    const int e = blockIdx.x * 256 + threadIdx.x;
    atomicAdd(&cnt4[g * N_NODES + p.r[g][e]], 1);
}

__global__ __launch_bounds__(256) void scan4(const int* __restrict__ cnt4,
                                             int* __restrict__ rs4,
                                             int* __restrict__ cur4) {
    const int g = blockIdx.x;
    const int* cnt = cnt4 + g * N_NODES;
    int* row_start = rs4 + (size_t)g * (N_NODES + 1);
    int* cursor = cur4 + g * N_NODES;
    __shared__ int ssum[256];
    const int t = threadIdx.x;
    int local[32];
    int s = 0;
#pragma unroll
    for (int j = 0; j < 32; ++j) { local[j] = cnt[t * 32 + j]; s += local[j]; }
    ssum[t] = s;
    __syncthreads();
    for (int off = 1; off < 256; off <<= 1) {
        const int v = ssum[t];
        const int add = (t >= off) ? ssum[t - off] : 0;
        __syncthreads();
        ssum[t] = v + add;
        __syncthreads();
    }
    int run = (t == 0) ? 0 : ssum[t - 1];
#pragma unroll
    for (int j = 0; j < 32; ++j) {
        row_start[t * 32 + j] = run;
        cursor[t * 32 + j] = run;
        run += local[j];
    }
    if (t == 255) row_start[N_NODES] = run;
}

__global__ __launch_bounds__(256) void scatter4(GraphPtrs p, int* __restrict__ cur4,
                                                unsigned long long* __restrict__ pe4) {
    const int g = blockIdx.y;
    const int e = blockIdx.x * 256 + threadIdx.x;
    const int r = p.r[g][e];
    const int pos = atomicAdd(&cur4[g * N_NODES + r], 1);
    pe4[(size_t)g * N_EDGES + pos] =
        (unsigned long long)(unsigned)p.c[g][e] |
        ((unsigned long long)__float_as_uint(p.v[g][e]) << 32);
}

// ---------------- gather SpMM layer 1: XCD-partitioned, all 4 branches ----------------
// Branch b runs on XCDs {2b, 2b+1}: its 8 MB Y1 fits the pair's combined 8 MB L2.
// blockIdx.x & 7 = XCD (round-robin dispatch heuristic; perf-only, not correctness).
struct SpmmB {
    const int* rs[4];
    const unsigned long long* pe[4];
    const unsigned short* Y[4];   // bf16
    const float* bi[4];
    unsigned short* H[4];
    int nc[4];
};

__global__ __launch_bounds__(256) void spmm_h1x(SpmmB sb) {
    const int id = blockIdx.x;              // 8192 blocks
    const int xcd = id & 7;
    const int z = xcd >> 1;                  // branch
    const int rb = ((id >> 3) << 1) + (id & 1);  // row-block 0..2047 within branch
    const int row = rb * 4 + (threadIdx.x >> 6);
    const int lane = threadIdx.x & 63;
    const int nc = sb.nc[z];
    const int* rs = sb.rs[z];
    const int s = rs[row], e1 = rs[row + 1];
    const unsigned long long* pe = sb.pe[z];
    const unsigned short* Y = sb.Y[z];
    const float* bi = sb.bi[z];

    if (nc == 512) {
        const int base = lane * 8;
        float acc[8];
#pragma unroll
        for (int j = 0; j < 8; ++j) acc[j] = 0.f;
        for (int e = s; e < e1; ++e) {
            const unsigned long long ev = pe[e];
            const float v = __uint_as_float((unsigned)(ev >> 32));
            const bf16x8 raw = *reinterpret_cast<const bf16x8*>(
                Y + (size_t)(unsigned)ev * 512 + base);
#pragma unroll
            for (int j = 0; j < 8; ++j)
                acc[j] = fmaf(v, bf2f((unsigned short)raw[j]), acc[j]);
        }
        bf16x8 vh;
#pragma unroll
        for (int j = 0; j < 8; ++j) vh[j] = (short)bf16_rne(lrelu(acc[j] + bi[base + j]));
        *reinterpret_cast<bf16x8*>(sb.H[z] + (size_t)row * 512 + base) = vh;
    } else {
        const int base = lane * 4;
        float acc[4];
#pragma unroll
        for (int j = 0; j < 4; ++j) acc[j] = 0.f;
        for (int e = s; e < e1; ++e) {
            const unsigned long long ev = pe[e];
            const float v = __uint_as_float((unsigned)(ev >> 32));
            const ushort4 raw = *reinterpret_cast<const ushort4*>(
                Y + (size_t)(unsigned)ev * 256 + base);
            acc[0] = fmaf(v, bf2f(raw.x), acc[0]);
            acc[1] = fmaf(v, bf2f(raw.y), acc[1]);
            acc[2] = fmaf(v, bf2f(raw.z), acc[2]);
            acc[3] = fmaf(v, bf2f(raw.w), acc[3]);
        }
        ushort4 vh;
        vh.x = bf16_rne(lrelu(acc[0] + bi[base + 0]));
        vh.y = bf16_rne(lrelu(acc[1] + bi[base + 1]));
        vh.z = bf16_rne(lrelu(acc[2] + bi[base + 2]));
        vh.w = bf16_rne(lrelu(acc[3] + bi[base + 3]));
        *reinterpret_cast<ushort4*>(sb.H[z] + (size_t)row * 256 + base) = vh;
    }
}

// tier-2 single-branch layer-1 spmm
template <int NC>
__global__ __launch_bounds__(256) void spmm_h1(const int* __restrict__ rs,
                                               const unsigned long long* __restrict__ pe,
                                               const unsigned short* __restrict__ Y,
                                               const float* __restrict__ bi,
                                               unsigned short* __restrict__ Hd) {
    constexpr int PL = NC / 64;
    const int row = (blockIdx.x * 256 + threadIdx.x) >> 6;
    const int lane = threadIdx.x & 63;
    const int s = rs[row], e1 = rs[row + 1];
    const int base = lane * PL;
    float acc[PL];
#pragma unroll
    for (int j = 0; j < PL; ++j) acc[j] = 0.f;
    for (int e = s; e < e1; ++e) {
        const unsigned long long ev = pe[e];
        const float v = __uint_as_float((unsigned)(ev >> 32));
        const unsigned short* y = Y + (size_t)(unsigned)ev * NC + base;
        if constexpr (PL == 8) {
            const bf16x8 raw = *reinterpret_cast<const bf16x8*>(y);
#pragma unroll
            for (int j = 0; j < 8; ++j)
                acc[j] = fmaf(v, bf2f((unsigned short)raw[j]), acc[j]);
        } else {
            const ushort4 raw = *reinterpret_cast<const ushort4*>(y);
            acc[0] = fmaf(v, bf2f(raw.x), acc[0]);
            acc[1] = fmaf(v, bf2f(raw.y), acc[1]);
            acc[2] = fmaf(v, bf2f(raw.z), acc[2]);
            acc[3] = fmaf(v, bf2f(raw.w), acc[3]);
        }
    }
    unsigned short* H = Hd + (size_t)row * NC + base;
    if constexpr (PL == 8) {
        bf16x8 vh;
#pragma unroll
        for (int j = 0; j < 8; ++j) vh[j] = (short)bf16_rne(lrelu(acc[j] + bi[base + j]));
        *reinterpret_cast<bf16x8*>(H) = vh;
    } else {
        ushort4 vh;
        vh.x = bf16_rne(lrelu(acc[0] + bi[base + 0]));
        vh.y = bf16_rne(lrelu(acc[1] + bi[base + 1]));
        vh.z = bf16_rne(lrelu(acc[2] + bi[base + 2]));
        vh.w = bf16_rne(lrelu(acc[3] + bi[base + 3]));
        *reinterpret_cast<ushort4*>(H) = vh;
    }
}

// ---------------- fused output: out[row] = 0.25 * sum_b lrelu(spmm_b(Y2_b)[row] + b2_b) ----------------
struct Out4 { const float* b2[4]; };

__global__ __launch_bounds__(256) void spmm_out4(const int* __restrict__ rs4,
                                                 const unsigned long long* __restrict__ pe4,
                                                 const unsigned short* __restrict__ Y2all,
                                                 Out4 ob, float* __restrict__ out) {
    const int row = (blockIdx.x * 256 + threadIdx.x) >> 6;
    const int lane = threadIdx.x & 63;
    const int base = lane * 2;
    float r0 = 0.f, r1 = 0.f;
#pragma unroll
    for (int b = 0; b < 4; ++b) {
        const int* rs = rs4 + (size_t)b * (N_NODES + 1);
        const int s = rs[row], e1 = rs[row + 1];
        const unsigned long long* pe = pe4 + (size_t)b * N_EDGES;
        const unsigned short* Y = Y2all + (size_t)b * N_NODES * 128;
        float a0 = 0.f, a1 = 0.f;
        for (int e = s; e < e1; ++e) {
            const unsigned long long ev = pe[e];
            const float v = __uint_as_float((unsigned)(ev >> 32));
            const unsigned u = *reinterpret_cast<const unsigned*>(
                Y + (size_t)(unsigned)ev * 128 + base);
            a0 = fmaf(v, __uint_as_float(u << 16), a0);
            a1 = fmaf(v, __uint_as_float(u & 0xFFFF0000u), a1);
        }
        const float* bi = ob.b2[b];
        r0 += lrelu(a0 + bi[base]);
        r1 += lrelu(a1 + bi[base + 1]);
    }
    *reinterpret_cast<float2*>(out + (size_t)row * 128 + base) =
        make_float2(0.25f * r0, 0.25f * r1);
}

// tier-2 single-branch output accumulate
__global__ __launch_bounds__(256) void spmm_out1(const int* __restrict__ rs,
                                                 const unsigned long long* __restrict__ pe,
                                                 const unsigned short* __restrict__ Y,
                                                 const float* __restrict__ bias,
                                                 float* __restrict__ out, int first) {
    const int row = (blockIdx.x * 256 + threadIdx.x) >> 6;
    const int lane = threadIdx.x & 63;
    const int base = lane * 2;
    const int s = rs[row], e1 = rs[row + 1];
    float a0 = 0.f, a1 = 0.f;
    for (int e = s; e < e1; ++e) {
        const unsigned long long ev = pe[e];
        const float v = __uint_as_float((unsigned)(ev >> 32));
        const unsigned u = *reinterpret_cast<const unsigned*>(
            Y + (size_t)(unsigned)ev * 128 + base);
        a0 = fmaf(v, __uint_as_float(u << 16), a0);
        a1 = fmaf(v, __uint_as_float(u & 0xFFFF0000u), a1);
    }
    float r0 = 0.25f * lrelu(a0 + bias[base]);
    float r1 = 0.25f * lrelu(a1 + bias[base + 1]);
    float* o = out + (size_t)row * 128 + base;
    if (!first) {
        const float2 p = *reinterpret_cast<const float2*>(o);
        r0 += p.x;
        r1 += p.y;
    }
    *reinterpret_cast<float2*>(o) = make_float2(r0, r1);
}

extern "C" void kernel_launch(void* const* d_in, const int* in_sizes, int n_in,
                              void* d_out, int out_size, void* d_ws, size_t ws_size,
                              hipStream_t stream) {
    const float* X[4] = {(const float*)d_in[0], (const float*)d_in[1],
                         (const float*)d_in[2], (const float*)d_in[3]};
    GraphPtrs gp;
    for (int b = 0; b < 4; ++b) {
        gp.r[b] = (const int*)d_in[4 + 3 * b];
        gp.c[b] = (const int*)d_in[5 + 3 * b];
        gp.v[b] = (const float*)d_in[6 + 3 * b];
    }
    const float *w1[4], *b1[4], *w2[4], *b2[4];
    for (int b = 0; b < 4; ++b) {
        w1[b] = (const float*)d_in[16 + 4 * b + 0];
        b1[b] = (const float*)d_in[16 + 4 * b + 1];
        w2[b] = (const float*)d_in[16 + 4 * b + 2];
        b2[b] = (const float*)d_in[16 + 4 * b + 3];
    }
    const int din[4] = {4096, 4096, 4096, 1024};
    const int dh[4] = {512, 512, 512, 256};
    float* out = (float*)d_out;

    char* wsc = (char*)d_ws;
    size_t off = 0;
    auto carve = [&](size_t bytes) {
        void* p = wsc + off;
        off += (bytes + 255) & ~(size_t)255;
        return p;
    };
    int* cnt4 = (int*)carve((size_t)4 * N_NODES * 4);
    int* rs4 = (int*)carve((size_t)4 * (N_NODES + 1) * 4);
    int* cur4 = (int*)carve((size_t)4 * N_NODES * 4);
    unsigned long long* pe4 = (unsigned long long*)carve((size_t)4 * N_EDGES * 8);

    size_t tier1_base = off;
    unsigned short *W1h[4], *W2h[4], *Y1[4], *H1[4];
    for (int b = 0; b < 4; ++b) W1h[b] = (unsigned short*)carve((size_t)dh[b] * din[b] * 2);
    for (int b = 0; b < 4; ++b) W2h[b] = (unsigned short*)carve((size_t)128 * dh[b] * 2);
    for (int b = 0; b < 4; ++b) Y1[b] = (unsigned short*)carve((size_t)N_NODES * dh[b] * 2);
    for (int b = 0; b < 4; ++b) H1[b] = (unsigned short*)carve((size_t)N_NODES * dh[b] * 2);
    unsigned short* Y2all = (unsigned short*)carve((size_t)4 * N_NODES * 128 * 2);
    const bool tier1 = (off <= ws_size);
    unsigned short* Y2s[4];
    if (tier1) {
        for (int b = 0; b < 4; ++b) Y2s[b] = Y2all + (size_t)b * N_NODES * 128;
    } else {
        off = tier1_base;
        unsigned short* w1h = (unsigned short*)carve((size_t)512 * 4096 * 2);
        unsigned short* w2h = (unsigned short*)carve((size_t)128 * 512 * 2);
        unsigned short* y1 = (unsigned short*)carve((size_t)N_NODES * 512 * 2);
        unsigned short* h1 = (unsigned short*)carve((size_t)N_NODES * 512 * 2);
        unsigned short* y2 = (unsigned short*)carve((size_t)N_NODES * 128 * 2);
        for (int b = 0; b < 4; ++b) {
            W1h[b] = w1h; W2h[b] = w2h;
            Y1[b] = y1; H1[b] = h1; Y2s[b] = y2;
        }
    }

    // ---- batched CSR build ----
    hipMemsetAsync(cnt4, 0, (size_t)4 * N_NODES * sizeof(int), stream);
    {
        dim3 g(N_EDGES / 256, 4);
        hist4<<<g, 256, 0, stream>>>(gp, cnt4);
        scan4<<<4, 256, 0, stream>>>(cnt4, rs4, cur4);
        scatter4<<<g, 256, 0, stream>>>(gp, cur4, pe4);
    }

    if (tier1) {
        TransB t1;
        for (int b = 0; b < 4; ++b) {
            t1.W[b] = w1[b]; t1.Th[b] = W1h[b];
            t1.K[b] = din[b]; t1.N[b] = dh[b];
        }
        tsplit<<<dim3(128, 16, 4), 256, 0, stream>>>(t1);

        GemmB g1;
        for (int b = 0; b < 4; ++b) {
            g1.A[b] = X[b]; g1.Bh[b] = W1h[b];
            g1.C[b] = Y1[b]; g1.K[b] = din[b]; g1.NT[b] = dh[b] / 256;
        }
        gemm_bf16s<8, 1><<<dim3(64, 2, 4), 256, 0, stream>>>(g1);

        // layer-1 spmm: single XCD-partitioned launch, all 4 branches
        SpmmB s1;
        for (int b = 0; b < 4; ++b) {
            s1.rs[b] = rs4 + (size_t)b * (N_NODES + 1);
            s1.pe[b] = pe4 + (size_t)b * N_EDGES;
            s1.Y[b] = Y1[b]; s1.bi[b] = b1[b]; s1.H[b] = H1[b];
            s1.nc[b] = dh[b];
        }
        spmm_h1x<<<8192, 256, 0, stream>>>(s1);

        TransB t2;
        for (int b = 0; b < 4; ++b) {
            t2.W[b] = w2[b]; t2.Th[b] = W2h[b];
            t2.K[b] = dh[b]; t2.N[b] = 128;
        }
        tsplit<<<dim3(16, 4, 4), 256, 0, stream>>>(t2);

        GemmB g2;
        for (int b = 0; b < 4; ++b) {
            g2.A[b] = H1[b]; g2.Bh[b] = W2h[b];
            g2.C[b] = Y2s[b]; g2.K[b] = dh[b]; g2.NT[b] = 1;
        }
        gemm_bf16s<4, 0><<<dim3(64, 1, 4), 256, 0, stream>>>(g2);

        Out4 ob;
        for (int b = 0; b < 4; ++b) ob.b2[b] = b2[b];
        spmm_out4<<<N_NODES / 4, 256, 0, stream>>>(rs4, pe4, Y2all, ob, out);
    } else {
        for (int b = 0; b < 4; ++b) {
            TransB t1;
            t1.W[0] = w1[b]; t1.Th[0] = W1h[b];
            t1.K[0] = din[b]; t1.N[0] = dh[b];
            tsplit<<<dim3(din[b] / 32, dh[b] / 32, 1), 256, 0, stream>>>(t1);
            GemmB g1;
            g1.A[0] = X[b]; g1.Bh[0] = W1h[b];
            g1.C[0] = Y1[b]; g1.K[0] = din[b]; g1.NT[0] = dh[b] / 256;
            gemm_bf16s<8, 1><<<dim3(64, dh[b] / 256, 1), 256, 0, stream>>>(g1);
            if (dh[b] == 512)
                spmm_h1<512><<<N_NODES / 4, 256, 0, stream>>>(
                    rs4 + (size_t)b * (N_NODES + 1), pe4 + (size_t)b * N_EDGES,
                    Y1[b], b1[b], H1[b]);
            else
                spmm_h1<256><<<N_NODES / 4, 256, 0, stream>>>(
                    rs4 + (size_t)b * (N_NODES + 1), pe4 + (size_t)b * N_EDGES,
                    Y1[b], b1[b], H1[b]);
            TransB t2;
            t2.W[0] = w2[b]; t2.Th[0] = W2h[b];
            t2.K[0] = dh[b]; t2.N[0] = 128;
            tsplit<<<dim3(dh[b] / 32, 4, 1), 256, 0, stream>>>(t2);
            GemmB g2;
            g2.A[0] = H1[b]; g2.Bh[0] = W2h[b];
            g2.C[0] = Y2s[b]; g2.K[0] = dh[b]; g2.NT[0] = 1;
            gemm_bf16s<4, 0><<<dim3(64, 1, 1), 256, 0, stream>>>(g2);
            spmm_out1<<<N_NODES / 4, 256, 0, stream>>>(
                rs4 + (size_t)b * (N_NODES + 1), pe4 + (size_t)b * N_EDGES,
                Y2s[b], b2[b], out, b == 0);
        }
    }
}